// Round 1
// baseline (1210.810 us; speedup 1.0000x reference)
//
#include <hip/hip_runtime.h>
#include <cstdint>
#include <cstddef>

#define Hh 8
#define Pp 64
#define Gg 64
#define DIN 512
#define CONVD 640
#define DPROJ 1168
#define BSZ 4
#define NTOK 8192
#define DIM 256

static __device__ __forceinline__ float sigmoidf_(float x) { return 1.f / (1.f + expf(-x)); }

// ---------------------------------------------------------------------------
// K1: C[r, j] = x[r,:256] @ [W_fx|W_x]^T (+bias), r in 32768, j in 1024.
// j<512 -> fx stored (B,H,N,P); j>=512 -> xm stored token-major (B*N, 512).
__global__ __launch_bounds__(256) void k_fxxm(
    const float* __restrict__ x, const float* __restrict__ Wfx, const float* __restrict__ bfx,
    const float* __restrict__ Wx, const float* __restrict__ bx,
    float* __restrict__ fx_out, float* __restrict__ xm_out) {
  __shared__ float at[64][65];
  __shared__ float bt[64][65];
  const int r0 = blockIdx.x * 64;
  const int c0 = blockIdx.y * 64;
  const int tid = threadIdx.x;
  const int i0 = (tid >> 4) << 2;
  const int j0 = (tid & 15) << 2;
  const int lrow = tid >> 2;
  const int lcol = (tid & 3) << 4;
  float acc[4][4] = {};
  for (int k0 = 0; k0 < DIM; k0 += 64) {
    const float* asrc = x + (size_t)(r0 + lrow) * DIM + k0 + lcol;
    const int j = c0 + lrow;
    const float* wsrc = (j < DIN ? Wfx + (size_t)j * DIM : Wx + (size_t)(j - DIN) * DIM) + k0 + lcol;
#pragma unroll
    for (int u = 0; u < 16; ++u) at[lrow][lcol + u] = asrc[u];
#pragma unroll
    for (int u = 0; u < 16; ++u) bt[lcol + u][lrow] = wsrc[u];
    __syncthreads();
#pragma unroll
    for (int kk = 0; kk < 64; ++kk) {
      float av[4], bv[4];
#pragma unroll
      for (int i = 0; i < 4; ++i) av[i] = at[i0 + i][kk];
#pragma unroll
      for (int j2 = 0; j2 < 4; ++j2) bv[j2] = bt[kk][j0 + j2];
#pragma unroll
      for (int i = 0; i < 4; ++i)
#pragma unroll
        for (int j2 = 0; j2 < 4; ++j2) acc[i][j2] += av[i] * bv[j2];
    }
    __syncthreads();
  }
#pragma unroll
  for (int i = 0; i < 4; ++i) {
    const int r = r0 + i0 + i;
    const int b = r >> 13, n = r & (NTOK - 1);
#pragma unroll
    for (int j2 = 0; j2 < 4; ++j2) {
      const int c = c0 + j0 + j2;
      float v = acc[i][j2];
      if (c < DIN) {
        v += bfx[c];
        const int h = c >> 6, p = c & 63;
        fx_out[(((b * Hh + h) * NTOK + n) << 6) + p] = v;
      } else {
        const int c2 = c - DIN;
        v += bx[c2];
        xm_out[(size_t)r * DIN + c2] = v;
      }
    }
  }
}

// ---------------------------------------------------------------------------
// K2: per (b,h,n) wave: scores = xm_h @ W_slice^T (+b_slice)/temp, softmax over G=64.
__global__ __launch_bounds__(256) void k_sw(
    const float* __restrict__ xm, const float* __restrict__ Wslice,
    const float* __restrict__ bslice, const float* __restrict__ temperature,
    float* __restrict__ sw) {
  __shared__ float ws[64][65];
  const int tid = threadIdx.x;
  for (int i = tid; i < 4096; i += 256) ws[i >> 6][i & 63] = Wslice[i];
  __syncthreads();
  const int wv = tid >> 6, lane = tid & 63;
  const int widx = blockIdx.x * 4 + wv;  // (b*H+h)*N + n, 0..262143
  const int n = widx & (NTOK - 1);
  const int bh = widx >> 13;
  const int h = bh & 7, b = bh >> 3;
  const float xv = xm[(size_t)(b * NTOK + n) * DIN + h * 64 + lane];
  float sc = 0.f;
#pragma unroll
  for (int p = 0; p < 64; ++p) sc += __shfl(xv, p) * ws[lane][p];
  const float t = fmaxf(temperature[h], 1e-6f);
  sc = (sc + bslice[lane]) / t;
  float m = sc;
#pragma unroll
  for (int off = 32; off; off >>= 1) m = fmaxf(m, __shfl_xor(m, off));
  const float e = expf(sc - m);
  float s = e;
#pragma unroll
  for (int off = 32; off; off >>= 1) s += __shfl_xor(s, off);
  sw[((size_t)bh * NTOK + n) * 64 + lane] = e / s;
}

// ---------------------------------------------------------------------------
// K3: per (b,h): st_raw[g,p] += sum_n sw[n,g]*fx[n,p]; snorm[g] += sum_n sw[n,g].
// Split-N (16 chunks of 512) with atomic accumulation.
__global__ __launch_bounds__(256) void k_st(
    const float* __restrict__ sw, const float* __restrict__ fx,
    float* __restrict__ st_raw, float* __restrict__ snorm) {
  __shared__ float s_sw[32][65];
  __shared__ float s_fx[32][65];
  const int bh = blockIdx.x;
  const int n0 = blockIdx.y * 512;
  const float* swp = sw + ((size_t)bh * NTOK + n0) * 64;
  const float* fxp = fx + ((size_t)bh * NTOK + n0) * 64;
  const int tid = threadIdx.x;
  const int g0 = (tid >> 4) << 2, p0 = (tid & 15) << 2;
  const int lrow = tid >> 3, lcol = (tid & 7) << 3;
  float acc[4][4] = {};
  float sn = 0.f;
  for (int nn = 0; nn < 512; nn += 32) {
    const float* a = swp + (size_t)(nn + lrow) * 64 + lcol;
    const float* f = fxp + (size_t)(nn + lrow) * 64 + lcol;
#pragma unroll
    for (int u = 0; u < 8; ++u) { s_sw[lrow][lcol + u] = a[u]; s_fx[lrow][lcol + u] = f[u]; }
    __syncthreads();
#pragma unroll
    for (int k = 0; k < 32; ++k) {
      float gv[4], pv[4];
#pragma unroll
      for (int i = 0; i < 4; ++i) gv[i] = s_sw[k][g0 + i];
#pragma unroll
      for (int i = 0; i < 4; ++i) pv[i] = s_fx[k][p0 + i];
#pragma unroll
      for (int i = 0; i < 4; ++i)
#pragma unroll
        for (int j = 0; j < 4; ++j) acc[i][j] += gv[i] * pv[j];
    }
    if (tid < 64) {
#pragma unroll
      for (int k = 0; k < 32; ++k) sn += s_sw[k][tid];
    }
    __syncthreads();
  }
  float* stp = st_raw + (size_t)bh * 4096;
#pragma unroll
  for (int i = 0; i < 4; ++i)
#pragma unroll
    for (int j = 0; j < 4; ++j) atomicAdd(&stp[(g0 + i) * 64 + p0 + j], acc[i][j]);
  if (tid < 64) atomicAdd(&snorm[bh * 64 + tid], sn);
}

// ---------------------------------------------------------------------------
// K3b: st2[b,g,h*64+p] = st_raw[b,h,g,p] / (snorm[b,h,g] + 1e-5)
__global__ __launch_bounds__(256) void k_stnorm(
    const float* __restrict__ st_raw, const float* __restrict__ snorm, float* __restrict__ st2) {
  const int idx = blockIdx.x * 256 + threadIdx.x;  // 131072
  const int p = idx & 63, g = (idx >> 6) & 63, h = (idx >> 12) & 7, b = idx >> 15;
  const float v = st_raw[idx] / (snorm[(b * Hh + h) * 64 + g] + 1e-5f);
  st2[(size_t)(b * 64 + g) * DIN + h * 64 + p] = v;
}

// ---------------------------------------------------------------------------
// K4: zx[r, c] = st2[r,:512] @ hy_in_w^T, r in 256, c in 1168.
__global__ __launch_bounds__(256) void k_inproj(
    const float* __restrict__ st2, const float* __restrict__ inw, float* __restrict__ zx) {
  __shared__ float at[64][65];
  __shared__ float bt[64][65];
  const int r0 = blockIdx.x * 64;
  const int c0 = blockIdx.y * 64;
  const int tid = threadIdx.x;
  const int i0 = (tid >> 4) << 2, j0 = (tid & 15) << 2;
  const int lrow = tid >> 2, lcol = (tid & 3) << 4;
  float acc[4][4] = {};
  for (int k0 = 0; k0 < DIN; k0 += 64) {
    const float* asrc = st2 + (size_t)(r0 + lrow) * DIN + k0 + lcol;
    const int j = c0 + lrow;
    const bool jok = j < DPROJ;
    const float* wsrc = inw + (size_t)(jok ? j : 0) * DIN + k0 + lcol;
#pragma unroll
    for (int u = 0; u < 16; ++u) at[lrow][lcol + u] = asrc[u];
#pragma unroll
    for (int u = 0; u < 16; ++u) bt[lcol + u][lrow] = jok ? wsrc[u] : 0.f;
    __syncthreads();
#pragma unroll
    for (int kk = 0; kk < 64; ++kk) {
      float av[4], bv[4];
#pragma unroll
      for (int i = 0; i < 4; ++i) av[i] = at[i0 + i][kk];
#pragma unroll
      for (int j2 = 0; j2 < 4; ++j2) bv[j2] = bt[kk][j0 + j2];
#pragma unroll
      for (int i = 0; i < 4; ++i)
#pragma unroll
        for (int j2 = 0; j2 < 4; ++j2) acc[i][j2] += av[i] * bv[j2];
    }
    __syncthreads();
  }
#pragma unroll
  for (int i = 0; i < 4; ++i) {
    const int r = r0 + i0 + i;
#pragma unroll
    for (int j2 = 0; j2 < 4; ++j2) {
      const int c = c0 + j0 + j2;
      if (c < DPROJ) zx[(size_t)r * DPROJ + c] = acc[i][j2];
    }
  }
}

// ---------------------------------------------------------------------------
// K4b: causal conv(k=3)+silu on xBC cols [512,1152); dt2/dA2 from cols [1152,1168).
__global__ __launch_bounds__(256) void k_prep(
    const float* __restrict__ zx, const float* __restrict__ convw, const float* __restrict__ convb,
    const float* __restrict__ dtbias, const float* __restrict__ Alog,
    float* __restrict__ xbc, float* __restrict__ dt2, float* __restrict__ dA2) {
  const int idx = blockIdx.x * 256 + threadIdx.x;
  const int NCONV = BSZ * 64 * CONVD;  // 163840
  if (idx < NCONV) {
    const int c = idx % CONVD;
    const int l = (idx / CONVD) & 63;
    const int b = idx / (CONVD * 64);
    float acc = convb[c];
#pragma unroll
    for (int k = 0; k < 3; ++k) {
      const int ls = l - 2 + k;
      if (ls >= 0) acc += zx[(size_t)(b * 64 + ls) * DPROJ + DIN + c] * convw[c * 3 + k];
    }
    xbc[idx] = acc * sigmoidf_(acc);
  } else if (idx < NCONV + 8 * 64 * 8) {
    const int j = idx - NCONV;
    const int h = j & 7, l = (j >> 3) & 63, bb = j >> 9;
    float raw;
    if (bb < 4) raw = zx[(size_t)(bb * 64 + l) * DPROJ + 1152 + h];
    else        raw = zx[(size_t)((bb - 4) * 64 + (63 - l)) * DPROJ + 1160 + h];
    const float d = raw + dtbias[h];
    const float sp = (d > 20.f) ? d : log1pf(expf(d));
    dt2[j] = sp;
    dA2[j] = expf(sp * -expf(Alog[h]));
  }
}

// ---------------------------------------------------------------------------
// K5: bidirectional SSM scan. wave handles 4 p's of one (bb,h); lane = state index n.
__global__ __launch_bounds__(256) void k_scan(
    const float* __restrict__ xbc, const float* __restrict__ dt2, const float* __restrict__ dA2,
    float* __restrict__ ys) {
  const int blk = blockIdx.x;          // 256 = 8(bb) * 8(h) * 4(pgroup)
  const int pg = blk & 3;
  const int h = (blk >> 2) & 7;
  const int bb = blk >> 5;
  const int wv = threadIdx.x >> 6, lane = threadIdx.x & 63;
  const int pbase = pg * 16 + wv * 4;
  const int b = (bb < 4) ? bb : bb - 4;
  const bool rev = bb >= 4;
  float st[4] = {0.f, 0.f, 0.f, 0.f};
  for (int t = 0; t < 64; ++t) {
    const int l = rev ? 63 - t : t;
    const float* row = xbc + (size_t)(b * 64 + l) * CONVD;
    const float bv = row[DIN + lane];
    const float cv = row[DIN + 64 + lane];
    const float dtv = dt2[(bb * 64 + t) * 8 + h];
    const float dav = dA2[(bb * 64 + t) * 8 + h];
#pragma unroll
    for (int j = 0; j < 4; ++j) {
      const float xval = row[h * 64 + pbase + j];
      const float s = st[j] * dav + dtv * xval * bv;
      st[j] = s;
      float pr = s * cv;
#pragma unroll
      for (int off = 32; off; off >>= 1) pr += __shfl_xor(pr, off);
      if (lane == 0) ys[(((size_t)(bb * 64 + t) * 8 + h) << 6) + pbase + j] = pr;
    }
  }
}

// ---------------------------------------------------------------------------
// K6a: y-combine + x_og*(fcD+D) + gate with silu(z) + RMS norm -> yg (4,64,512)
__global__ __launch_bounds__(256) void k_gate(
    const float* __restrict__ ys, const float* __restrict__ xbc, const float* __restrict__ zx,
    const float* __restrict__ fcdw, const float* __restrict__ Dp,
    const float* __restrict__ normw, float* __restrict__ yg) {
  __shared__ float red[256][9];
  __shared__ float s_xfc[8];
  const int bl = blockIdx.x;  // b*64 + l
  const int b = bl >> 6, l = bl & 63;
  const int tid = threadIdx.x;
  const float xog0 = xbc[(size_t)bl * CONVD + tid];
  const float xog1 = xbc[(size_t)bl * CONVD + 256 + tid];
#pragma unroll
  for (int h = 0; h < 8; ++h)
    red[tid][h] = xog0 * fcdw[h * DIN + tid] + xog1 * fcdw[h * DIN + 256 + tid];
  __syncthreads();
  for (int s = 128; s > 0; s >>= 1) {
    if (tid < s) {
#pragma unroll
      for (int h = 0; h < 8; ++h) red[tid][h] += red[tid + s][h];
    }
    __syncthreads();
  }
  if (tid < 8) s_xfc[tid] = red[0][tid] + Dp[tid];
  __syncthreads();
  float ygv[2];
  float sumsq = 0.f;
#pragma unroll
  for (int ci = 0; ci < 2; ++ci) {
    const int c = tid + ci * 256;
    const int h = c >> 6, p = c & 63;
    float yv = 0.f;
    if (l >= 1)  yv += ys[(((size_t)(b * 64 + (l - 1)) * 8 + h) << 6) + p];
    if (l <= 62) yv += ys[(((size_t)((4 + b) * 64 + (62 - l)) * 8 + h) << 6) + p];
    const float xog = (ci == 0) ? xog0 : xog1;
    yv += xog * s_xfc[h];
    const float z = zx[(size_t)bl * DPROJ + c];
    const float g = yv * (z * sigmoidf_(z));
    ygv[ci] = g;
    sumsq += g * g;
  }
  red[tid][0] = sumsq;
  __syncthreads();
  for (int s = 128; s > 0; s >>= 1) {
    if (tid < s) red[tid][0] += red[tid + s][0];
    __syncthreads();
  }
  const float scale = 1.f / sqrtf(red[0][0] / 512.f + 1e-5f);
#pragma unroll
  for (int ci = 0; ci < 2; ++ci) {
    const int c = tid + ci * 256;
    yg[(size_t)bl * DIN + c] = ygv[ci] * scale * normw[c];
  }
}

// ---------------------------------------------------------------------------
// K6b: ot = yg (256x512) @ hy_out_w^T (512x512)
__global__ __launch_bounds__(256) void k_oproj(
    const float* __restrict__ yg, const float* __restrict__ how, float* __restrict__ ot) {
  __shared__ float at[64][65];
  __shared__ float bt[64][65];
  const int r0 = blockIdx.x * 64;
  const int c0 = blockIdx.y * 64;
  const int tid = threadIdx.x;
  const int i0 = (tid >> 4) << 2, j0 = (tid & 15) << 2;
  const int lrow = tid >> 2, lcol = (tid & 3) << 4;
  float acc[4][4] = {};
  for (int k0 = 0; k0 < DIN; k0 += 64) {
    const float* asrc = yg + (size_t)(r0 + lrow) * DIN + k0 + lcol;
    const float* wsrc = how + (size_t)(c0 + lrow) * DIN + k0 + lcol;
#pragma unroll
    for (int u = 0; u < 16; ++u) at[lrow][lcol + u] = asrc[u];
#pragma unroll
    for (int u = 0; u < 16; ++u) bt[lcol + u][lrow] = wsrc[u];
    __syncthreads();
#pragma unroll
    for (int kk = 0; kk < 64; ++kk) {
      float av[4], bv[4];
#pragma unroll
      for (int i = 0; i < 4; ++i) av[i] = at[i0 + i][kk];
#pragma unroll
      for (int j2 = 0; j2 < 4; ++j2) bv[j2] = bt[kk][j0 + j2];
#pragma unroll
      for (int i = 0; i < 4; ++i)
#pragma unroll
        for (int j2 = 0; j2 < 4; ++j2) acc[i][j2] += av[i] * bv[j2];
    }
    __syncthreads();
  }
#pragma unroll
  for (int i = 0; i < 4; ++i)
#pragma unroll
    for (int j2 = 0; j2 < 4; ++j2)
      ot[(size_t)(r0 + i0 + i) * DIN + c0 + j0 + j2] = acc[i][j2];
}

// ---------------------------------------------------------------------------
// K7: inter[b, n, h*64+p] = sum_g sw[b,h,n,g] * ot[b, g, h*64+p]
__global__ __launch_bounds__(256) void k_mix(
    const float* __restrict__ sw, const float* __restrict__ ot, float* __restrict__ inter) {
  __shared__ float s_sw[64][65];
  __shared__ float s_ot[64][65];
  const int bh = blockIdx.y;
  const int b = bh >> 3, h = bh & 7;
  const int n0 = blockIdx.x * 64;
  const int tid = threadIdx.x;
  const int lrow = tid >> 2, lcol = (tid & 3) << 4;
  {
    const float* a = sw + ((size_t)bh * NTOK + n0 + lrow) * 64 + lcol;
    const float* o = ot + (size_t)(b * 64 + lrow) * DIN + h * 64 + lcol;
#pragma unroll
    for (int u = 0; u < 16; ++u) { s_sw[lrow][lcol + u] = a[u]; s_ot[lrow][lcol + u] = o[u]; }
  }
  __syncthreads();
  const int i0 = (tid >> 4) << 2, j0 = (tid & 15) << 2;
  float acc[4][4] = {};
#pragma unroll
  for (int g = 0; g < 64; ++g) {
    float gv[4], pv[4];
#pragma unroll
    for (int i = 0; i < 4; ++i) gv[i] = s_sw[i0 + i][g];
#pragma unroll
    for (int i = 0; i < 4; ++i) pv[i] = s_ot[g][j0 + i];
#pragma unroll
    for (int i = 0; i < 4; ++i)
#pragma unroll
      for (int j = 0; j < 4; ++j) acc[i][j] += gv[i] * pv[j];
  }
#pragma unroll
  for (int i = 0; i < 4; ++i)
#pragma unroll
    for (int j = 0; j < 4; ++j)
      inter[(size_t)(b * NTOK + n0 + i0 + i) * DIN + h * 64 + j0 + j] = acc[i][j];
}

// ---------------------------------------------------------------------------
// K8: out = inter (32768x512) @ out_w^T (512->256) + out_b
__global__ __launch_bounds__(256) void k_final(
    const float* __restrict__ inter, const float* __restrict__ outw,
    const float* __restrict__ outb, float* __restrict__ out) {
  __shared__ float at[64][65];
  __shared__ float bt[64][65];
  const int r0 = blockIdx.x * 64;
  const int c0 = blockIdx.y * 64;
  const int tid = threadIdx.x;
  const int i0 = (tid >> 4) << 2, j0 = (tid & 15) << 2;
  const int lrow = tid >> 2, lcol = (tid & 3) << 4;
  float acc[4][4] = {};
  for (int k0 = 0; k0 < DIN; k0 += 64) {
    const float* asrc = inter + (size_t)(r0 + lrow) * DIN + k0 + lcol;
    const float* wsrc = outw + (size_t)(c0 + lrow) * DIN + k0 + lcol;
#pragma unroll
    for (int u = 0; u < 16; ++u) at[lrow][lcol + u] = asrc[u];
#pragma unroll
    for (int u = 0; u < 16; ++u) bt[lcol + u][lrow] = wsrc[u];
    __syncthreads();
#pragma unroll
    for (int kk = 0; kk < 64; ++kk) {
      float av[4], bv[4];
#pragma unroll
      for (int i = 0; i < 4; ++i) av[i] = at[i0 + i][kk];
#pragma unroll
      for (int j2 = 0; j2 < 4; ++j2) bv[j2] = bt[kk][j0 + j2];
#pragma unroll
      for (int i = 0; i < 4; ++i)
#pragma unroll
        for (int j2 = 0; j2 < 4; ++j2) acc[i][j2] += av[i] * bv[j2];
    }
    __syncthreads();
  }
#pragma unroll
  for (int i = 0; i < 4; ++i) {
    const int r = r0 + i0 + i;
#pragma unroll
    for (int j2 = 0; j2 < 4; ++j2) {
      const int c = c0 + j0 + j2;
      out[(size_t)r * DIM + c] = acc[i][j2] + outb[c];
    }
  }
}

// ---------------------------------------------------------------------------
extern "C" void kernel_launch(void* const* d_in, const int* in_sizes, int n_in,
                              void* d_out, int out_size, void* d_ws, size_t ws_size,
                              hipStream_t stream) {
  const float* x      = (const float*)d_in[0];
  const float* Wfx    = (const float*)d_in[1];
  const float* bfx    = (const float*)d_in[2];
  const float* Wx     = (const float*)d_in[3];
  const float* bx     = (const float*)d_in[4];
  const float* Wslice = (const float*)d_in[5];
  const float* bslice = (const float*)d_in[6];
  const float* temp   = (const float*)d_in[7];
  const float* inw    = (const float*)d_in[8];
  const float* convw  = (const float*)d_in[9];
  const float* convb  = (const float*)d_in[10];
  const float* dtbias = (const float*)d_in[11];
  const float* Alog   = (const float*)d_in[12];
  const float* Dp     = (const float*)d_in[13];
  const float* fcdw   = (const float*)d_in[14];
  const float* normw  = (const float*)d_in[15];
  const float* how    = (const float*)d_in[16];
  const float* outw   = (const float*)d_in[17];
  const float* outb   = (const float*)d_in[18];

  float* ws = (float*)d_ws;
  float* fx     = ws;                   // 16,777,216
  float* sw     = fx + 16777216;        // 16,777,216
  float* xm     = sw + 16777216;        // 16,777,216 (reused as inter after K2/K7)
  float* inter  = xm;
  float* st_raw = xm + 16777216;        // 131,072
  float* snorm  = st_raw + 131072;      // 2,048
  float* st2    = snorm + 2048;         // 131,072
  float* zx     = st2 + 131072;         // 299,008
  float* xbc    = zx + 299008;          // 163,840
  float* dt2    = xbc + 163840;         // 4,096
  float* dA2    = dt2 + 4096;           // 4,096
  float* ysb    = dA2 + 4096;           // 262,144
  float* ygb    = ysb + 262144;         // 131,072
  float* otb    = ygb + 131072;         // 131,072

  // zero atomic accumulators (st_raw + snorm are contiguous)
  hipMemsetAsync(st_raw, 0, (131072 + 2048) * sizeof(float), stream);

  k_fxxm  <<<dim3(512, 16), 256, 0, stream>>>(x, Wfx, bfx, Wx, bx, fx, xm);
  k_sw    <<<dim3(65536),   256, 0, stream>>>(xm, Wslice, bslice, temp, sw);
  k_st    <<<dim3(32, 16),  256, 0, stream>>>(sw, fx, st_raw, snorm);
  k_stnorm<<<dim3(512),     256, 0, stream>>>(st_raw, snorm, st2);
  k_inproj<<<dim3(4, 19),   256, 0, stream>>>(st2, inw, zx);
  k_prep  <<<dim3(656),     256, 0, stream>>>(zx, convw, convb, dtbias, Alog, xbc, dt2, dA2);
  k_scan  <<<dim3(256),     256, 0, stream>>>(xbc, dt2, dA2, ysb);
  k_gate  <<<dim3(256),     256, 0, stream>>>(ysb, xbc, zx, fcdw, Dp, normw, ygb);
  k_oproj <<<dim3(4, 8),    256, 0, stream>>>(ygb, how, otb);
  k_mix   <<<dim3(128, 32), 256, 0, stream>>>(sw, otb, inter);
  k_final <<<dim3(512, 4),  256, 0, stream>>>(inter, outw, outb, (float*)d_out);
}

// Round 2
// 723.594 us; speedup vs baseline: 1.6733x; 1.6733x over previous
//
#include <hip/hip_runtime.h>
#include <hip/hip_bf16.h>
#include <cstdint>
#include <cstddef>

#define Hh 8
#define DIN 512
#define CONVD 640
#define DPROJ 1168
#define NTOK 8192
#define DIM 256

typedef __attribute__((ext_vector_type(8))) short short8;
typedef __attribute__((ext_vector_type(4))) float f32x4;

static __device__ __forceinline__ float sigmoidf_(float x) { return 1.f / (1.f + expf(-x)); }
static __device__ __forceinline__ unsigned short f2b(float f) {
  __hip_bfloat16 h = __float2bfloat16(f);
  return *(unsigned short*)&h;
}
static __device__ __forceinline__ float b2f(unsigned short u) {
  union { unsigned int i; float f; } cv; cv.i = ((unsigned int)u) << 16; return cv.f;
}

// ---------------------------------------------------------------------------
// K0: fp32 -> bf16 conversions: x (8388608), Wfx|Wx -> wcat (262144), outw (131072)
__global__ __launch_bounds__(256) void k_cvt(
    const float* __restrict__ x, const float* __restrict__ wfx, const float* __restrict__ wx,
    const float* __restrict__ outw, unsigned short* __restrict__ xb,
    unsigned short* __restrict__ wcat, unsigned short* __restrict__ outwb) {
  const int e = (blockIdx.x * 256 + threadIdx.x) * 4;
  const float* src; unsigned short* dst; int i;
  if (e < 8388608)       { i = e;           src = x;    dst = xb; }
  else if (e < 8519680)  { i = e - 8388608; src = wfx;  dst = wcat; }
  else if (e < 8650752)  { i = e - 8519680; src = wx;   dst = wcat + 131072; }
  else                   { i = e - 8650752; src = outw; dst = outwb; }
  float4 v = *(const float4*)(src + i);
  ushort4 o;
  o.x = f2b(v.x); o.y = f2b(v.y); o.z = f2b(v.z); o.w = f2b(v.w);
  *(ushort4*)(dst + i) = o;
}

// ---------------------------------------------------------------------------
// K1: [fx|xm] = x @ [W_fx|W_x]^T (+bias). MFMA bf16. M=32768, N=1024, K=256.
// fx -> bf16 (b,h,n,p); xm -> fp32 token-major.
__global__ __launch_bounds__(256) void k_fxxm(
    const unsigned short* __restrict__ xb, const unsigned short* __restrict__ wcat,
    const float* __restrict__ bfx, const float* __restrict__ bx,
    unsigned short* __restrict__ fxb, float* __restrict__ xm) {
  __shared__ unsigned short As[8 * 128 * 8];  // [kb][m][8]
  __shared__ unsigned short Bs[8 * 128 * 8];
  const int tid = threadIdx.x;
  const int m0 = blockIdx.x * 128;
  const int n0 = blockIdx.y * 128;
  const int w = tid >> 6, lane = tid & 63;
  const int l15 = lane & 15, kq = lane >> 4;
  const int wm = (w & 1) * 64, wn = (w >> 1) * 64;
  f32x4 acc[4][4];
#pragma unroll
  for (int i = 0; i < 4; ++i)
#pragma unroll
    for (int j = 0; j < 4; ++j) acc[i][j] = (f32x4){0.f, 0.f, 0.f, 0.f};
  for (int kt = 0; kt < 256; kt += 64) {
#pragma unroll
    for (int i = 0; i < 4; ++i) {
      const int c = tid + 256 * i, m = c >> 3, kb = c & 7;
      *(short8*)&As[(kb * 128 + m) * 8] = *(const short8*)&xb[(size_t)(m0 + m) * 256 + kt + kb * 8];
      *(short8*)&Bs[(kb * 128 + m) * 8] = *(const short8*)&wcat[(size_t)(n0 + m) * 256 + kt + kb * 8];
    }
    __syncthreads();
#pragma unroll
    for (int kw = 0; kw < 2; ++kw) {
      short8 af[4], bfr[4];
#pragma unroll
      for (int i = 0; i < 4; ++i) {
        af[i]  = *(const short8*)&As[((kw * 4 + kq) * 128 + wm + i * 16 + l15) * 8];
        bfr[i] = *(const short8*)&Bs[((kw * 4 + kq) * 128 + wn + i * 16 + l15) * 8];
      }
#pragma unroll
      for (int i = 0; i < 4; ++i)
#pragma unroll
        for (int j = 0; j < 4; ++j)
          acc[i][j] = __builtin_amdgcn_mfma_f32_16x16x32_bf16(af[i], bfr[j], acc[i][j], 0, 0, 0);
    }
    __syncthreads();
  }
#pragma unroll
  for (int i = 0; i < 4; ++i)
#pragma unroll
    for (int j = 0; j < 4; ++j)
#pragma unroll
      for (int r = 0; r < 4; ++r) {
        const int R = m0 + wm + i * 16 + kq * 4 + r;
        const int C = n0 + wn + j * 16 + l15;
        float v = acc[i][j][r];
        if (C < DIN) {
          v += bfx[C];
          const int b = R >> 13, n = R & (NTOK - 1), h = C >> 6, p = C & 63;
          fxb[(((size_t)(b * Hh + h) * NTOK + n) << 6) + p] = f2b(v);
        } else {
          xm[(size_t)R * DIN + (C - DIN)] = v + bx[C - DIN];
        }
      }
}

// ---------------------------------------------------------------------------
// K2: per (b,h,n) wave: scores = xm_h @ W_slice^T (+b)/temp, softmax over G=64 -> bf16
__global__ __launch_bounds__(256) void k_sw(
    const float* __restrict__ xm, const float* __restrict__ Wslice,
    const float* __restrict__ bslice, const float* __restrict__ temperature,
    unsigned short* __restrict__ swb) {
  __shared__ float ws[64][65];
  const int tid = threadIdx.x;
  for (int i = tid; i < 4096; i += 256) ws[i >> 6][i & 63] = Wslice[i];
  __syncthreads();
  const int wv = tid >> 6, lane = tid & 63;
  const int widx = blockIdx.x * 4 + wv;
  const int n = widx & (NTOK - 1);
  const int bh = widx >> 13;
  const int h = bh & 7, b = bh >> 3;
  const float xv = xm[(size_t)(b * NTOK + n) * DIN + h * 64 + lane];
  float sc = 0.f;
#pragma unroll
  for (int p = 0; p < 64; ++p) sc += __shfl(xv, p) * ws[lane][p];
  const float t = fmaxf(temperature[h], 1e-6f);
  sc = (sc + bslice[lane]) / t;
  float m = sc;
#pragma unroll
  for (int off = 32; off; off >>= 1) m = fmaxf(m, __shfl_xor(m, off));
  const float e = expf(sc - m);
  float s = e;
#pragma unroll
  for (int off = 32; off; off >>= 1) s += __shfl_xor(s, off);
  swb[((size_t)bh * NTOK + n) * 64 + lane] = f2b(e / s);
}

// ---------------------------------------------------------------------------
// K3: st_raw[bh][g][p] = sum_n sw[n,g]*fx[n,p]; snorm[bh][g] = sum_n sw[n,g].
// MFMA with LDS-transpose staging (contraction over n). grid (16 nsplit, 32 bh).
__global__ __launch_bounds__(256) void k_st(
    const unsigned short* __restrict__ swb, const unsigned short* __restrict__ fxb,
    float* __restrict__ st_raw, float* __restrict__ snorm) {
  __shared__ unsigned short swT[64][136];  // [g][n] (+pad, 16B-aligned rows)
  __shared__ unsigned short fxT[64][136];  // [p][n]
  const int tid = threadIdx.x;
  const int bh = blockIdx.y;
  const int nbase = blockIdx.x * 512;
  const int w = tid >> 6, lane = tid & 63;
  const int l15 = lane & 15, kq = lane >> 4;
  f32x4 acc[4];
#pragma unroll
  for (int i = 0; i < 4; ++i) acc[i] = (f32x4){0.f, 0.f, 0.f, 0.f};
  float sn = 0.f;
  for (int nc = 0; nc < 4; ++nc) {
    const int n0 = nbase + nc * 128;
#pragma unroll
    for (int i = 0; i < 4; ++i) {
      const int c = tid + 256 * i, n = c >> 3, gc = c & 7;
      short8 sv = *(const short8*)&swb[((size_t)bh * NTOK + n0 + n) * 64 + gc * 8];
      short8 fv = *(const short8*)&fxb[((size_t)bh * NTOK + n0 + n) * 64 + gc * 8];
#pragma unroll
      for (int u = 0; u < 8; ++u) {
        swT[gc * 8 + u][n] = (unsigned short)sv[u];
        fxT[gc * 8 + u][n] = (unsigned short)fv[u];
      }
    }
    __syncthreads();
    {
      const int g = tid & 63, q = tid >> 6;
#pragma unroll
      for (int nn = 0; nn < 32; ++nn) sn += b2f(swT[g][q * 32 + nn]);
    }
#pragma unroll
    for (int kw = 0; kw < 4; ++kw) {
      short8 bfr = *(const short8*)&fxT[w * 16 + l15][kw * 32 + kq * 8];
#pragma unroll
      for (int mi = 0; mi < 4; ++mi) {
        short8 af = *(const short8*)&swT[mi * 16 + l15][kw * 32 + kq * 8];
        acc[mi] = __builtin_amdgcn_mfma_f32_16x16x32_bf16(af, bfr, acc[mi], 0, 0, 0);
      }
    }
    __syncthreads();
  }
  float* stp = st_raw + (size_t)bh * 4096;
#pragma unroll
  for (int mi = 0; mi < 4; ++mi)
#pragma unroll
    for (int r = 0; r < 4; ++r)
      atomicAdd(&stp[(mi * 16 + kq * 4 + r) * 64 + w * 16 + l15], acc[mi][r]);
  atomicAdd(&snorm[bh * 64 + (tid & 63)], sn);
}

// ---------------------------------------------------------------------------
// K3b: st2[b,g,h*64+p] = st_raw[b,h,g,p] / (snorm[b,h,g] + 1e-5)
__global__ __launch_bounds__(256) void k_stnorm(
    const float* __restrict__ st_raw, const float* __restrict__ snorm, float* __restrict__ st2) {
  const int idx = blockIdx.x * 256 + threadIdx.x;
  const int p = idx & 63, g = (idx >> 6) & 63, h = (idx >> 12) & 7, b = idx >> 15;
  const float v = st_raw[idx] / (snorm[(b * Hh + h) * 64 + g] + 1e-5f);
  st2[(size_t)(b * 64 + g) * DIN + h * 64 + p] = v;
}

// ---------------------------------------------------------------------------
// K4: zx = st2 (256x512) @ hy_in_w^T (512->1168). fp32 (tiny).
__global__ __launch_bounds__(256) void k_inproj(
    const float* __restrict__ st2, const float* __restrict__ inw, float* __restrict__ zx) {
  __shared__ float at[64][65];
  __shared__ float bt[64][65];
  const int r0 = blockIdx.x * 64;
  const int c0 = blockIdx.y * 64;
  const int tid = threadIdx.x;
  const int i0 = (tid >> 4) << 2, j0 = (tid & 15) << 2;
  const int lrow = tid >> 2, lcol = (tid & 3) << 4;
  float acc[4][4] = {};
  for (int k0 = 0; k0 < DIN; k0 += 64) {
    const float* asrc = st2 + (size_t)(r0 + lrow) * DIN + k0 + lcol;
    const int j = c0 + lrow;
    const bool jok = j < DPROJ;
    const float* wsrc = inw + (size_t)(jok ? j : 0) * DIN + k0 + lcol;
#pragma unroll
    for (int u = 0; u < 16; ++u) at[lrow][lcol + u] = asrc[u];
#pragma unroll
    for (int u = 0; u < 16; ++u) bt[lcol + u][lrow] = jok ? wsrc[u] : 0.f;
    __syncthreads();
#pragma unroll
    for (int kk = 0; kk < 64; ++kk) {
      float av[4], bv[4];
#pragma unroll
      for (int i = 0; i < 4; ++i) av[i] = at[i0 + i][kk];
#pragma unroll
      for (int j2 = 0; j2 < 4; ++j2) bv[j2] = bt[kk][j0 + j2];
#pragma unroll
      for (int i = 0; i < 4; ++i)
#pragma unroll
        for (int j2 = 0; j2 < 4; ++j2) acc[i][j2] += av[i] * bv[j2];
    }
    __syncthreads();
  }
#pragma unroll
  for (int i = 0; i < 4; ++i)
#pragma unroll
    for (int j2 = 0; j2 < 4; ++j2) {
      const int c = c0 + j0 + j2;
      if (c < DPROJ) zx[(size_t)(r0 + i0 + i) * DPROJ + c] = acc[i][j2];
    }
}

// ---------------------------------------------------------------------------
// K4b: conv(k=3)+silu; dt2/dA2.
__global__ __launch_bounds__(256) void k_prep(
    const float* __restrict__ zx, const float* __restrict__ convw, const float* __restrict__ convb,
    const float* __restrict__ dtbias, const float* __restrict__ Alog,
    float* __restrict__ xbc, float* __restrict__ dt2, float* __restrict__ dA2) {
  const int idx = blockIdx.x * 256 + threadIdx.x;
  const int NCONV = 4 * 64 * CONVD;
  if (idx < NCONV) {
    const int c = idx % CONVD;
    const int l = (idx / CONVD) & 63;
    const int b = idx / (CONVD * 64);
    float acc = convb[c];
#pragma unroll
    for (int k = 0; k < 3; ++k) {
      const int ls = l - 2 + k;
      if (ls >= 0) acc += zx[(size_t)(b * 64 + ls) * DPROJ + DIN + c] * convw[c * 3 + k];
    }
    xbc[idx] = acc * sigmoidf_(acc);
  } else if (idx < NCONV + 8 * 64 * 8) {
    const int j = idx - NCONV;
    const int h = j & 7, l = (j >> 3) & 63, bb = j >> 9;
    float raw;
    if (bb < 4) raw = zx[(size_t)(bb * 64 + l) * DPROJ + 1152 + h];
    else        raw = zx[(size_t)((bb - 4) * 64 + (63 - l)) * DPROJ + 1160 + h];
    const float d = raw + dtbias[h];
    const float sp = (d > 20.f) ? d : log1pf(expf(d));
    dt2[j] = sp;
    dA2[j] = expf(sp * -expf(Alog[h]));
  }
}

// ---------------------------------------------------------------------------
// K5: bidirectional SSM scan (fp32).
__global__ __launch_bounds__(256) void k_scan(
    const float* __restrict__ xbc, const float* __restrict__ dt2, const float* __restrict__ dA2,
    float* __restrict__ ys) {
  const int blk = blockIdx.x;
  const int pg = blk & 3;
  const int h = (blk >> 2) & 7;
  const int bb = blk >> 5;
  const int wv = threadIdx.x >> 6, lane = threadIdx.x & 63;
  const int pbase = pg * 16 + wv * 4;
  const int b = (bb < 4) ? bb : bb - 4;
  const bool rev = bb >= 4;
  float st[4] = {0.f, 0.f, 0.f, 0.f};
  for (int t = 0; t < 64; ++t) {
    const int l = rev ? 63 - t : t;
    const float* row = xbc + (size_t)(b * 64 + l) * CONVD;
    const float bv = row[DIN + lane];
    const float cv = row[DIN + 64 + lane];
    const float dtv = dt2[(bb * 64 + t) * 8 + h];
    const float dav = dA2[(bb * 64 + t) * 8 + h];
#pragma unroll
    for (int j = 0; j < 4; ++j) {
      const float xval = row[h * 64 + pbase + j];
      const float s = st[j] * dav + dtv * xval * bv;
      st[j] = s;
      float pr = s * cv;
#pragma unroll
      for (int off = 32; off; off >>= 1) pr += __shfl_xor(pr, off);
      if (lane == 0) ys[(((size_t)(bb * 64 + t) * 8 + h) << 6) + pbase + j] = pr;
    }
  }
}

// ---------------------------------------------------------------------------
// K6a: combine + gate + RMS norm (fp32).
__global__ __launch_bounds__(256) void k_gate(
    const float* __restrict__ ys, const float* __restrict__ xbc, const float* __restrict__ zx,
    const float* __restrict__ fcdw, const float* __restrict__ Dp,
    const float* __restrict__ normw, float* __restrict__ yg) {
  __shared__ float red[256][9];
  __shared__ float s_xfc[8];
  const int bl = blockIdx.x;
  const int b = bl >> 6, l = bl & 63;
  const int tid = threadIdx.x;
  const float xog0 = xbc[(size_t)bl * CONVD + tid];
  const float xog1 = xbc[(size_t)bl * CONVD + 256 + tid];
#pragma unroll
  for (int h = 0; h < 8; ++h)
    red[tid][h] = xog0 * fcdw[h * DIN + tid] + xog1 * fcdw[h * DIN + 256 + tid];
  __syncthreads();
  for (int s = 128; s > 0; s >>= 1) {
    if (tid < s) {
#pragma unroll
      for (int h = 0; h < 8; ++h) red[tid][h] += red[tid + s][h];
    }
    __syncthreads();
  }
  if (tid < 8) s_xfc[tid] = red[0][tid] + Dp[tid];
  __syncthreads();
  float ygv[2];
  float sumsq = 0.f;
#pragma unroll
  for (int ci = 0; ci < 2; ++ci) {
    const int c = tid + ci * 256;
    const int h = c >> 6, p = c & 63;
    float yv = 0.f;
    if (l >= 1)  yv += ys[(((size_t)(b * 64 + (l - 1)) * 8 + h) << 6) + p];
    if (l <= 62) yv += ys[(((size_t)((4 + b) * 64 + (62 - l)) * 8 + h) << 6) + p];
    const float xog = (ci == 0) ? xog0 : xog1;
    yv += xog * s_xfc[h];
    const float z = zx[(size_t)bl * DPROJ + c];
    const float g = yv * (z * sigmoidf_(z));
    ygv[ci] = g;
    sumsq += g * g;
  }
  red[tid][0] = sumsq;
  __syncthreads();
  for (int s = 128; s > 0; s >>= 1) {
    if (tid < s) red[tid][0] += red[tid + s][0];
    __syncthreads();
  }
  const float scale = 1.f / sqrtf(red[0][0] / 512.f + 1e-5f);
#pragma unroll
  for (int ci = 0; ci < 2; ++ci) {
    const int c = tid + ci * 256;
    yg[(size_t)bl * DIN + c] = ygv[ci] * scale * normw[c];
  }
}

// ---------------------------------------------------------------------------
// K6b: ot = yg (256x512) @ hy_out_w^T; epilogue writes otT bf16 [(b,h,p)][g].
__global__ __launch_bounds__(256) void k_oproj(
    const float* __restrict__ yg, const float* __restrict__ how, unsigned short* __restrict__ otT) {
  __shared__ float at[64][65];
  __shared__ float bt[64][65];
  const int r0 = blockIdx.x * 64;
  const int c0 = blockIdx.y * 64;
  const int tid = threadIdx.x;
  const int i0 = (tid >> 4) << 2, j0 = (tid & 15) << 2;
  const int lrow = tid >> 2, lcol = (tid & 3) << 4;
  float acc[4][4] = {};
  for (int k0 = 0; k0 < DIN; k0 += 64) {
    const float* asrc = yg + (size_t)(r0 + lrow) * DIN + k0 + lcol;
    const float* wsrc = how + (size_t)(c0 + lrow) * DIN + k0 + lcol;
#pragma unroll
    for (int u = 0; u < 16; ++u) at[lrow][lcol + u] = asrc[u];
#pragma unroll
    for (int u = 0; u < 16; ++u) bt[lcol + u][lrow] = wsrc[u];
    __syncthreads();
#pragma unroll
    for (int kk = 0; kk < 64; ++kk) {
      float av[4], bv[4];
#pragma unroll
      for (int i = 0; i < 4; ++i) av[i] = at[i0 + i][kk];
#pragma unroll
      for (int j2 = 0; j2 < 4; ++j2) bv[j2] = bt[kk][j0 + j2];
#pragma unroll
      for (int i = 0; i < 4; ++i)
#pragma unroll
        for (int j2 = 0; j2 < 4; ++j2) acc[i][j2] += av[i] * bv[j2];
    }
    __syncthreads();
  }
#pragma unroll
  for (int i = 0; i < 4; ++i)
#pragma unroll
    for (int j2 = 0; j2 < 4; ++j2) {
      const int r = r0 + i0 + i;   // b*64+g
      const int c = c0 + j0 + j2;  // h*64+p
      otT[(((size_t)((r >> 6) * 8 + (c >> 6)) * 64 + (c & 63)) << 6) + (r & 63)] = f2b(acc[i][j2]);
    }
}

// ---------------------------------------------------------------------------
// K7: inter[b,n,h*64+p] = sum_g sw[bh,n,g]*otT[bh,p,g]. MFMA bf16. grid (32 mtile, 32 bh).
__global__ __launch_bounds__(256) void k_mix(
    const unsigned short* __restrict__ swb, const unsigned short* __restrict__ otT,
    unsigned short* __restrict__ interb) {
  __shared__ unsigned short As[8 * 256 * 8];  // [kb][n(256)][8]
  __shared__ unsigned short Bs[8 * 64 * 8];   // [kb][p(64)][8]
  const int tid = threadIdx.x;
  const int bh = blockIdx.y;
  const int b = bh >> 3, h = bh & 7;
  const int n0 = blockIdx.x * 256;
  const int w = tid >> 6, lane = tid & 63;
  const int l15 = lane & 15, kq = lane >> 4;
#pragma unroll
  for (int i = 0; i < 8; ++i) {
    const int c = tid + 256 * i, m = c >> 3, kb = c & 7;
    *(short8*)&As[(kb * 256 + m) * 8] = *(const short8*)&swb[((size_t)bh * NTOK + n0 + m) * 64 + kb * 8];
  }
#pragma unroll
  for (int i = 0; i < 2; ++i) {
    const int c = tid + 256 * i, p = c >> 3, kb = c & 7;
    *(short8*)&Bs[(kb * 64 + p) * 8] = *(const short8*)&otT[((size_t)bh * 64 + p) * 64 + kb * 8];
  }
  __syncthreads();
  f32x4 acc[4][4];
#pragma unroll
  for (int i = 0; i < 4; ++i)
#pragma unroll
    for (int j = 0; j < 4; ++j) acc[i][j] = (f32x4){0.f, 0.f, 0.f, 0.f};
#pragma unroll
  for (int kw = 0; kw < 2; ++kw) {
    short8 af[4], bfr[4];
#pragma unroll
    for (int i = 0; i < 4; ++i) {
      af[i]  = *(const short8*)&As[((kw * 4 + kq) * 256 + w * 64 + i * 16 + l15) * 8];
      bfr[i] = *(const short8*)&Bs[((kw * 4 + kq) * 64 + i * 16 + l15) * 8];
    }
#pragma unroll
    for (int i = 0; i < 4; ++i)
#pragma unroll
      for (int j = 0; j < 4; ++j)
        acc[i][j] = __builtin_amdgcn_mfma_f32_16x16x32_bf16(af[i], bfr[j], acc[i][j], 0, 0, 0);
  }
#pragma unroll
  for (int i = 0; i < 4; ++i)
#pragma unroll
    for (int j = 0; j < 4; ++j)
#pragma unroll
      for (int r = 0; r < 4; ++r) {
        const int n = n0 + w * 64 + i * 16 + kq * 4 + r;
        const int col = h * 64 + j * 16 + l15;
        interb[(size_t)(b * NTOK + n) * DIN + col] = f2b(acc[i][j][r]);
      }
}

// ---------------------------------------------------------------------------
// K8: out = inter (32768x512 bf16) @ out_w^T (256x512 bf16) + out_b. MFMA.
__global__ __launch_bounds__(256) void k_final(
    const unsigned short* __restrict__ interb, const unsigned short* __restrict__ outwb,
    const float* __restrict__ outb, float* __restrict__ out) {
  __shared__ unsigned short As[8 * 128 * 8];
  __shared__ unsigned short Bs[8 * 128 * 8];
  const int tid = threadIdx.x;
  const int m0 = blockIdx.x * 128;
  const int n0 = blockIdx.y * 128;
  const int w = tid >> 6, lane = tid & 63;
  const int l15 = lane & 15, kq = lane >> 4;
  const int wm = (w & 1) * 64, wn = (w >> 1) * 64;
  f32x4 acc[4][4];
#pragma unroll
  for (int i = 0; i < 4; ++i)
#pragma unroll
    for (int j = 0; j < 4; ++j) acc[i][j] = (f32x4){0.f, 0.f, 0.f, 0.f};
  for (int kt = 0; kt < DIN; kt += 64) {
#pragma unroll
    for (int i = 0; i < 4; ++i) {
      const int c = tid + 256 * i, m = c >> 3, kb = c & 7;
      *(short8*)&As[(kb * 128 + m) * 8] = *(const short8*)&interb[(size_t)(m0 + m) * DIN + kt + kb * 8];
      *(short8*)&Bs[(kb * 128 + m) * 8] = *(const short8*)&outwb[(size_t)(n0 + m) * DIN + kt + kb * 8];
    }
    __syncthreads();
#pragma unroll
    for (int kw = 0; kw < 2; ++kw) {
      short8 af[4], bfr[4];
#pragma unroll
      for (int i = 0; i < 4; ++i) {
        af[i]  = *(const short8*)&As[((kw * 4 + kq) * 128 + wm + i * 16 + l15) * 8];
        bfr[i] = *(const short8*)&Bs[((kw * 4 + kq) * 128 + wn + i * 16 + l15) * 8];
      }
#pragma unroll
      for (int i = 0; i < 4; ++i)
#pragma unroll
        for (int j = 0; j < 4; ++j)
          acc[i][j] = __builtin_amdgcn_mfma_f32_16x16x32_bf16(af[i], bfr[j], acc[i][j], 0, 0, 0);
    }
    __syncthreads();
  }
#pragma unroll
  for (int i = 0; i < 4; ++i)
#pragma unroll
    for (int j = 0; j < 4; ++j)
#pragma unroll
      for (int r = 0; r < 4; ++r) {
        const int R = m0 + wm + i * 16 + kq * 4 + r;
        const int C = n0 + wn + j * 16 + l15;
        out[(size_t)R * DIM + C] = acc[i][j][r] + outb[C];
      }
}

// ---------------------------------------------------------------------------
extern "C" void kernel_launch(void* const* d_in, const int* in_sizes, int n_in,
                              void* d_out, int out_size, void* d_ws, size_t ws_size,
                              hipStream_t stream) {
  const float* x      = (const float*)d_in[0];
  const float* Wfx    = (const float*)d_in[1];
  const float* bfx    = (const float*)d_in[2];
  const float* Wx     = (const float*)d_in[3];
  const float* bx     = (const float*)d_in[4];
  const float* Wslice = (const float*)d_in[5];
  const float* bslice = (const float*)d_in[6];
  const float* temp   = (const float*)d_in[7];
  const float* inw    = (const float*)d_in[8];
  const float* convw  = (const float*)d_in[9];
  const float* convb  = (const float*)d_in[10];
  const float* dtbias = (const float*)d_in[11];
  const float* Alog   = (const float*)d_in[12];
  const float* Dp     = (const float*)d_in[13];
  const float* fcdw   = (const float*)d_in[14];
  const float* normw  = (const float*)d_in[15];
  const float* how    = (const float*)d_in[16];
  const float* outw   = (const float*)d_in[17];
  const float* outb   = (const float*)d_in[18];

  float* ws = (float*)d_ws;
  float*          xm     = ws;                                  // 16,777,216 f
  unsigned short* fxb    = (unsigned short*)(ws + 16777216);    // 16,777,216 us
  unsigned short* swb    = (unsigned short*)(ws + 25165824);    // 16,777,216 us
  unsigned short* interb = (unsigned short*)(ws + 33554432);    // 16,777,216 us
  unsigned short* xbfb   = (unsigned short*)(ws + 41943040);    //  8,388,608 us
  unsigned short* wcatb  = (unsigned short*)(ws + 46137344);    //    262,144 us
  unsigned short* outwbf = (unsigned short*)(ws + 46268416);    //    131,072 us
  unsigned short* otTb   = (unsigned short*)(ws + 46333952);    //    131,072 us
  float*          st_raw = ws + 46399488;                       //    131,072 f
  float*          snorm  = ws + 46530560;                       //      2,048 f
  float*          st2    = ws + 46532608;                       //    131,072 f
  float*          zx     = ws + 46663680;                       //    299,008 f
  float*          xbc    = ws + 46962688;                       //    163,840 f
  float*          dt2    = ws + 47126528;                       //      4,096 f
  float*          dA2    = ws + 47130624;                       //      4,096 f
  float*          ysb    = ws + 47134720;                       //    262,144 f
  float*          ygb    = ws + 47396864;                       //    131,072 f

  hipMemsetAsync(st_raw, 0, (131072 + 2048) * sizeof(float), stream);

  k_cvt   <<<dim3(8576),     256, 0, stream>>>(x, Wfx, Wx, outw, xbfb, wcatb, outwbf);
  k_fxxm  <<<dim3(256, 8),   256, 0, stream>>>(xbfb, wcatb, bfx, bx, fxb, xm);
  k_sw    <<<dim3(65536),    256, 0, stream>>>(xm, Wslice, bslice, temp, swb);
  k_st    <<<dim3(16, 32),   256, 0, stream>>>(swb, fxb, st_raw, snorm);
  k_stnorm<<<dim3(512),      256, 0, stream>>>(st_raw, snorm, st2);
  k_inproj<<<dim3(4, 19),    256, 0, stream>>>(st2, inw, zx);
  k_prep  <<<dim3(656),      256, 0, stream>>>(zx, convw, convb, dtbias, Alog, xbc, dt2, dA2);
  k_scan  <<<dim3(256),      256, 0, stream>>>(xbc, dt2, dA2, ysb);
  k_gate  <<<dim3(256),      256, 0, stream>>>(ysb, xbc, zx, fcdw, Dp, normw, ygb);
  k_oproj <<<dim3(4, 8),     256, 0, stream>>>(ygb, how, otTb);
  k_mix   <<<dim3(32, 32),   256, 0, stream>>>(swb, otTb, interb);
  k_final <<<dim3(256, 2),   256, 0, stream>>>(interb, outwbf, outb, (float*)d_out);
}

// Round 3
// 457.135 us; speedup vs baseline: 2.6487x; 1.5829x over previous
//
#include <hip/hip_runtime.h>
#include <hip/hip_bf16.h>
#include <cstdint>
#include <cstddef>

#define Hh 8
#define DIN 512
#define CONVD 640
#define DPROJ 1168
#define NTOK 8192
#define DIM 256

typedef __attribute__((ext_vector_type(8))) short short8;
typedef __attribute__((ext_vector_type(4))) float f32x4;

static __device__ __forceinline__ float sigmoidf_(float x) { return 1.f / (1.f + expf(-x)); }
static __device__ __forceinline__ unsigned short f2b(float f) {
  __hip_bfloat16 h = __float2bfloat16(f);
  return *(unsigned short*)&h;
}
static __device__ __forceinline__ float b2f(unsigned short u) {
  union { unsigned int i; float f; } cv; cv.i = ((unsigned int)u) << 16; return cv.f;
}

// ---------------------------------------------------------------------------
// K0: fp32 -> bf16 conversions: x (8388608), Wfx|Wx -> wcat (262144), outw (131072)
__global__ __launch_bounds__(256) void k_cvt(
    const float* __restrict__ x, const float* __restrict__ wfx, const float* __restrict__ wx,
    const float* __restrict__ outw, unsigned short* __restrict__ xb,
    unsigned short* __restrict__ wcat, unsigned short* __restrict__ outwb) {
  const int e = (blockIdx.x * 256 + threadIdx.x) * 4;
  const float* src; unsigned short* dst; int i;
  if (e < 8388608)       { i = e;           src = x;    dst = xb; }
  else if (e < 8519680)  { i = e - 8388608; src = wfx;  dst = wcat; }
  else if (e < 8650752)  { i = e - 8519680; src = wx;   dst = wcat + 131072; }
  else                   { i = e - 8650752; src = outw; dst = outwb; }
  float4 v = *(const float4*)(src + i);
  ushort4 o;
  o.x = f2b(v.x); o.y = f2b(v.y); o.z = f2b(v.z); o.w = f2b(v.w);
  *(ushort4*)(dst + i) = o;
}

// ---------------------------------------------------------------------------
// K1: [fx|xm] = x @ [W_fx|W_x]^T (+bias). MFMA bf16. M=32768, N=1024, K=256.
// fx -> bf16 (b,h,n,p); xm -> bf16 token-major (b*n, 512).
__global__ __launch_bounds__(256) void k_fxxm(
    const unsigned short* __restrict__ xb, const unsigned short* __restrict__ wcat,
    const float* __restrict__ bfx, const float* __restrict__ bx,
    unsigned short* __restrict__ fxb, unsigned short* __restrict__ xmb) {
  __shared__ unsigned short As[8 * 128 * 8];  // [kb][m][8]
  __shared__ unsigned short Bs[8 * 128 * 8];
  const int tid = threadIdx.x;
  const int m0 = blockIdx.x * 128;
  const int n0 = blockIdx.y * 128;
  const int w = tid >> 6, lane = tid & 63;
  const int l15 = lane & 15, kq = lane >> 4;
  const int wm = (w & 1) * 64, wn = (w >> 1) * 64;
  f32x4 acc[4][4];
#pragma unroll
  for (int i = 0; i < 4; ++i)
#pragma unroll
    for (int j = 0; j < 4; ++j) acc[i][j] = (f32x4){0.f, 0.f, 0.f, 0.f};
  for (int kt = 0; kt < 256; kt += 64) {
#pragma unroll
    for (int i = 0; i < 4; ++i) {
      const int c = tid + 256 * i, m = c >> 3, kb = c & 7;
      *(short8*)&As[(kb * 128 + m) * 8] = *(const short8*)&xb[(size_t)(m0 + m) * 256 + kt + kb * 8];
      *(short8*)&Bs[(kb * 128 + m) * 8] = *(const short8*)&wcat[(size_t)(n0 + m) * 256 + kt + kb * 8];
    }
    __syncthreads();
#pragma unroll
    for (int kw = 0; kw < 2; ++kw) {
      short8 af[4], bfr[4];
#pragma unroll
      for (int i = 0; i < 4; ++i) {
        af[i]  = *(const short8*)&As[((kw * 4 + kq) * 128 + wm + i * 16 + l15) * 8];
        bfr[i] = *(const short8*)&Bs[((kw * 4 + kq) * 128 + wn + i * 16 + l15) * 8];
      }
#pragma unroll
      for (int i = 0; i < 4; ++i)
#pragma unroll
        for (int j = 0; j < 4; ++j)
          acc[i][j] = __builtin_amdgcn_mfma_f32_16x16x32_bf16(af[i], bfr[j], acc[i][j], 0, 0, 0);
    }
    __syncthreads();
  }
#pragma unroll
  for (int i = 0; i < 4; ++i)
#pragma unroll
    for (int j = 0; j < 4; ++j)
#pragma unroll
      for (int r = 0; r < 4; ++r) {
        const int R = m0 + wm + i * 16 + kq * 4 + r;
        const int C = n0 + wn + j * 16 + l15;
        float v = acc[i][j][r];
        if (C < DIN) {
          v += bfx[C];
          const int b = R >> 13, n = R & (NTOK - 1), h = C >> 6, p = C & 63;
          fxb[(((size_t)(b * Hh + h) * NTOK + n) << 6) + p] = f2b(v);
        } else {
          xmb[(size_t)R * DIN + (C - DIN)] = f2b(v + bx[C - DIN]);
        }
      }
}

// ---------------------------------------------------------------------------
// K2: fused score-GEMM + softmax. Per block: 256 tokens of one (b,h).
// scores = xm_h (bf16) @ Wslice^T via MFMA; softmax over g in C-layout;
// coalesced bf16 output via LDS staging.
__global__ __launch_bounds__(256) void k_sw(
    const unsigned short* __restrict__ xmb, const float* __restrict__ Wslice,
    const float* __restrict__ bslice, const float* __restrict__ temperature,
    unsigned short* __restrict__ swb) {
  __shared__ unsigned short s_sw[256][72];
  const int tid = threadIdx.x;
  const int bh = blockIdx.y;
  const int b = bh >> 3, h = bh & 7;
  const int n0 = blockIdx.x * 256;
  const int w = tid >> 6, lane = tid & 63;
  const int l15 = lane & 15, kq = lane >> 4;
  const float invt = 1.f / fmaxf(temperature[h], 1e-6f);
  // B fragments: B[g = j*16+l15][k = kt*32 + kq*8 + u]
  short8 bfr[2][4];
#pragma unroll
  for (int kt = 0; kt < 2; ++kt)
#pragma unroll
    for (int j = 0; j < 4; ++j) {
      const float* wp = Wslice + (j * 16 + l15) * 64 + kt * 32 + kq * 8;
      short8 t;
#pragma unroll
      for (int u = 0; u < 8; ++u) t[u] = (short)f2b(wp[u]);
      bfr[kt][j] = t;
    }
  float bs[4];
#pragma unroll
  for (int j = 0; j < 4; ++j) bs[j] = bslice[j * 16 + l15];
  f32x4 acc[4][4];
#pragma unroll
  for (int i = 0; i < 4; ++i)
#pragma unroll
    for (int j = 0; j < 4; ++j) acc[i][j] = (f32x4){0.f, 0.f, 0.f, 0.f};
#pragma unroll
  for (int kt = 0; kt < 2; ++kt) {
    short8 af[4];
#pragma unroll
    for (int i = 0; i < 4; ++i)
      af[i] = *(const short8*)&xmb[((size_t)(b * NTOK) + n0 + w * 64 + i * 16 + l15) * DIN +
                                   h * 64 + kt * 32 + kq * 8];
#pragma unroll
    for (int i = 0; i < 4; ++i)
#pragma unroll
      for (int j = 0; j < 4; ++j)
        acc[i][j] = __builtin_amdgcn_mfma_f32_16x16x32_bf16(af[i], bfr[kt][j], acc[i][j], 0, 0, 0);
  }
  // softmax per token row (fixed i, r): values spread over j (x4) and 16 col-lanes
#pragma unroll
  for (int i = 0; i < 4; ++i)
#pragma unroll
    for (int r = 0; r < 4; ++r) {
      float v[4];
      float m = -1e30f;
#pragma unroll
      for (int j = 0; j < 4; ++j) { v[j] = (acc[i][j][r] + bs[j]) * invt; m = fmaxf(m, v[j]); }
#pragma unroll
      for (int off = 8; off; off >>= 1) m = fmaxf(m, __shfl_xor(m, off));
      float s = 0.f;
#pragma unroll
      for (int j = 0; j < 4; ++j) { v[j] = expf(v[j] - m); s += v[j]; }
#pragma unroll
      for (int off = 8; off; off >>= 1) s += __shfl_xor(s, off);
      const float inv = 1.f / s;
      const int row = w * 64 + i * 16 + kq * 4 + r;
#pragma unroll
      for (int j = 0; j < 4; ++j) s_sw[row][j * 16 + l15] = f2b(v[j] * inv);
    }
  __syncthreads();
#pragma unroll
  for (int it = 0; it < 8; ++it) {
    const int c = tid + 256 * it;
    const int row = c >> 3, seg = c & 7;
    *(short8*)&swb[((size_t)bh * NTOK + n0 + row) * 64 + seg * 8] =
        *(const short8*)&s_sw[row][seg * 8];
  }
}

// ---------------------------------------------------------------------------
// K3: st_raw[bh][g][p] = sum_n sw[n,g]*fx[n,p]; snorm[bh][g] = sum_n sw[n,g].
__global__ __launch_bounds__(256) void k_st(
    const unsigned short* __restrict__ swb, const unsigned short* __restrict__ fxb,
    float* __restrict__ st_raw, float* __restrict__ snorm) {
  __shared__ unsigned short swT[64][136];
  __shared__ unsigned short fxT[64][136];
  const int tid = threadIdx.x;
  const int bh = blockIdx.y;
  const int nbase = blockIdx.x * 512;
  const int w = tid >> 6, lane = tid & 63;
  const int l15 = lane & 15, kq = lane >> 4;
  f32x4 acc[4];
#pragma unroll
  for (int i = 0; i < 4; ++i) acc[i] = (f32x4){0.f, 0.f, 0.f, 0.f};
  float sn = 0.f;
  for (int nc = 0; nc < 4; ++nc) {
    const int n0 = nbase + nc * 128;
#pragma unroll
    for (int i = 0; i < 4; ++i) {
      const int c = tid + 256 * i, n = c >> 3, gc = c & 7;
      short8 sv = *(const short8*)&swb[((size_t)bh * NTOK + n0 + n) * 64 + gc * 8];
      short8 fv = *(const short8*)&fxb[((size_t)bh * NTOK + n0 + n) * 64 + gc * 8];
#pragma unroll
      for (int u = 0; u < 8; ++u) {
        swT[gc * 8 + u][n] = (unsigned short)sv[u];
        fxT[gc * 8 + u][n] = (unsigned short)fv[u];
      }
    }
    __syncthreads();
    {
      const int g = tid & 63, q = tid >> 6;
#pragma unroll
      for (int nn = 0; nn < 32; ++nn) sn += b2f(swT[g][q * 32 + nn]);
    }
#pragma unroll
    for (int kw = 0; kw < 4; ++kw) {
      short8 bfr = *(const short8*)&fxT[w * 16 + l15][kw * 32 + kq * 8];
#pragma unroll
      for (int mi = 0; mi < 4; ++mi) {
        short8 af = *(const short8*)&swT[mi * 16 + l15][kw * 32 + kq * 8];
        acc[mi] = __builtin_amdgcn_mfma_f32_16x16x32_bf16(af, bfr, acc[mi], 0, 0, 0);
      }
    }
    __syncthreads();
  }
  float* stp = st_raw + (size_t)bh * 4096;
#pragma unroll
  for (int mi = 0; mi < 4; ++mi)
#pragma unroll
    for (int r = 0; r < 4; ++r)
      atomicAdd(&stp[(mi * 16 + kq * 4 + r) * 64 + w * 16 + l15], acc[mi][r]);
  atomicAdd(&snorm[bh * 64 + (tid & 63)], sn);
}

// ---------------------------------------------------------------------------
// K3b: st2[b,g,h*64+p] = st_raw[b,h,g,p] / (snorm[b,h,g] + 1e-5)
__global__ __launch_bounds__(256) void k_stnorm(
    const float* __restrict__ st_raw, const float* __restrict__ snorm, float* __restrict__ st2) {
  const int idx = blockIdx.x * 256 + threadIdx.x;
  const int p = idx & 63, g = (idx >> 6) & 63, h = (idx >> 12) & 7, b = idx >> 15;
  const float v = st_raw[idx] / (snorm[(b * Hh + h) * 64 + g] + 1e-5f);
  st2[(size_t)(b * 64 + g) * DIN + h * 64 + p] = v;
}

// ---------------------------------------------------------------------------
// K4: zx = st2 (256x512) @ hy_in_w^T (512->1168). fp32 (tiny).
__global__ __launch_bounds__(256) void k_inproj(
    const float* __restrict__ st2, const float* __restrict__ inw, float* __restrict__ zx) {
  __shared__ float at[64][65];
  __shared__ float bt[64][65];
  const int r0 = blockIdx.x * 64;
  const int c0 = blockIdx.y * 64;
  const int tid = threadIdx.x;
  const int i0 = (tid >> 4) << 2, j0 = (tid & 15) << 2;
  const int lrow = tid >> 2, lcol = (tid & 3) << 4;
  float acc[4][4] = {};
  for (int k0 = 0; k0 < DIN; k0 += 64) {
    const float* asrc = st2 + (size_t)(r0 + lrow) * DIN + k0 + lcol;
    const int j = c0 + lrow;
    const bool jok = j < DPROJ;
    const float* wsrc = inw + (size_t)(jok ? j : 0) * DIN + k0 + lcol;
#pragma unroll
    for (int u = 0; u < 16; ++u) at[lrow][lcol + u] = asrc[u];
#pragma unroll
    for (int u = 0; u < 16; ++u) bt[lcol + u][lrow] = jok ? wsrc[u] : 0.f;
    __syncthreads();
#pragma unroll
    for (int kk = 0; kk < 64; ++kk) {
      float av[4], bv[4];
#pragma unroll
      for (int i = 0; i < 4; ++i) av[i] = at[i0 + i][kk];
#pragma unroll
      for (int j2 = 0; j2 < 4; ++j2) bv[j2] = bt[kk][j0 + j2];
#pragma unroll
      for (int i = 0; i < 4; ++i)
#pragma unroll
        for (int j2 = 0; j2 < 4; ++j2) acc[i][j2] += av[i] * bv[j2];
    }
    __syncthreads();
  }
#pragma unroll
  for (int i = 0; i < 4; ++i)
#pragma unroll
    for (int j2 = 0; j2 < 4; ++j2) {
      const int c = c0 + j0 + j2;
      if (c < DPROJ) zx[(size_t)(r0 + i0 + i) * DPROJ + c] = acc[i][j2];
    }
}

// ---------------------------------------------------------------------------
// K4b: conv(k=3)+silu; dt2/dA2.
__global__ __launch_bounds__(256) void k_prep(
    const float* __restrict__ zx, const float* __restrict__ convw, const float* __restrict__ convb,
    const float* __restrict__ dtbias, const float* __restrict__ Alog,
    float* __restrict__ xbc, float* __restrict__ dt2, float* __restrict__ dA2) {
  const int idx = blockIdx.x * 256 + threadIdx.x;
  const int NCONV = 4 * 64 * CONVD;
  if (idx < NCONV) {
    const int c = idx % CONVD;
    const int l = (idx / CONVD) & 63;
    const int b = idx / (CONVD * 64);
    float acc = convb[c];
#pragma unroll
    for (int k = 0; k < 3; ++k) {
      const int ls = l - 2 + k;
      if (ls >= 0) acc += zx[(size_t)(b * 64 + ls) * DPROJ + DIN + c] * convw[c * 3 + k];
    }
    xbc[idx] = acc * sigmoidf_(acc);
  } else if (idx < NCONV + 8 * 64 * 8) {
    const int j = idx - NCONV;
    const int h = j & 7, l = (j >> 3) & 63, bb = j >> 9;
    float raw;
    if (bb < 4) raw = zx[(size_t)(bb * 64 + l) * DPROJ + 1152 + h];
    else        raw = zx[(size_t)((bb - 4) * 64 + (63 - l)) * DPROJ + 1160 + h];
    const float d = raw + dtbias[h];
    const float sp = (d > 20.f) ? d : log1pf(expf(d));
    dt2[j] = sp;
    dA2[j] = expf(sp * -expf(Alog[h]));
  }
}

// ---------------------------------------------------------------------------
// K5: bidirectional SSM scan (fp32).
__global__ __launch_bounds__(256) void k_scan(
    const float* __restrict__ xbc, const float* __restrict__ dt2, const float* __restrict__ dA2,
    float* __restrict__ ys) {
  const int blk = blockIdx.x;
  const int pg = blk & 3;
  const int h = (blk >> 2) & 7;
  const int bb = blk >> 5;
  const int wv = threadIdx.x >> 6, lane = threadIdx.x & 63;
  const int pbase = pg * 16 + wv * 4;
  const int b = (bb < 4) ? bb : bb - 4;
  const bool rev = bb >= 4;
  float st[4] = {0.f, 0.f, 0.f, 0.f};
  for (int t = 0; t < 64; ++t) {
    const int l = rev ? 63 - t : t;
    const float* row = xbc + (size_t)(b * 64 + l) * CONVD;
    const float bv = row[DIN + lane];
    const float cv = row[DIN + 64 + lane];
    const float dtv = dt2[(bb * 64 + t) * 8 + h];
    const float dav = dA2[(bb * 64 + t) * 8 + h];
#pragma unroll
    for (int j = 0; j < 4; ++j) {
      const float xval = row[h * 64 + pbase + j];
      const float s = st[j] * dav + dtv * xval * bv;
      st[j] = s;
      float pr = s * cv;
#pragma unroll
      for (int off = 32; off; off >>= 1) pr += __shfl_xor(pr, off);
      if (lane == 0) ys[(((size_t)(bb * 64 + t) * 8 + h) << 6) + pbase + j] = pr;
    }
  }
}

// ---------------------------------------------------------------------------
// K6a: combine + gate + RMS norm (fp32).
__global__ __launch_bounds__(256) void k_gate(
    const float* __restrict__ ys, const float* __restrict__ xbc, const float* __restrict__ zx,
    const float* __restrict__ fcdw, const float* __restrict__ Dp,
    const float* __restrict__ normw, float* __restrict__ yg) {
  __shared__ float red[256][9];
  __shared__ float s_xfc[8];
  const int bl = blockIdx.x;
  const int b = bl >> 6, l = bl & 63;
  const int tid = threadIdx.x;
  const float xog0 = xbc[(size_t)bl * CONVD + tid];
  const float xog1 = xbc[(size_t)bl * CONVD + 256 + tid];
#pragma unroll
  for (int h = 0; h < 8; ++h)
    red[tid][h] = xog0 * fcdw[h * DIN + tid] + xog1 * fcdw[h * DIN + 256 + tid];
  __syncthreads();
  for (int s = 128; s > 0; s >>= 1) {
    if (tid < s) {
#pragma unroll
      for (int h = 0; h < 8; ++h) red[tid][h] += red[tid + s][h];
    }
    __syncthreads();
  }
  if (tid < 8) s_xfc[tid] = red[0][tid] + Dp[tid];
  __syncthreads();
  float ygv[2];
  float sumsq = 0.f;
#pragma unroll
  for (int ci = 0; ci < 2; ++ci) {
    const int c = tid + ci * 256;
    const int h = c >> 6, p = c & 63;
    float yv = 0.f;
    if (l >= 1)  yv += ys[(((size_t)(b * 64 + (l - 1)) * 8 + h) << 6) + p];
    if (l <= 62) yv += ys[(((size_t)((4 + b) * 64 + (62 - l)) * 8 + h) << 6) + p];
    const float xog = (ci == 0) ? xog0 : xog1;
    yv += xog * s_xfc[h];
    const float z = zx[(size_t)bl * DPROJ + c];
    const float g = yv * (z * sigmoidf_(z));
    ygv[ci] = g;
    sumsq += g * g;
  }
  red[tid][0] = sumsq;
  __syncthreads();
  for (int s = 128; s > 0; s >>= 1) {
    if (tid < s) red[tid][0] += red[tid + s][0];
    __syncthreads();
  }
  const float scale = 1.f / sqrtf(red[0][0] / 512.f + 1e-5f);
#pragma unroll
  for (int ci = 0; ci < 2; ++ci) {
    const int c = tid + ci * 256;
    yg[(size_t)bl * DIN + c] = ygv[ci] * scale * normw[c];
  }
}

// ---------------------------------------------------------------------------
// K6b: ot = yg (256x512) @ hy_out_w^T; epilogue writes otT bf16 [(b,h,p)][g].
__global__ __launch_bounds__(256) void k_oproj(
    const float* __restrict__ yg, const float* __restrict__ how, unsigned short* __restrict__ otT) {
  __shared__ float at[64][65];
  __shared__ float bt[64][65];
  const int r0 = blockIdx.x * 64;
  const int c0 = blockIdx.y * 64;
  const int tid = threadIdx.x;
  const int i0 = (tid >> 4) << 2, j0 = (tid & 15) << 2;
  const int lrow = tid >> 2, lcol = (tid & 3) << 4;
  float acc[4][4] = {};
  for (int k0 = 0; k0 < DIN; k0 += 64) {
    const float* asrc = yg + (size_t)(r0 + lrow) * DIN + k0 + lcol;
    const float* wsrc = how + (size_t)(c0 + lrow) * DIN + k0 + lcol;
#pragma unroll
    for (int u = 0; u < 16; ++u) at[lrow][lcol + u] = asrc[u];
#pragma unroll
    for (int u = 0; u < 16; ++u) bt[lcol + u][lrow] = wsrc[u];
    __syncthreads();
#pragma unroll
    for (int kk = 0; kk < 64; ++kk) {
      float av[4], bv[4];
#pragma unroll
      for (int i = 0; i < 4; ++i) av[i] = at[i0 + i][kk];
#pragma unroll
      for (int j2 = 0; j2 < 4; ++j2) bv[j2] = bt[kk][j0 + j2];
#pragma unroll
      for (int i = 0; i < 4; ++i)
#pragma unroll
        for (int j2 = 0; j2 < 4; ++j2) acc[i][j2] += av[i] * bv[j2];
    }
    __syncthreads();
  }
#pragma unroll
  for (int i = 0; i < 4; ++i)
#pragma unroll
    for (int j2 = 0; j2 < 4; ++j2) {
      const int r = r0 + i0 + i;   // b*64+g
      const int c = c0 + j0 + j2;  // h*64+p
      otT[(((size_t)((r >> 6) * 8 + (c >> 6)) * 64 + (c & 63)) << 6) + (r & 63)] = f2b(acc[i][j2]);
    }
}

// ---------------------------------------------------------------------------
// K7: inter[b,n,h*64+p] = sum_g sw[bh,n,g]*otT[bh,p,g]. MFMA bf16.
__global__ __launch_bounds__(256) void k_mix(
    const unsigned short* __restrict__ swb, const unsigned short* __restrict__ otT,
    unsigned short* __restrict__ interb) {
  __shared__ unsigned short As[8 * 256 * 8];
  __shared__ unsigned short Bs[8 * 64 * 8];
  const int tid = threadIdx.x;
  const int bh = blockIdx.y;
  const int b = bh >> 3, h = bh & 7;
  const int n0 = blockIdx.x * 256;
  const int w = tid >> 6, lane = tid & 63;
  const int l15 = lane & 15, kq = lane >> 4;
#pragma unroll
  for (int i = 0; i < 8; ++i) {
    const int c = tid + 256 * i, m = c >> 3, kb = c & 7;
    *(short8*)&As[(kb * 256 + m) * 8] = *(const short8*)&swb[((size_t)bh * NTOK + n0 + m) * 64 + kb * 8];
  }
#pragma unroll
  for (int i = 0; i < 2; ++i) {
    const int c = tid + 256 * i, p = c >> 3, kb = c & 7;
    *(short8*)&Bs[(kb * 64 + p) * 8] = *(const short8*)&otT[((size_t)bh * 64 + p) * 64 + kb * 8];
  }
  __syncthreads();
  f32x4 acc[4][4];
#pragma unroll
  for (int i = 0; i < 4; ++i)
#pragma unroll
    for (int j = 0; j < 4; ++j) acc[i][j] = (f32x4){0.f, 0.f, 0.f, 0.f};
#pragma unroll
  for (int kw = 0; kw < 2; ++kw) {
    short8 af[4], bfr[4];
#pragma unroll
    for (int i = 0; i < 4; ++i) {
      af[i]  = *(const short8*)&As[((kw * 4 + kq) * 256 + w * 64 + i * 16 + l15) * 8];
      bfr[i] = *(const short8*)&Bs[((kw * 4 + kq) * 64 + i * 16 + l15) * 8];
    }
#pragma unroll
    for (int i = 0; i < 4; ++i)
#pragma unroll
      for (int j = 0; j < 4; ++j)
        acc[i][j] = __builtin_amdgcn_mfma_f32_16x16x32_bf16(af[i], bfr[j], acc[i][j], 0, 0, 0);
  }
#pragma unroll
  for (int i = 0; i < 4; ++i)
#pragma unroll
    for (int j = 0; j < 4; ++j)
#pragma unroll
      for (int r = 0; r < 4; ++r) {
        const int n = n0 + w * 64 + i * 16 + kq * 4 + r;
        const int col = h * 64 + j * 16 + l15;
        interb[(size_t)(b * NTOK + n) * DIN + col] = f2b(acc[i][j][r]);
      }
}

// ---------------------------------------------------------------------------
// K8: out = inter (32768x512 bf16) @ out_w^T (256x512 bf16) + out_b. MFMA.
__global__ __launch_bounds__(256) void k_final(
    const unsigned short* __restrict__ interb, const unsigned short* __restrict__ outwb,
    const float* __restrict__ outb, float* __restrict__ out) {
  __shared__ unsigned short As[8 * 128 * 8];
  __shared__ unsigned short Bs[8 * 128 * 8];
  const int tid = threadIdx.x;
  const int m0 = blockIdx.x * 128;
  const int n0 = blockIdx.y * 128;
  const int w = tid >> 6, lane = tid & 63;
  const int l15 = lane & 15, kq = lane >> 4;
  const int wm = (w & 1) * 64, wn = (w >> 1) * 64;
  f32x4 acc[4][4];
#pragma unroll
  for (int i = 0; i < 4; ++i)
#pragma unroll
    for (int j = 0; j < 4; ++j) acc[i][j] = (f32x4){0.f, 0.f, 0.f, 0.f};
  for (int kt = 0; kt < DIN; kt += 64) {
#pragma unroll
    for (int i = 0; i < 4; ++i) {
      const int c = tid + 256 * i, m = c >> 3, kb = c & 7;
      *(short8*)&As[(kb * 128 + m) * 8] = *(const short8*)&interb[(size_t)(m0 + m) * DIN + kt + kb * 8];
      *(short8*)&Bs[(kb * 128 + m) * 8] = *(const short8*)&outwb[(size_t)(n0 + m) * DIN + kt + kb * 8];
    }
    __syncthreads();
#pragma unroll
    for (int kw = 0; kw < 2; ++kw) {
      short8 af[4], bfr[4];
#pragma unroll
      for (int i = 0; i < 4; ++i) {
        af[i]  = *(const short8*)&As[((kw * 4 + kq) * 128 + wm + i * 16 + l15) * 8];
        bfr[i] = *(const short8*)&Bs[((kw * 4 + kq) * 128 + wn + i * 16 + l15) * 8];
      }
#pragma unroll
      for (int i = 0; i < 4; ++i)
#pragma unroll
        for (int j = 0; j < 4; ++j)
          acc[i][j] = __builtin_amdgcn_mfma_f32_16x16x32_bf16(af[i], bfr[j], acc[i][j], 0, 0, 0);
    }
    __syncthreads();
  }
#pragma unroll
  for (int i = 0; i < 4; ++i)
#pragma unroll
    for (int j = 0; j < 4; ++j)
#pragma unroll
      for (int r = 0; r < 4; ++r) {
        const int R = m0 + wm + i * 16 + kq * 4 + r;
        const int C = n0 + wn + j * 16 + l15;
        out[(size_t)R * DIM + C] = acc[i][j][r] + outb[C];
      }
}

// ---------------------------------------------------------------------------
extern "C" void kernel_launch(void* const* d_in, const int* in_sizes, int n_in,
                              void* d_out, int out_size, void* d_ws, size_t ws_size,
                              hipStream_t stream) {
  const float* x      = (const float*)d_in[0];
  const float* Wfx    = (const float*)d_in[1];
  const float* bfx    = (const float*)d_in[2];
  const float* Wx     = (const float*)d_in[3];
  const float* bx     = (const float*)d_in[4];
  const float* Wslice = (const float*)d_in[5];
  const float* bslice = (const float*)d_in[6];
  const float* temp   = (const float*)d_in[7];
  const float* inw    = (const float*)d_in[8];
  const float* convw  = (const float*)d_in[9];
  const float* convb  = (const float*)d_in[10];
  const float* dtbias = (const float*)d_in[11];
  const float* Alog   = (const float*)d_in[12];
  const float* Dp     = (const float*)d_in[13];
  const float* fcdw   = (const float*)d_in[14];
  const float* normw  = (const float*)d_in[15];
  const float* how    = (const float*)d_in[16];
  const float* outw   = (const float*)d_in[17];
  const float* outb   = (const float*)d_in[18];

  unsigned short* us = (unsigned short*)d_ws;
  unsigned short* fxb    = us;                   // 16,777,216
  unsigned short* xmb    = fxb + 16777216;       // 16,777,216
  unsigned short* swb    = xmb + 16777216;       // 16,777,216
  unsigned short* interb = swb + 16777216;       // 16,777,216
  unsigned short* xbfb   = interb + 16777216;    //  8,388,608
  unsigned short* wcatb  = xbfb + 8388608;       //    262,144
  unsigned short* outwbf = wcatb + 262144;       //    131,072
  unsigned short* otTb   = outwbf + 131072;      //    131,072
  float* fbase = (float*)(otTb + 131072);
  float* st_raw = fbase;                          //    131,072
  float* snorm  = st_raw + 131072;                //      2,048
  float* st2    = snorm + 2048;                   //    131,072
  float* zx     = st2 + 131072;                   //    299,008
  float* xbc    = zx + 299008;                    //    163,840
  float* dt2    = xbc + 163840;                   //      4,096
  float* dA2    = dt2 + 4096;                     //      4,096
  float* ysb    = dA2 + 4096;                     //    262,144
  float* ygb    = ysb + 262144;                   //    131,072

  hipMemsetAsync(st_raw, 0, (131072 + 2048) * sizeof(float), stream);

  k_cvt   <<<dim3(8576),     256, 0, stream>>>(x, Wfx, Wx, outw, xbfb, wcatb, outwbf);
  k_fxxm  <<<dim3(256, 8),   256, 0, stream>>>(xbfb, wcatb, bfx, bx, fxb, xmb);
  k_sw    <<<dim3(32, 32),   256, 0, stream>>>(xmb, Wslice, bslice, temp, swb);
  k_st    <<<dim3(16, 32),   256, 0, stream>>>(swb, fxb, st_raw, snorm);
  k_stnorm<<<dim3(512),      256, 0, stream>>>(st_raw, snorm, st2);
  k_inproj<<<dim3(4, 19),    256, 0, stream>>>(st2, inw, zx);
  k_prep  <<<dim3(656),      256, 0, stream>>>(zx, convw, convb, dtbias, Alog, xbc, dt2, dA2);
  k_scan  <<<dim3(256),      256, 0, stream>>>(xbc, dt2, dA2, ysb);
  k_gate  <<<dim3(256),      256, 0, stream>>>(ysb, xbc, zx, fcdw, Dp, normw, ygb);
  k_oproj <<<dim3(4, 8),     256, 0, stream>>>(ygb, how, otTb);
  k_mix   <<<dim3(32, 32),   256, 0, stream>>>(swb, otTb, interb);
  k_final <<<dim3(256, 2),   256, 0, stream>>>(interb, outwbf, outb, (float*)d_out);
}

// Round 4
// 388.302 us; speedup vs baseline: 3.1182x; 1.1773x over previous
//
#include <hip/hip_runtime.h>
#include <hip/hip_bf16.h>
#include <cstdint>
#include <cstddef>

#define Hh 8
#define DIN 512
#define CONVD 640
#define DPROJ 1168
#define NTOK 8192
#define DIM 256

typedef __attribute__((ext_vector_type(8))) short short8;
typedef __attribute__((ext_vector_type(4))) float f32x4;

static __device__ __forceinline__ float sigmoidf_(float x) { return 1.f / (1.f + expf(-x)); }
static __device__ __forceinline__ unsigned short f2b(float f) {
  __hip_bfloat16 h = __float2bfloat16(f);
  return *(unsigned short*)&h;
}
static __device__ __forceinline__ float b2f(unsigned short u) {
  union { unsigned int i; float f; } cv; cv.i = ((unsigned int)u) << 16; return cv.f;
}

// ---------------------------------------------------------------------------
// K0: fp32 -> bf16 conversions: x (8388608), Wfx|Wx -> wcat (262144), outw (131072)
__global__ __launch_bounds__(256) void k_cvt(
    const float* __restrict__ x, const float* __restrict__ wfx, const float* __restrict__ wx,
    const float* __restrict__ outw, unsigned short* __restrict__ xb,
    unsigned short* __restrict__ wcat, unsigned short* __restrict__ outwb) {
  const int e = (blockIdx.x * 256 + threadIdx.x) * 4;
  const float* src; unsigned short* dst; int i;
  if (e < 8388608)       { i = e;           src = x;    dst = xb; }
  else if (e < 8519680)  { i = e - 8388608; src = wfx;  dst = wcat; }
  else if (e < 8650752)  { i = e - 8519680; src = wx;   dst = wcat + 131072; }
  else                   { i = e - 8650752; src = outw; dst = outwb; }
  float4 v = *(const float4*)(src + i);
  ushort4 o;
  o.x = f2b(v.x); o.y = f2b(v.y); o.z = f2b(v.z); o.w = f2b(v.w);
  *(ushort4*)(dst + i) = o;
}

// ---------------------------------------------------------------------------
// K1: [fx|xm] = x @ [W_fx|W_x]^T (+bias). MFMA bf16. M=32768, N=1024, K=256.
__global__ __launch_bounds__(256) void k_fxxm(
    const unsigned short* __restrict__ xb, const unsigned short* __restrict__ wcat,
    const float* __restrict__ bfx, const float* __restrict__ bx,
    unsigned short* __restrict__ fxb, unsigned short* __restrict__ xmb) {
  __shared__ unsigned short As[8 * 128 * 8];  // [kb][m][8]
  __shared__ unsigned short Bs[8 * 128 * 8];
  const int tid = threadIdx.x;
  const int m0 = blockIdx.x * 128;
  const int n0 = blockIdx.y * 128;
  const int w = tid >> 6, lane = tid & 63;
  const int l15 = lane & 15, kq = lane >> 4;
  const int wm = (w & 1) * 64, wn = (w >> 1) * 64;
  f32x4 acc[4][4];
#pragma unroll
  for (int i = 0; i < 4; ++i)
#pragma unroll
    for (int j = 0; j < 4; ++j) acc[i][j] = (f32x4){0.f, 0.f, 0.f, 0.f};
  for (int kt = 0; kt < 256; kt += 64) {
#pragma unroll
    for (int i = 0; i < 4; ++i) {
      const int c = tid + 256 * i, m = c >> 3, kb = c & 7;
      *(short8*)&As[(kb * 128 + m) * 8] = *(const short8*)&xb[(size_t)(m0 + m) * 256 + kt + kb * 8];
      *(short8*)&Bs[(kb * 128 + m) * 8] = *(const short8*)&wcat[(size_t)(n0 + m) * 256 + kt + kb * 8];
    }
    __syncthreads();
#pragma unroll
    for (int kw = 0; kw < 2; ++kw) {
      short8 af[4], bfr[4];
#pragma unroll
      for (int i = 0; i < 4; ++i) {
        af[i]  = *(const short8*)&As[((kw * 4 + kq) * 128 + wm + i * 16 + l15) * 8];
        bfr[i] = *(const short8*)&Bs[((kw * 4 + kq) * 128 + wn + i * 16 + l15) * 8];
      }
#pragma unroll
      for (int i = 0; i < 4; ++i)
#pragma unroll
        for (int j = 0; j < 4; ++j)
          acc[i][j] = __builtin_amdgcn_mfma_f32_16x16x32_bf16(af[i], bfr[j], acc[i][j], 0, 0, 0);
    }
    __syncthreads();
  }
#pragma unroll
  for (int i = 0; i < 4; ++i)
#pragma unroll
    for (int j = 0; j < 4; ++j)
#pragma unroll
      for (int r = 0; r < 4; ++r) {
        const int R = m0 + wm + i * 16 + kq * 4 + r;
        const int C = n0 + wn + j * 16 + l15;
        float v = acc[i][j][r];
        if (C < DIN) {
          v += bfx[C];
          const int b = R >> 13, n = R & (NTOK - 1), h = C >> 6, p = C & 63;
          fxb[(((size_t)(b * Hh + h) * NTOK + n) << 6) + p] = f2b(v);
        } else {
          xmb[(size_t)R * DIN + (C - DIN)] = f2b(v + bx[C - DIN]);
        }
      }
}

// ---------------------------------------------------------------------------
// K2: fused score-GEMM + softmax (MFMA, softmax in C-layout).
__global__ __launch_bounds__(256) void k_sw(
    const unsigned short* __restrict__ xmb, const float* __restrict__ Wslice,
    const float* __restrict__ bslice, const float* __restrict__ temperature,
    unsigned short* __restrict__ swb) {
  __shared__ unsigned short s_sw[256][72];
  const int tid = threadIdx.x;
  const int bh = blockIdx.y;
  const int b = bh >> 3, h = bh & 7;
  const int n0 = blockIdx.x * 256;
  const int w = tid >> 6, lane = tid & 63;
  const int l15 = lane & 15, kq = lane >> 4;
  const float invt = 1.f / fmaxf(temperature[h], 1e-6f);
  short8 bfr[2][4];
#pragma unroll
  for (int kt = 0; kt < 2; ++kt)
#pragma unroll
    for (int j = 0; j < 4; ++j) {
      const float* wp = Wslice + (j * 16 + l15) * 64 + kt * 32 + kq * 8;
      short8 t;
#pragma unroll
      for (int u = 0; u < 8; ++u) t[u] = (short)f2b(wp[u]);
      bfr[kt][j] = t;
    }
  float bs[4];
#pragma unroll
  for (int j = 0; j < 4; ++j) bs[j] = bslice[j * 16 + l15];
  f32x4 acc[4][4];
#pragma unroll
  for (int i = 0; i < 4; ++i)
#pragma unroll
    for (int j = 0; j < 4; ++j) acc[i][j] = (f32x4){0.f, 0.f, 0.f, 0.f};
#pragma unroll
  for (int kt = 0; kt < 2; ++kt) {
    short8 af[4];
#pragma unroll
    for (int i = 0; i < 4; ++i)
      af[i] = *(const short8*)&xmb[((size_t)(b * NTOK) + n0 + w * 64 + i * 16 + l15) * DIN +
                                   h * 64 + kt * 32 + kq * 8];
#pragma unroll
    for (int i = 0; i < 4; ++i)
#pragma unroll
      for (int j = 0; j < 4; ++j)
        acc[i][j] = __builtin_amdgcn_mfma_f32_16x16x32_bf16(af[i], bfr[kt][j], acc[i][j], 0, 0, 0);
  }
#pragma unroll
  for (int i = 0; i < 4; ++i)
#pragma unroll
    for (int r = 0; r < 4; ++r) {
      float v[4];
      float m = -1e30f;
#pragma unroll
      for (int j = 0; j < 4; ++j) { v[j] = (acc[i][j][r] + bs[j]) * invt; m = fmaxf(m, v[j]); }
#pragma unroll
      for (int off = 8; off; off >>= 1) m = fmaxf(m, __shfl_xor(m, off));
      float s = 0.f;
#pragma unroll
      for (int j = 0; j < 4; ++j) { v[j] = expf(v[j] - m); s += v[j]; }
#pragma unroll
      for (int off = 8; off; off >>= 1) s += __shfl_xor(s, off);
      const float inv = 1.f / s;
      const int row = w * 64 + i * 16 + kq * 4 + r;
#pragma unroll
      for (int j = 0; j < 4; ++j) s_sw[row][j * 16 + l15] = f2b(v[j] * inv);
    }
  __syncthreads();
#pragma unroll
  for (int it = 0; it < 8; ++it) {
    const int c = tid + 256 * it;
    const int row = c >> 3, seg = c & 7;
    *(short8*)&swb[((size_t)bh * NTOK + n0 + row) * 64 + seg * 8] =
        *(const short8*)&s_sw[row][seg * 8];
  }
}

// ---------------------------------------------------------------------------
// K3: st_raw[bh][g][p] = sum_n sw[n,g]*fx[n,p]; snorm[bh][g] = sum_n sw[n,g].
__global__ __launch_bounds__(256) void k_st(
    const unsigned short* __restrict__ swb, const unsigned short* __restrict__ fxb,
    float* __restrict__ st_raw, float* __restrict__ snorm) {
  __shared__ unsigned short swT[64][136];
  __shared__ unsigned short fxT[64][136];
  const int tid = threadIdx.x;
  const int bh = blockIdx.y;
  const int nbase = blockIdx.x * 512;
  const int w = tid >> 6, lane = tid & 63;
  const int l15 = lane & 15, kq = lane >> 4;
  f32x4 acc[4];
#pragma unroll
  for (int i = 0; i < 4; ++i) acc[i] = (f32x4){0.f, 0.f, 0.f, 0.f};
  float sn = 0.f;
  for (int nc = 0; nc < 4; ++nc) {
    const int n0 = nbase + nc * 128;
#pragma unroll
    for (int i = 0; i < 4; ++i) {
      const int c = tid + 256 * i, n = c >> 3, gc = c & 7;
      short8 sv = *(const short8*)&swb[((size_t)bh * NTOK + n0 + n) * 64 + gc * 8];
      short8 fv = *(const short8*)&fxb[((size_t)bh * NTOK + n0 + n) * 64 + gc * 8];
#pragma unroll
      for (int u = 0; u < 8; ++u) {
        swT[gc * 8 + u][n] = (unsigned short)sv[u];
        fxT[gc * 8 + u][n] = (unsigned short)fv[u];
      }
    }
    __syncthreads();
    {
      const int g = tid & 63, q = tid >> 6;
#pragma unroll
      for (int nn = 0; nn < 32; ++nn) sn += b2f(swT[g][q * 32 + nn]);
    }
#pragma unroll
    for (int kw = 0; kw < 4; ++kw) {
      short8 bfr = *(const short8*)&fxT[w * 16 + l15][kw * 32 + kq * 8];
#pragma unroll
      for (int mi = 0; mi < 4; ++mi) {
        short8 af = *(const short8*)&swT[mi * 16 + l15][kw * 32 + kq * 8];
        acc[mi] = __builtin_amdgcn_mfma_f32_16x16x32_bf16(af, bfr, acc[mi], 0, 0, 0);
      }
    }
    __syncthreads();
  }
  float* stp = st_raw + (size_t)bh * 4096;
#pragma unroll
  for (int mi = 0; mi < 4; ++mi)
#pragma unroll
    for (int r = 0; r < 4; ++r)
      atomicAdd(&stp[(mi * 16 + kq * 4 + r) * 64 + w * 16 + l15], acc[mi][r]);
  atomicAdd(&snorm[bh * 64 + (tid & 63)], sn);
}

// ---------------------------------------------------------------------------
// K3b: st2[b,g,h*64+p] = st_raw[b,h,g,p] / (snorm[b,h,g] + 1e-5)
__global__ __launch_bounds__(256) void k_stnorm(
    const float* __restrict__ st_raw, const float* __restrict__ snorm, float* __restrict__ st2) {
  const int idx = blockIdx.x * 256 + threadIdx.x;
  const int p = idx & 63, g = (idx >> 6) & 63, h = (idx >> 12) & 7, b = idx >> 15;
  const float v = st_raw[idx] / (snorm[(b * Hh + h) * 64 + g] + 1e-5f);
  st2[(size_t)(b * 64 + g) * DIN + h * 64 + p] = v;
}

// ---------------------------------------------------------------------------
// K4: zx = st2 (256x512) @ hy_in_w^T (512->1168). fp32 (tiny).
__global__ __launch_bounds__(256) void k_inproj(
    const float* __restrict__ st2, const float* __restrict__ inw, float* __restrict__ zx) {
  __shared__ float at[64][65];
  __shared__ float bt[64][65];
  const int r0 = blockIdx.x * 64;
  const int c0 = blockIdx.y * 64;
  const int tid = threadIdx.x;
  const int i0 = (tid >> 4) << 2, j0 = (tid & 15) << 2;
  const int lrow = tid >> 2, lcol = (tid & 3) << 4;
  float acc[4][4] = {};
  for (int k0 = 0; k0 < DIN; k0 += 64) {
    const float* asrc = st2 + (size_t)(r0 + lrow) * DIN + k0 + lcol;
    const int j = c0 + lrow;
    const bool jok = j < DPROJ;
    const float* wsrc = inw + (size_t)(jok ? j : 0) * DIN + k0 + lcol;
#pragma unroll
    for (int u = 0; u < 16; ++u) at[lrow][lcol + u] = asrc[u];
#pragma unroll
    for (int u = 0; u < 16; ++u) bt[lcol + u][lrow] = jok ? wsrc[u] : 0.f;
    __syncthreads();
#pragma unroll
    for (int kk = 0; kk < 64; ++kk) {
      float av[4], bv[4];
#pragma unroll
      for (int i = 0; i < 4; ++i) av[i] = at[i0 + i][kk];
#pragma unroll
      for (int j2 = 0; j2 < 4; ++j2) bv[j2] = bt[kk][j0 + j2];
#pragma unroll
      for (int i = 0; i < 4; ++i)
#pragma unroll
        for (int j2 = 0; j2 < 4; ++j2) acc[i][j2] += av[i] * bv[j2];
    }
    __syncthreads();
  }
#pragma unroll
  for (int i = 0; i < 4; ++i)
#pragma unroll
    for (int j2 = 0; j2 < 4; ++j2) {
      const int c = c0 + j0 + j2;
      if (c < DPROJ) zx[(size_t)(r0 + i0 + i) * DPROJ + c] = acc[i][j2];
    }
}

// ---------------------------------------------------------------------------
// K4b: conv(k=3)+silu; dt2 / ldA2 (LOG decay: sp * -exp(A_log)).
__global__ __launch_bounds__(256) void k_prep(
    const float* __restrict__ zx, const float* __restrict__ convw, const float* __restrict__ convb,
    const float* __restrict__ dtbias, const float* __restrict__ Alog,
    float* __restrict__ xbc, float* __restrict__ dt2, float* __restrict__ ldA2) {
  const int idx = blockIdx.x * 256 + threadIdx.x;
  const int NCONV = 4 * 64 * CONVD;
  if (idx < NCONV) {
    const int c = idx % CONVD;
    const int l = (idx / CONVD) & 63;
    const int b = idx / (CONVD * 64);
    float acc = convb[c];
#pragma unroll
    for (int k = 0; k < 3; ++k) {
      const int ls = l - 2 + k;
      if (ls >= 0) acc += zx[(size_t)(b * 64 + ls) * DPROJ + DIN + c] * convw[c * 3 + k];
    }
    xbc[idx] = acc * sigmoidf_(acc);
  } else if (idx < NCONV + 8 * 64 * 8) {
    const int j = idx - NCONV;
    const int h = j & 7, l = (j >> 3) & 63, bb = j >> 9;
    float raw;
    if (bb < 4) raw = zx[(size_t)(bb * 64 + l) * DPROJ + 1152 + h];
    else        raw = zx[(size_t)((bb - 4) * 64 + (63 - l)) * DPROJ + 1160 + h];
    const float d = raw + dtbias[h];
    const float sp = (d > 20.f) ? d : log1pf(expf(d));
    dt2[j] = sp;
    ldA2[j] = sp * -expf(Alog[h]);
  }
}

// ---------------------------------------------------------------------------
// K5: SSM via decay-matrix MFMA form. One block per (bb,h) (64 blocks).
// y_t[p] = sum_{s<=t} exp(L[t]-L[s]) * dt_s * (C_t . B_s) * x_s[p]
__global__ __launch_bounds__(256) void k_ssm(
    const float* __restrict__ xbc, const float* __restrict__ dt2, const float* __restrict__ ldA2,
    float* __restrict__ ys) {
  __shared__ unsigned short s_C[64][72];   // C2[t][n]
  __shared__ unsigned short s_Bm[64][72];  // B2[s][n]
  __shared__ unsigned short s_X[64][72];   // X^T[p][s]
  __shared__ unsigned short s_G[64][72];   // G[t][s]
  __shared__ float s_L[64];
  __shared__ float s_dt[64];
  const int blk = blockIdx.x;
  const int h = blk & 7, bb = blk >> 3;
  const int b = (bb < 4) ? bb : bb - 4;
  const bool rev = bb >= 4;
  const int tid = threadIdx.x;
  const int w = tid >> 6, lane = tid & 63;
  const int l15 = lane & 15, kq = lane >> 4;
  {
    const int l = tid >> 2, part = tid & 3;
    const int t = rev ? 63 - l : l;
    const float* src = xbc + (size_t)(b * 64 + l) * CONVD + DIN + part * 32;
#pragma unroll
    for (int u = 0; u < 32; u += 4) {
      float4 v = *(const float4*)(src + u);
      const int c = part * 32 + u;
      unsigned short* dst = (c < 64) ? &s_Bm[t][c] : &s_C[t][c - 64];
      dst[0] = f2b(v.x); dst[1] = f2b(v.y); dst[2] = f2b(v.z); dst[3] = f2b(v.w);
    }
    const float* xs = xbc + (size_t)(b * 64 + l) * CONVD + h * 64 + part * 16;
#pragma unroll
    for (int u = 0; u < 16; u += 4) {
      float4 v = *(const float4*)(xs + u);
      const int p = part * 16 + u;
      s_X[p + 0][t] = f2b(v.x); s_X[p + 1][t] = f2b(v.y);
      s_X[p + 2][t] = f2b(v.z); s_X[p + 3][t] = f2b(v.w);
    }
  }
  if (w == 0) {
    const float dtv = dt2[(bb * 64 + lane) * 8 + h];
    float ld = ldA2[(bb * 64 + lane) * 8 + h];
#pragma unroll
    for (int off = 1; off < 64; off <<= 1) {
      const float o = __shfl_up(ld, off);
      if (lane >= off) ld += o;
    }
    s_L[lane] = ld;
    s_dt[lane] = dtv;
  }
  __syncthreads();
  // S = C2 @ B2^T : D[t][s], wave w covers s in [w*16, w*16+16)
  f32x4 accS[4];
#pragma unroll
  for (int i = 0; i < 4; ++i) accS[i] = (f32x4){0.f, 0.f, 0.f, 0.f};
#pragma unroll
  for (int kw = 0; kw < 2; ++kw) {
    const short8 bfr = *(const short8*)&s_Bm[w * 16 + l15][kw * 32 + kq * 8];
#pragma unroll
    for (int i = 0; i < 4; ++i) {
      const short8 af = *(const short8*)&s_C[i * 16 + l15][kw * 32 + kq * 8];
      accS[i] = __builtin_amdgcn_mfma_f32_16x16x32_bf16(af, bfr, accS[i], 0, 0, 0);
    }
  }
  const int s_idx = w * 16 + l15;
  const float Ls = s_L[s_idx];
  const float dts = s_dt[s_idx];
#pragma unroll
  for (int i = 0; i < 4; ++i)
#pragma unroll
    for (int r = 0; r < 4; ++r) {
      const int t = i * 16 + kq * 4 + r;
      const float g = (s_idx <= t) ? accS[i][r] * expf(s_L[t] - Ls) * dts : 0.f;
      s_G[t][s_idx] = f2b(g);
    }
  __syncthreads();
  // Y = G @ X : D[t][p], wave w covers p in [w*16, w*16+16)
  f32x4 accY[4];
#pragma unroll
  for (int i = 0; i < 4; ++i) accY[i] = (f32x4){0.f, 0.f, 0.f, 0.f};
#pragma unroll
  for (int kw = 0; kw < 2; ++kw) {
    const short8 bfr = *(const short8*)&s_X[w * 16 + l15][kw * 32 + kq * 8];
#pragma unroll
    for (int i = 0; i < 4; ++i) {
      const short8 af = *(const short8*)&s_G[i * 16 + l15][kw * 32 + kq * 8];
      accY[i] = __builtin_amdgcn_mfma_f32_16x16x32_bf16(af, bfr, accY[i], 0, 0, 0);
    }
  }
#pragma unroll
  for (int i = 0; i < 4; ++i)
#pragma unroll
    for (int r = 0; r < 4; ++r) {
      const int t = i * 16 + kq * 4 + r;
      ys[(((size_t)(bb * 64 + t) * 8 + h) << 6) + w * 16 + l15] = accY[i][r];
    }
}

// ---------------------------------------------------------------------------
// K6a: combine + gate + RMS norm (fp32).
__global__ __launch_bounds__(256) void k_gate(
    const float* __restrict__ ys, const float* __restrict__ xbc, const float* __restrict__ zx,
    const float* __restrict__ fcdw, const float* __restrict__ Dp,
    const float* __restrict__ normw, float* __restrict__ yg) {
  __shared__ float red[256][9];
  __shared__ float s_xfc[8];
  const int bl = blockIdx.x;
  const int b = bl >> 6, l = bl & 63;
  const int tid = threadIdx.x;
  const float xog0 = xbc[(size_t)bl * CONVD + tid];
  const float xog1 = xbc[(size_t)bl * CONVD + 256 + tid];
#pragma unroll
  for (int h = 0; h < 8; ++h)
    red[tid][h] = xog0 * fcdw[h * DIN + tid] + xog1 * fcdw[h * DIN + 256 + tid];
  __syncthreads();
  for (int s = 128; s > 0; s >>= 1) {
    if (tid < s) {
#pragma unroll
      for (int h = 0; h < 8; ++h) red[tid][h] += red[tid + s][h];
    }
    __syncthreads();
  }
  if (tid < 8) s_xfc[tid] = red[0][tid] + Dp[tid];
  __syncthreads();
  float ygv[2];
  float sumsq = 0.f;
#pragma unroll
  for (int ci = 0; ci < 2; ++ci) {
    const int c = tid + ci * 256;
    const int h = c >> 6, p = c & 63;
    float yv = 0.f;
    if (l >= 1)  yv += ys[(((size_t)(b * 64 + (l - 1)) * 8 + h) << 6) + p];
    if (l <= 62) yv += ys[(((size_t)((4 + b) * 64 + (62 - l)) * 8 + h) << 6) + p];
    const float xog = (ci == 0) ? xog0 : xog1;
    yv += xog * s_xfc[h];
    const float z = zx[(size_t)bl * DPROJ + c];
    const float g = yv * (z * sigmoidf_(z));
    ygv[ci] = g;
    sumsq += g * g;
  }
  red[tid][0] = sumsq;
  __syncthreads();
  for (int s = 128; s > 0; s >>= 1) {
    if (tid < s) red[tid][0] += red[tid + s][0];
    __syncthreads();
  }
  const float scale = 1.f / sqrtf(red[0][0] / 512.f + 1e-5f);
#pragma unroll
  for (int ci = 0; ci < 2; ++ci) {
    const int c = tid + ci * 256;
    yg[(size_t)bl * DIN + c] = ygv[ci] * scale * normw[c];
  }
}

// ---------------------------------------------------------------------------
// K6b: ot = yg (256x512) @ hy_out_w^T; epilogue writes otT bf16 [(b,h,p)][g].
__global__ __launch_bounds__(256) void k_oproj(
    const float* __restrict__ yg, const float* __restrict__ how, unsigned short* __restrict__ otT) {
  __shared__ float at[64][65];
  __shared__ float bt[64][65];
  const int r0 = blockIdx.x * 64;
  const int c0 = blockIdx.y * 64;
  const int tid = threadIdx.x;
  const int i0 = (tid >> 4) << 2, j0 = (tid & 15) << 2;
  const int lrow = tid >> 2, lcol = (tid & 3) << 4;
  float acc[4][4] = {};
  for (int k0 = 0; k0 < DIN; k0 += 64) {
    const float* asrc = yg + (size_t)(r0 + lrow) * DIN + k0 + lcol;
    const float* wsrc = how + (size_t)(c0 + lrow) * DIN + k0 + lcol;
#pragma unroll
    for (int u = 0; u < 16; ++u) at[lrow][lcol + u] = asrc[u];
#pragma unroll
    for (int u = 0; u < 16; ++u) bt[lcol + u][lrow] = wsrc[u];
    __syncthreads();
#pragma unroll
    for (int kk = 0; kk < 64; ++kk) {
      float av[4], bv[4];
#pragma unroll
      for (int i = 0; i < 4; ++i) av[i] = at[i0 + i][kk];
#pragma unroll
      for (int j2 = 0; j2 < 4; ++j2) bv[j2] = bt[kk][j0 + j2];
#pragma unroll
      for (int i = 0; i < 4; ++i)
#pragma unroll
        for (int j2 = 0; j2 < 4; ++j2) acc[i][j2] += av[i] * bv[j2];
    }
    __syncthreads();
  }
#pragma unroll
  for (int i = 0; i < 4; ++i)
#pragma unroll
    for (int j2 = 0; j2 < 4; ++j2) {
      const int r = r0 + i0 + i;   // b*64+g
      const int c = c0 + j0 + j2;  // h*64+p
      otT[(((size_t)((r >> 6) * 8 + (c >> 6)) * 64 + (c & 63)) << 6) + (r & 63)] = f2b(acc[i][j2]);
    }
}

// ---------------------------------------------------------------------------
// K7: inter[b,n,h*64+p] = sum_g sw[bh,n,g]*otT[bh,p,g]. MFMA bf16.
__global__ __launch_bounds__(256) void k_mix(
    const unsigned short* __restrict__ swb, const unsigned short* __restrict__ otT,
    unsigned short* __restrict__ interb) {
  __shared__ unsigned short As[8 * 256 * 8];
  __shared__ unsigned short Bs[8 * 64 * 8];
  const int tid = threadIdx.x;
  const int bh = blockIdx.y;
  const int b = bh >> 3, h = bh & 7;
  const int n0 = blockIdx.x * 256;
  const int w = tid >> 6, lane = tid & 63;
  const int l15 = lane & 15, kq = lane >> 4;
#pragma unroll
  for (int i = 0; i < 8; ++i) {
    const int c = tid + 256 * i, m = c >> 3, kb = c & 7;
    *(short8*)&As[(kb * 256 + m) * 8] = *(const short8*)&swb[((size_t)bh * NTOK + n0 + m) * 64 + kb * 8];
  }
#pragma unroll
  for (int i = 0; i < 2; ++i) {
    const int c = tid + 256 * i, p = c >> 3, kb = c & 7;
    *(short8*)&Bs[(kb * 64 + p) * 8] = *(const short8*)&otT[((size_t)bh * 64 + p) * 64 + kb * 8];
  }
  __syncthreads();
  f32x4 acc[4][4];
#pragma unroll
  for (int i = 0; i < 4; ++i)
#pragma unroll
    for (int j = 0; j < 4; ++j) acc[i][j] = (f32x4){0.f, 0.f, 0.f, 0.f};
#pragma unroll
  for (int kw = 0; kw < 2; ++kw) {
    short8 af[4], bfr[4];
#pragma unroll
    for (int i = 0; i < 4; ++i) {
      af[i]  = *(const short8*)&As[((kw * 4 + kq) * 256 + w * 64 + i * 16 + l15) * 8];
      bfr[i] = *(const short8*)&Bs[((kw * 4 + kq) * 64 + i * 16 + l15) * 8];
    }
#pragma unroll
    for (int i = 0; i < 4; ++i)
#pragma unroll
      for (int j = 0; j < 4; ++j)
        acc[i][j] = __builtin_amdgcn_mfma_f32_16x16x32_bf16(af[i], bfr[j], acc[i][j], 0, 0, 0);
  }
#pragma unroll
  for (int i = 0; i < 4; ++i)
#pragma unroll
    for (int j = 0; j < 4; ++j)
#pragma unroll
      for (int r = 0; r < 4; ++r) {
        const int n = n0 + w * 64 + i * 16 + kq * 4 + r;
        const int col = h * 64 + j * 16 + l15;
        interb[(size_t)(b * NTOK + n) * DIN + col] = f2b(acc[i][j][r]);
      }
}

// ---------------------------------------------------------------------------
// K8: out = inter (32768x512 bf16) @ out_w^T (256x512 bf16) + out_b. MFMA.
__global__ __launch_bounds__(256) void k_final(
    const unsigned short* __restrict__ interb, const unsigned short* __restrict__ outwb,
    const float* __restrict__ outb, float* __restrict__ out) {
  __shared__ unsigned short As[8 * 128 * 8];
  __shared__ unsigned short Bs[8 * 128 * 8];
  const int tid = threadIdx.x;
  const int m0 = blockIdx.x * 128;
  const int n0 = blockIdx.y * 128;
  const int w = tid >> 6, lane = tid & 63;
  const int l15 = lane & 15, kq = lane >> 4;
  const int wm = (w & 1) * 64, wn = (w >> 1) * 64;
  f32x4 acc[4][4];
#pragma unroll
  for (int i = 0; i < 4; ++i)
#pragma unroll
    for (int j = 0; j < 4; ++j) acc[i][j] = (f32x4){0.f, 0.f, 0.f, 0.f};
  for (int kt = 0; kt < DIN; kt += 64) {
#pragma unroll
    for (int i = 0; i < 4; ++i) {
      const int c = tid + 256 * i, m = c >> 3, kb = c & 7;
      *(short8*)&As[(kb * 128 + m) * 8] = *(const short8*)&interb[(size_t)(m0 + m) * DIN + kt + kb * 8];
      *(short8*)&Bs[(kb * 128 + m) * 8] = *(const short8*)&outwb[(size_t)(n0 + m) * DIN + kt + kb * 8];
    }
    __syncthreads();
#pragma unroll
    for (int kw = 0; kw < 2; ++kw) {
      short8 af[4], bfr[4];
#pragma unroll
      for (int i = 0; i < 4; ++i) {
        af[i]  = *(const short8*)&As[((kw * 4 + kq) * 128 + wm + i * 16 + l15) * 8];
        bfr[i] = *(const short8*)&Bs[((kw * 4 + kq) * 128 + wn + i * 16 + l15) * 8];
      }
#pragma unroll
      for (int i = 0; i < 4; ++i)
#pragma unroll
        for (int j = 0; j < 4; ++j)
          acc[i][j] = __builtin_amdgcn_mfma_f32_16x16x32_bf16(af[i], bfr[j], acc[i][j], 0, 0, 0);
    }
    __syncthreads();
  }
#pragma unroll
  for (int i = 0; i < 4; ++i)
#pragma unroll
    for (int j = 0; j < 4; ++j)
#pragma unroll
      for (int r = 0; r < 4; ++r) {
        const int R = m0 + wm + i * 16 + kq * 4 + r;
        const int C = n0 + wn + j * 16 + l15;
        out[(size_t)R * DIM + C] = acc[i][j][r] + outb[C];
      }
}

// ---------------------------------------------------------------------------
extern "C" void kernel_launch(void* const* d_in, const int* in_sizes, int n_in,
                              void* d_out, int out_size, void* d_ws, size_t ws_size,
                              hipStream_t stream) {
  const float* x      = (const float*)d_in[0];
  const float* Wfx    = (const float*)d_in[1];
  const float* bfx    = (const float*)d_in[2];
  const float* Wx     = (const float*)d_in[3];
  const float* bx     = (const float*)d_in[4];
  const float* Wslice = (const float*)d_in[5];
  const float* bslice = (const float*)d_in[6];
  const float* temp   = (const float*)d_in[7];
  const float* inw    = (const float*)d_in[8];
  const float* convw  = (const float*)d_in[9];
  const float* convb  = (const float*)d_in[10];
  const float* dtbias = (const float*)d_in[11];
  const float* Alog   = (const float*)d_in[12];
  const float* Dp     = (const float*)d_in[13];
  const float* fcdw   = (const float*)d_in[14];
  const float* normw  = (const float*)d_in[15];
  const float* how    = (const float*)d_in[16];
  const float* outw   = (const float*)d_in[17];
  const float* outb   = (const float*)d_in[18];

  unsigned short* us = (unsigned short*)d_ws;
  unsigned short* fxb    = us;                   // 16,777,216
  unsigned short* xmb    = fxb + 16777216;       // 16,777,216
  unsigned short* swb    = xmb + 16777216;       // 16,777,216
  unsigned short* interb = swb + 16777216;       // 16,777,216
  unsigned short* xbfb   = interb + 16777216;    //  8,388,608
  unsigned short* wcatb  = xbfb + 8388608;       //    262,144
  unsigned short* outwbf = wcatb + 262144;       //    131,072
  unsigned short* otTb   = outwbf + 131072;      //    131,072
  float* fbase = (float*)(otTb + 131072);
  float* st_raw = fbase;                          //    131,072
  float* snorm  = st_raw + 131072;                //      2,048
  float* st2    = snorm + 2048;                   //    131,072
  float* zx     = st2 + 131072;                   //    299,008
  float* xbc    = zx + 299008;                    //    163,840
  float* dt2    = xbc + 163840;                   //      4,096
  float* ldA2   = dt2 + 4096;                     //      4,096
  float* ysb    = ldA2 + 4096;                    //    262,144
  float* ygb    = ysb + 262144;                   //    131,072

  hipMemsetAsync(st_raw, 0, (131072 + 2048) * sizeof(float), stream);

  k_cvt   <<<dim3(8576),     256, 0, stream>>>(x, Wfx, Wx, outw, xbfb, wcatb, outwbf);
  k_fxxm  <<<dim3(256, 8),   256, 0, stream>>>(xbfb, wcatb, bfx, bx, fxb, xmb);
  k_sw    <<<dim3(32, 32),   256, 0, stream>>>(xmb, Wslice, bslice, temp, swb);
  k_st    <<<dim3(16, 32),   256, 0, stream>>>(swb, fxb, st_raw, snorm);
  k_stnorm<<<dim3(512),      256, 0, stream>>>(st_raw, snorm, st2);
  k_inproj<<<dim3(4, 19),    256, 0, stream>>>(st2, inw, zx);
  k_prep  <<<dim3(656),      256, 0, stream>>>(zx, convw, convb, dtbias, Alog, xbc, dt2, ldA2);
  k_ssm   <<<dim3(64),       256, 0, stream>>>(xbc, dt2, ldA2, ysb);
  k_gate  <<<dim3(256),      256, 0, stream>>>(ysb, xbc, zx, fcdw, Dp, normw, ygb);
  k_oproj <<<dim3(4, 8),     256, 0, stream>>>(ygb, how, otTb);
  k_mix   <<<dim3(32, 32),   256, 0, stream>>>(swb, otTb, interb);
  k_final <<<dim3(256, 2),   256, 0, stream>>>(interb, outwbf, outb, (float*)d_out);
}

// Round 5
// 334.969 us; speedup vs baseline: 3.6147x; 1.1592x over previous
//
#include <hip/hip_runtime.h>
#include <hip/hip_bf16.h>
#include <cstdint>
#include <cstddef>

#define Hh 8
#define DIN 512
#define CONVD 640
#define DPROJ 1168
#define NTOK 8192
#define DIM 256

typedef __attribute__((ext_vector_type(8))) short short8;
typedef __attribute__((ext_vector_type(4))) float f32x4;

static __device__ __forceinline__ float sigmoidf_(float x) { return 1.f / (1.f + expf(-x)); }
static __device__ __forceinline__ unsigned short f2b(float f) {
  __hip_bfloat16 h = __float2bfloat16(f);
  return *(unsigned short*)&h;
}
static __device__ __forceinline__ float b2f(unsigned short u) {
  union { unsigned int i; float f; } cv; cv.i = ((unsigned int)u) << 16; return cv.f;
}

// ---------------------------------------------------------------------------
// K0: fp32->bf16: x, Wfx|Wx -> wcat, outw; plus fused bias bcat = [bfx|bx] (fp32).
__global__ __launch_bounds__(256) void k_cvt(
    const float* __restrict__ x, const float* __restrict__ wfx, const float* __restrict__ wx,
    const float* __restrict__ outw, const float* __restrict__ bfx, const float* __restrict__ bx,
    unsigned short* __restrict__ xb, unsigned short* __restrict__ wcat,
    unsigned short* __restrict__ outwb, float* __restrict__ bcat) {
  const int e = (blockIdx.x * 256 + threadIdx.x) * 4;
  if (e >= 8781824) {
    const int i = e - 8781824;  // 0..1023
    float4 v;
    if (i < 512) v = *(const float4*)(bfx + i);
    else         v = *(const float4*)(bx + (i - 512));
    *(float4*)(bcat + i) = v;
    return;
  }
  const float* src; unsigned short* dst; int i;
  if (e < 8388608)       { i = e;           src = x;    dst = xb; }
  else if (e < 8519680)  { i = e - 8388608; src = wfx;  dst = wcat; }
  else if (e < 8650752)  { i = e - 8519680; src = wx;   dst = wcat + 131072; }
  else                   { i = e - 8650752; src = outw; dst = outwb; }
  float4 v = *(const float4*)(src + i);
  ushort4 o;
  o.x = f2b(v.x); o.y = f2b(v.y); o.z = f2b(v.z); o.w = f2b(v.w);
  *(ushort4*)(dst + i) = o;
}

// ---------------------------------------------------------------------------
// K1: cb = x @ [W_fx|W_x]^T + bcat, token-major bf16 (32768 x 1024).
// Pitched LDS staging [kb][130][8] (conflict-free), LDS-staged coalesced epilogue.
__global__ __launch_bounds__(256) void k_fxxm(
    const unsigned short* __restrict__ xb, const unsigned short* __restrict__ wcat,
    const float* __restrict__ bcat, unsigned short* __restrict__ cb) {
  __shared__ unsigned short lds[17408];  // 34816 B
  unsigned short* As = lds;              // [kb][130][8] -> 8320 shorts
  unsigned short* Bs = lds + 8320;
  const int tid = threadIdx.x;
  const int m0 = blockIdx.x * 128;
  const int n0 = blockIdx.y * 128;
  const int w = tid >> 6, lane = tid & 63;
  const int l15 = lane & 15, kq = lane >> 4;
  const int wm = (w & 1) * 64, wn = (w >> 1) * 64;
  float bs[4];
#pragma unroll
  for (int j = 0; j < 4; ++j) bs[j] = bcat[n0 + wn + j * 16 + l15];
  f32x4 acc[4][4];
#pragma unroll
  for (int i = 0; i < 4; ++i)
#pragma unroll
    for (int j = 0; j < 4; ++j) acc[i][j] = (f32x4){0.f, 0.f, 0.f, 0.f};
  for (int kt = 0; kt < 256; kt += 64) {
#pragma unroll
    for (int i = 0; i < 4; ++i) {
      const int c = tid + 256 * i, m = c >> 3, kb = c & 7;
      *(short8*)&As[(kb * 130 + m) * 8] = *(const short8*)&xb[(size_t)(m0 + m) * 256 + kt + kb * 8];
      *(short8*)&Bs[(kb * 130 + m) * 8] = *(const short8*)&wcat[(size_t)(n0 + m) * 256 + kt + kb * 8];
    }
    __syncthreads();
#pragma unroll
    for (int kw = 0; kw < 2; ++kw) {
      short8 af[4], bfr[4];
#pragma unroll
      for (int i = 0; i < 4; ++i) {
        af[i]  = *(const short8*)&As[((kw * 4 + kq) * 130 + wm + i * 16 + l15) * 8];
        bfr[i] = *(const short8*)&Bs[((kw * 4 + kq) * 130 + wn + i * 16 + l15) * 8];
      }
#pragma unroll
      for (int i = 0; i < 4; ++i)
#pragma unroll
        for (int j = 0; j < 4; ++j)
          acc[i][j] = __builtin_amdgcn_mfma_f32_16x16x32_bf16(af[i], bfr[j], acc[i][j], 0, 0, 0);
    }
    __syncthreads();
  }
  // epilogue: C-layout -> LDS [128][136] -> coalesced short8 stores
  unsigned short* Cs = lds;
#pragma unroll
  for (int i = 0; i < 4; ++i)
#pragma unroll
    for (int j = 0; j < 4; ++j)
#pragma unroll
      for (int r = 0; r < 4; ++r) {
        const int m = wm + i * 16 + kq * 4 + r;
        const int n = wn + j * 16 + l15;
        Cs[m * 136 + n] = f2b(acc[i][j][r] + bs[j]);
      }
  __syncthreads();
#pragma unroll
  for (int it = 0; it < 8; ++it) {
    const int c = tid + 256 * it;
    const int m = c >> 4, seg = c & 15;
    *(short8*)&cb[(size_t)(m0 + m) * 1024 + n0 + seg * 8] = *(const short8*)&Cs[m * 136 + seg * 8];
  }
}

// ---------------------------------------------------------------------------
// K2: fused score-GEMM + softmax; reads xm part of cb (cols 512..1023).
__global__ __launch_bounds__(256) void k_sw(
    const unsigned short* __restrict__ cb, const float* __restrict__ Wslice,
    const float* __restrict__ bslice, const float* __restrict__ temperature,
    unsigned short* __restrict__ swb) {
  __shared__ unsigned short s_sw[256][72];
  const int tid = threadIdx.x;
  const int bh = blockIdx.y;
  const int b = bh >> 3, h = bh & 7;
  const int n0 = blockIdx.x * 256;
  const int w = tid >> 6, lane = tid & 63;
  const int l15 = lane & 15, kq = lane >> 4;
  const float invt = 1.f / fmaxf(temperature[h], 1e-6f);
  short8 bfr[2][4];
#pragma unroll
  for (int kt = 0; kt < 2; ++kt)
#pragma unroll
    for (int j = 0; j < 4; ++j) {
      const float* wp = Wslice + (j * 16 + l15) * 64 + kt * 32 + kq * 8;
      short8 t;
#pragma unroll
      for (int u = 0; u < 8; ++u) t[u] = (short)f2b(wp[u]);
      bfr[kt][j] = t;
    }
  float bs[4];
#pragma unroll
  for (int j = 0; j < 4; ++j) bs[j] = bslice[j * 16 + l15];
  f32x4 acc[4][4];
#pragma unroll
  for (int i = 0; i < 4; ++i)
#pragma unroll
    for (int j = 0; j < 4; ++j) acc[i][j] = (f32x4){0.f, 0.f, 0.f, 0.f};
#pragma unroll
  for (int kt = 0; kt < 2; ++kt) {
    short8 af[4];
#pragma unroll
    for (int i = 0; i < 4; ++i)
      af[i] = *(const short8*)&cb[((size_t)(b * NTOK) + n0 + w * 64 + i * 16 + l15) * 1024 +
                                  512 + h * 64 + kt * 32 + kq * 8];
#pragma unroll
    for (int i = 0; i < 4; ++i)
#pragma unroll
      for (int j = 0; j < 4; ++j)
        acc[i][j] = __builtin_amdgcn_mfma_f32_16x16x32_bf16(af[i], bfr[kt][j], acc[i][j], 0, 0, 0);
  }
#pragma unroll
  for (int i = 0; i < 4; ++i)
#pragma unroll
    for (int r = 0; r < 4; ++r) {
      float v[4];
      float m = -1e30f;
#pragma unroll
      for (int j = 0; j < 4; ++j) { v[j] = (acc[i][j][r] + bs[j]) * invt; m = fmaxf(m, v[j]); }
#pragma unroll
      for (int off = 8; off; off >>= 1) m = fmaxf(m, __shfl_xor(m, off));
      float s = 0.f;
#pragma unroll
      for (int j = 0; j < 4; ++j) { v[j] = expf(v[j] - m); s += v[j]; }
#pragma unroll
      for (int off = 8; off; off >>= 1) s += __shfl_xor(s, off);
      const float inv = 1.f / s;
      const int row = w * 64 + i * 16 + kq * 4 + r;
#pragma unroll
      for (int j = 0; j < 4; ++j) s_sw[row][j * 16 + l15] = f2b(v[j] * inv);
    }
  __syncthreads();
#pragma unroll
  for (int it = 0; it < 8; ++it) {
    const int c = tid + 256 * it;
    const int row = c >> 3, seg = c & 7;
    *(short8*)&swb[((size_t)bh * NTOK + n0 + row) * 64 + seg * 8] =
        *(const short8*)&s_sw[row][seg * 8];
  }
}

// ---------------------------------------------------------------------------
// K3: st_raw[bh][g][p] = sum_n sw[n,g]*fx[n,p]; snorm[bh][g] = sum_n sw[n,g].
// fx read from cb (cols h*64..h*64+63).
__global__ __launch_bounds__(256) void k_st(
    const unsigned short* __restrict__ swb, const unsigned short* __restrict__ cb,
    float* __restrict__ st_raw, float* __restrict__ snorm) {
  __shared__ unsigned short swT[64][136];
  __shared__ unsigned short fxT[64][136];
  const int tid = threadIdx.x;
  const int bh = blockIdx.y;
  const int b = bh >> 3, h = bh & 7;
  const int nbase = blockIdx.x * 512;
  const int w = tid >> 6, lane = tid & 63;
  const int l15 = lane & 15, kq = lane >> 4;
  f32x4 acc[4];
#pragma unroll
  for (int i = 0; i < 4; ++i) acc[i] = (f32x4){0.f, 0.f, 0.f, 0.f};
  float sn = 0.f;
  for (int nc = 0; nc < 4; ++nc) {
    const int n0 = nbase + nc * 128;
#pragma unroll
    for (int i = 0; i < 4; ++i) {
      const int c = tid + 256 * i, n = c >> 3, gc = c & 7;
      short8 sv = *(const short8*)&swb[((size_t)bh * NTOK + n0 + n) * 64 + gc * 8];
      short8 fv = *(const short8*)&cb[((size_t)(b * NTOK) + n0 + n) * 1024 + h * 64 + gc * 8];
#pragma unroll
      for (int u = 0; u < 8; ++u) {
        swT[gc * 8 + u][n] = (unsigned short)sv[u];
        fxT[gc * 8 + u][n] = (unsigned short)fv[u];
      }
    }
    __syncthreads();
    {
      const int g = tid & 63, q = tid >> 6;
#pragma unroll
      for (int nn = 0; nn < 32; ++nn) sn += b2f(swT[g][q * 32 + nn]);
    }
#pragma unroll
    for (int kw = 0; kw < 4; ++kw) {
      short8 bfr = *(const short8*)&fxT[w * 16 + l15][kw * 32 + kq * 8];
#pragma unroll
      for (int mi = 0; mi < 4; ++mi) {
        short8 af = *(const short8*)&swT[mi * 16 + l15][kw * 32 + kq * 8];
        acc[mi] = __builtin_amdgcn_mfma_f32_16x16x32_bf16(af, bfr, acc[mi], 0, 0, 0);
      }
    }
    __syncthreads();
  }
  float* stp = st_raw + (size_t)bh * 4096;
#pragma unroll
  for (int mi = 0; mi < 4; ++mi)
#pragma unroll
    for (int r = 0; r < 4; ++r)
      atomicAdd(&stp[(mi * 16 + kq * 4 + r) * 64 + w * 16 + l15], acc[mi][r]);
  atomicAdd(&snorm[bh * 64 + (tid & 63)], sn);
}

// ---------------------------------------------------------------------------
// K3b: st2[b,g,h*64+p] = st_raw[b,h,g,p] / (snorm[b,h,g] + 1e-5)
__global__ __launch_bounds__(256) void k_stnorm(
    const float* __restrict__ st_raw, const float* __restrict__ snorm, float* __restrict__ st2) {
  const int idx = blockIdx.x * 256 + threadIdx.x;
  const int p = idx & 63, g = (idx >> 6) & 63, h = (idx >> 12) & 7, b = idx >> 15;
  const float v = st_raw[idx] / (snorm[(b * Hh + h) * 64 + g] + 1e-5f);
  st2[(size_t)(b * 64 + g) * DIN + h * 64 + p] = v;
}

// ---------------------------------------------------------------------------
// K4: zx = st2 (256x512) @ hy_in_w^T (512->1168). fp32 (tiny).
__global__ __launch_bounds__(256) void k_inproj(
    const float* __restrict__ st2, const float* __restrict__ inw, float* __restrict__ zx) {
  __shared__ float at[64][65];
  __shared__ float bt[64][65];
  const int r0 = blockIdx.x * 64;
  const int c0 = blockIdx.y * 64;
  const int tid = threadIdx.x;
  const int i0 = (tid >> 4) << 2, j0 = (tid & 15) << 2;
  const int lrow = tid >> 2, lcol = (tid & 3) << 4;
  float acc[4][4] = {};
  for (int k0 = 0; k0 < DIN; k0 += 64) {
    const float* asrc = st2 + (size_t)(r0 + lrow) * DIN + k0 + lcol;
    const int j = c0 + lrow;
    const bool jok = j < DPROJ;
    const float* wsrc = inw + (size_t)(jok ? j : 0) * DIN + k0 + lcol;
#pragma unroll
    for (int u = 0; u < 16; ++u) at[lrow][lcol + u] = asrc[u];
#pragma unroll
    for (int u = 0; u < 16; ++u) bt[lcol + u][lrow] = jok ? wsrc[u] : 0.f;
    __syncthreads();
#pragma unroll
    for (int kk = 0; kk < 64; ++kk) {
      float av[4], bv[4];
#pragma unroll
      for (int i = 0; i < 4; ++i) av[i] = at[i0 + i][kk];
#pragma unroll
      for (int j2 = 0; j2 < 4; ++j2) bv[j2] = bt[kk][j0 + j2];
#pragma unroll
      for (int i = 0; i < 4; ++i)
#pragma unroll
        for (int j2 = 0; j2 < 4; ++j2) acc[i][j2] += av[i] * bv[j2];
    }
    __syncthreads();
  }
#pragma unroll
  for (int i = 0; i < 4; ++i)
#pragma unroll
    for (int j2 = 0; j2 < 4; ++j2) {
      const int c = c0 + j0 + j2;
      if (c < DPROJ) zx[(size_t)(r0 + i0 + i) * DPROJ + c] = acc[i][j2];
    }
}

// ---------------------------------------------------------------------------
// K4b: conv(k=3)+silu; dt2 / ldA2 (LOG decay).
__global__ __launch_bounds__(256) void k_prep(
    const float* __restrict__ zx, const float* __restrict__ convw, const float* __restrict__ convb,
    const float* __restrict__ dtbias, const float* __restrict__ Alog,
    float* __restrict__ xbc, float* __restrict__ dt2, float* __restrict__ ldA2) {
  const int idx = blockIdx.x * 256 + threadIdx.x;
  const int NCONV = 4 * 64 * CONVD;
  if (idx < NCONV) {
    const int c = idx % CONVD;
    const int l = (idx / CONVD) & 63;
    const int b = idx / (CONVD * 64);
    float acc = convb[c];
#pragma unroll
    for (int k = 0; k < 3; ++k) {
      const int ls = l - 2 + k;
      if (ls >= 0) acc += zx[(size_t)(b * 64 + ls) * DPROJ + DIN + c] * convw[c * 3 + k];
    }
    xbc[idx] = acc * sigmoidf_(acc);
  } else if (idx < NCONV + 8 * 64 * 8) {
    const int j = idx - NCONV;
    const int h = j & 7, l = (j >> 3) & 63, bb = j >> 9;
    float raw;
    if (bb < 4) raw = zx[(size_t)(bb * 64 + l) * DPROJ + 1152 + h];
    else        raw = zx[(size_t)((bb - 4) * 64 + (63 - l)) * DPROJ + 1160 + h];
    const float d = raw + dtbias[h];
    const float sp = (d > 20.f) ? d : log1pf(expf(d));
    dt2[j] = sp;
    ldA2[j] = sp * -expf(Alog[h]);
  }
}

// ---------------------------------------------------------------------------
// K5: SSM via decay-matrix MFMA form. One block per (bb,h).
__global__ __launch_bounds__(256) void k_ssm(
    const float* __restrict__ xbc, const float* __restrict__ dt2, const float* __restrict__ ldA2,
    float* __restrict__ ys) {
  __shared__ unsigned short s_C[64][72];
  __shared__ unsigned short s_Bm[64][72];
  __shared__ unsigned short s_X[64][72];
  __shared__ unsigned short s_G[64][72];
  __shared__ float s_L[64];
  __shared__ float s_dt[64];
  const int blk = blockIdx.x;
  const int h = blk & 7, bb = blk >> 3;
  const int b = (bb < 4) ? bb : bb - 4;
  const bool rev = bb >= 4;
  const int tid = threadIdx.x;
  const int w = tid >> 6, lane = tid & 63;
  const int l15 = lane & 15, kq = lane >> 4;
  {
    const int l = tid >> 2, part = tid & 3;
    const int t = rev ? 63 - l : l;
    const float* src = xbc + (size_t)(b * 64 + l) * CONVD + DIN + part * 32;
#pragma unroll
    for (int u = 0; u < 32; u += 4) {
      float4 v = *(const float4*)(src + u);
      const int c = part * 32 + u;
      unsigned short* dst = (c < 64) ? &s_Bm[t][c] : &s_C[t][c - 64];
      dst[0] = f2b(v.x); dst[1] = f2b(v.y); dst[2] = f2b(v.z); dst[3] = f2b(v.w);
    }
    const float* xs = xbc + (size_t)(b * 64 + l) * CONVD + h * 64 + part * 16;
#pragma unroll
    for (int u = 0; u < 16; u += 4) {
      float4 v = *(const float4*)(xs + u);
      const int p = part * 16 + u;
      s_X[p + 0][t] = f2b(v.x); s_X[p + 1][t] = f2b(v.y);
      s_X[p + 2][t] = f2b(v.z); s_X[p + 3][t] = f2b(v.w);
    }
  }
  if (w == 0) {
    const float dtv = dt2[(bb * 64 + lane) * 8 + h];
    float ld = ldA2[(bb * 64 + lane) * 8 + h];
#pragma unroll
    for (int off = 1; off < 64; off <<= 1) {
      const float o = __shfl_up(ld, off);
      if (lane >= off) ld += o;
    }
    s_L[lane] = ld;
    s_dt[lane] = dtv;
  }
  __syncthreads();
  f32x4 accS[4];
#pragma unroll
  for (int i = 0; i < 4; ++i) accS[i] = (f32x4){0.f, 0.f, 0.f, 0.f};
#pragma unroll
  for (int kw = 0; kw < 2; ++kw) {
    const short8 bfr = *(const short8*)&s_Bm[w * 16 + l15][kw * 32 + kq * 8];
#pragma unroll
    for (int i = 0; i < 4; ++i) {
      const short8 af = *(const short8*)&s_C[i * 16 + l15][kw * 32 + kq * 8];
      accS[i] = __builtin_amdgcn_mfma_f32_16x16x32_bf16(af, bfr, accS[i], 0, 0, 0);
    }
  }
  const int s_idx = w * 16 + l15;
  const float Ls = s_L[s_idx];
  const float dts = s_dt[s_idx];
#pragma unroll
  for (int i = 0; i < 4; ++i)
#pragma unroll
    for (int r = 0; r < 4; ++r) {
      const int t = i * 16 + kq * 4 + r;
      const float g = (s_idx <= t) ? accS[i][r] * expf(s_L[t] - Ls) * dts : 0.f;
      s_G[t][s_idx] = f2b(g);
    }
  __syncthreads();
  f32x4 accY[4];
#pragma unroll
  for (int i = 0; i < 4; ++i) accY[i] = (f32x4){0.f, 0.f, 0.f, 0.f};
#pragma unroll
  for (int kw = 0; kw < 2; ++kw) {
    const short8 bfr = *(const short8*)&s_X[w * 16 + l15][kw * 32 + kq * 8];
#pragma unroll
    for (int i = 0; i < 4; ++i) {
      const short8 af = *(const short8*)&s_G[i * 16 + l15][kw * 32 + kq * 8];
      accY[i] = __builtin_amdgcn_mfma_f32_16x16x32_bf16(af, bfr, accY[i], 0, 0, 0);
    }
  }
#pragma unroll
  for (int i = 0; i < 4; ++i)
#pragma unroll
    for (int r = 0; r < 4; ++r) {
      const int t = i * 16 + kq * 4 + r;
      ys[(((size_t)(bb * 64 + t) * 8 + h) << 6) + w * 16 + l15] = accY[i][r];
    }
}

// ---------------------------------------------------------------------------
// K6a: combine + gate + RMS norm (fp32).
__global__ __launch_bounds__(256) void k_gate(
    const float* __restrict__ ys, const float* __restrict__ xbc, const float* __restrict__ zx,
    const float* __restrict__ fcdw, const float* __restrict__ Dp,
    const float* __restrict__ normw, float* __restrict__ yg) {
  __shared__ float red[256][9];
  __shared__ float s_xfc[8];
  const int bl = blockIdx.x;
  const int b = bl >> 6, l = bl & 63;
  const int tid = threadIdx.x;
  const float xog0 = xbc[(size_t)bl * CONVD + tid];
  const float xog1 = xbc[(size_t)bl * CONVD + 256 + tid];
#pragma unroll
  for (int h = 0; h < 8; ++h)
    red[tid][h] = xog0 * fcdw[h * DIN + tid] + xog1 * fcdw[h * DIN + 256 + tid];
  __syncthreads();
  for (int s = 128; s > 0; s >>= 1) {
    if (tid < s) {
#pragma unroll
      for (int h = 0; h < 8; ++h) red[tid][h] += red[tid + s][h];
    }
    __syncthreads();
  }
  if (tid < 8) s_xfc[tid] = red[0][tid] + Dp[tid];
  __syncthreads();
  float ygv[2];
  float sumsq = 0.f;
#pragma unroll
  for (int ci = 0; ci < 2; ++ci) {
    const int c = tid + ci * 256;
    const int h = c >> 6, p = c & 63;
    float yv = 0.f;
    if (l >= 1)  yv += ys[(((size_t)(b * 64 + (l - 1)) * 8 + h) << 6) + p];
    if (l <= 62) yv += ys[(((size_t)((4 + b) * 64 + (62 - l)) * 8 + h) << 6) + p];
    const float xog = (ci == 0) ? xog0 : xog1;
    yv += xog * s_xfc[h];
    const float z = zx[(size_t)bl * DPROJ + c];
    const float g = yv * (z * sigmoidf_(z));
    ygv[ci] = g;
    sumsq += g * g;
  }
  red[tid][0] = sumsq;
  __syncthreads();
  for (int s = 128; s > 0; s >>= 1) {
    if (tid < s) red[tid][0] += red[tid + s][0];
    __syncthreads();
  }
  const float scale = 1.f / sqrtf(red[0][0] / 512.f + 1e-5f);
#pragma unroll
  for (int ci = 0; ci < 2; ++ci) {
    const int c = tid + ci * 256;
    yg[(size_t)bl * DIN + c] = ygv[ci] * scale * normw[c];
  }
}

// ---------------------------------------------------------------------------
// K6b: ot = yg (256x512) @ hy_out_w^T; epilogue writes otT bf16 [(b,h,p)][g].
__global__ __launch_bounds__(256) void k_oproj(
    const float* __restrict__ yg, const float* __restrict__ how, unsigned short* __restrict__ otT) {
  __shared__ float at[64][65];
  __shared__ float bt[64][65];
  const int r0 = blockIdx.x * 64;
  const int c0 = blockIdx.y * 64;
  const int tid = threadIdx.x;
  const int i0 = (tid >> 4) << 2, j0 = (tid & 15) << 2;
  const int lrow = tid >> 2, lcol = (tid & 3) << 4;
  float acc[4][4] = {};
  for (int k0 = 0; k0 < DIN; k0 += 64) {
    const float* asrc = yg + (size_t)(r0 + lrow) * DIN + k0 + lcol;
    const float* wsrc = how + (size_t)(c0 + lrow) * DIN + k0 + lcol;
#pragma unroll
    for (int u = 0; u < 16; ++u) at[lrow][lcol + u] = asrc[u];
#pragma unroll
    for (int u = 0; u < 16; ++u) bt[lcol + u][lrow] = wsrc[u];
    __syncthreads();
#pragma unroll
    for (int kk = 0; kk < 64; ++kk) {
      float av[4], bv[4];
#pragma unroll
      for (int i = 0; i < 4; ++i) av[i] = at[i0 + i][kk];
#pragma unroll
      for (int j2 = 0; j2 < 4; ++j2) bv[j2] = bt[kk][j0 + j2];
#pragma unroll
      for (int i = 0; i < 4; ++i)
#pragma unroll
        for (int j2 = 0; j2 < 4; ++j2) acc[i][j2] += av[i] * bv[j2];
    }
    __syncthreads();
  }
#pragma unroll
  for (int i = 0; i < 4; ++i)
#pragma unroll
    for (int j2 = 0; j2 < 4; ++j2) {
      const int r = r0 + i0 + i;   // b*64+g
      const int c = c0 + j0 + j2;  // h*64+p
      otT[(((size_t)((r >> 6) * 8 + (c >> 6)) * 64 + (c & 63)) << 6) + (r & 63)] = f2b(acc[i][j2]);
    }
}

// ---------------------------------------------------------------------------
// K7: inter[b,n,h*64+p] = sum_g sw[bh,n,g]*otT[bh,p,g]. Pitched LDS + staged epilogue.
__global__ __launch_bounds__(256) void k_mix(
    const unsigned short* __restrict__ swb, const unsigned short* __restrict__ otT,
    unsigned short* __restrict__ interb) {
  __shared__ unsigned short lds[20736];  // 41472 B
  unsigned short* As = lds;              // [kb][258][8] -> 16512 shorts
  unsigned short* Bs = lds + 16512;      // [kb][66][8]  -> 4224 shorts
  const int tid = threadIdx.x;
  const int bh = blockIdx.y;
  const int b = bh >> 3, h = bh & 7;
  const int n0 = blockIdx.x * 256;
  const int w = tid >> 6, lane = tid & 63;
  const int l15 = lane & 15, kq = lane >> 4;
#pragma unroll
  for (int i = 0; i < 8; ++i) {
    const int c = tid + 256 * i, m = c >> 3, kb = c & 7;
    *(short8*)&As[(kb * 258 + m) * 8] = *(const short8*)&swb[((size_t)bh * NTOK + n0 + m) * 64 + kb * 8];
  }
#pragma unroll
  for (int i = 0; i < 2; ++i) {
    const int c = tid + 256 * i, p = c >> 3, kb = c & 7;
    *(short8*)&Bs[(kb * 66 + p) * 8] = *(const short8*)&otT[((size_t)bh * 64 + p) * 64 + kb * 8];
  }
  __syncthreads();
  f32x4 acc[4][4];
#pragma unroll
  for (int i = 0; i < 4; ++i)
#pragma unroll
    for (int j = 0; j < 4; ++j) acc[i][j] = (f32x4){0.f, 0.f, 0.f, 0.f};
#pragma unroll
  for (int kw = 0; kw < 2; ++kw) {
    short8 af[4], bfr[4];
#pragma unroll
    for (int i = 0; i < 4; ++i) {
      af[i]  = *(const short8*)&As[((kw * 4 + kq) * 258 + w * 64 + i * 16 + l15) * 8];
      bfr[i] = *(const short8*)&Bs[((kw * 4 + kq) * 66 + i * 16 + l15) * 8];
    }
#pragma unroll
    for (int i = 0; i < 4; ++i)
#pragma unroll
      for (int j = 0; j < 4; ++j)
        acc[i][j] = __builtin_amdgcn_mfma_f32_16x16x32_bf16(af[i], bfr[j], acc[i][j], 0, 0, 0);
  }
  __syncthreads();
  // epilogue: stage [256][72] in LDS, then coalesced short8 stores
  unsigned short* Cs = lds;
#pragma unroll
  for (int i = 0; i < 4; ++i)
#pragma unroll
    for (int j = 0; j < 4; ++j)
#pragma unroll
      for (int r = 0; r < 4; ++r) {
        const int m = w * 64 + i * 16 + kq * 4 + r;
        const int n = j * 16 + l15;
        Cs[m * 72 + n] = f2b(acc[i][j][r]);
      }
  __syncthreads();
#pragma unroll
  for (int it = 0; it < 8; ++it) {
    const int c = tid + 256 * it;
    const int row = c >> 3, seg = c & 7;
    *(short8*)&interb[((size_t)(b * NTOK) + n0 + row) * 512 + h * 64 + seg * 8] =
        *(const short8*)&Cs[row * 72 + seg * 8];
  }
}

// ---------------------------------------------------------------------------
// K8: out = inter @ out_w^T + out_b. Pitched LDS, 2-pass fp32 staged epilogue.
__global__ __launch_bounds__(256) void k_final(
    const unsigned short* __restrict__ interb, const unsigned short* __restrict__ outwb,
    const float* __restrict__ outb, float* __restrict__ out) {
  __shared__ float ldsf[8448];           // 33792 B
  unsigned short* ls = (unsigned short*)ldsf;
  unsigned short* As = ls;               // [kb][130][8]
  unsigned short* Bs = ls + 8320;
  const int tid = threadIdx.x;
  const int m0 = blockIdx.x * 128;
  const int n0 = blockIdx.y * 128;
  const int w = tid >> 6, lane = tid & 63;
  const int l15 = lane & 15, kq = lane >> 4;
  const int wm = (w & 1) * 64, wn = (w >> 1) * 64;
  float ob[4];
#pragma unroll
  for (int j = 0; j < 4; ++j) ob[j] = outb[n0 + wn + j * 16 + l15];
  f32x4 acc[4][4];
#pragma unroll
  for (int i = 0; i < 4; ++i)
#pragma unroll
    for (int j = 0; j < 4; ++j) acc[i][j] = (f32x4){0.f, 0.f, 0.f, 0.f};
  for (int kt = 0; kt < DIN; kt += 64) {
#pragma unroll
    for (int i = 0; i < 4; ++i) {
      const int c = tid + 256 * i, m = c >> 3, kb = c & 7;
      *(short8*)&As[(kb * 130 + m) * 8] = *(const short8*)&interb[(size_t)(m0 + m) * DIN + kt + kb * 8];
      *(short8*)&Bs[(kb * 130 + m) * 8] = *(const short8*)&outwb[(size_t)(n0 + m) * DIN + kt + kb * 8];
    }
    __syncthreads();
#pragma unroll
    for (int kw = 0; kw < 2; ++kw) {
      short8 af[4], bfr[4];
#pragma unroll
      for (int i = 0; i < 4; ++i) {
        af[i]  = *(const short8*)&As[((kw * 4 + kq) * 130 + wm + i * 16 + l15) * 8];
        bfr[i] = *(const short8*)&Bs[((kw * 4 + kq) * 130 + wn + i * 16 + l15) * 8];
      }
#pragma unroll
      for (int i = 0; i < 4; ++i)
#pragma unroll
        for (int j = 0; j < 4; ++j)
          acc[i][j] = __builtin_amdgcn_mfma_f32_16x16x32_bf16(af[i], bfr[j], acc[i][j], 0, 0, 0);
    }
    __syncthreads();
  }
  // 2-pass epilogue: 64 rows at a time staged fp32 [64][132]
  float* Cs = ldsf;
#pragma unroll
  for (int pass = 0; pass < 2; ++pass) {
    __syncthreads();
    if ((w & 1) == pass) {
#pragma unroll
      for (int i = 0; i < 4; ++i)
#pragma unroll
        for (int j = 0; j < 4; ++j)
#pragma unroll
          for (int r = 0; r < 4; ++r) {
            const int ml = i * 16 + kq * 4 + r;
            const int n = wn + j * 16 + l15;
            Cs[ml * 132 + n] = acc[i][j][r] + ob[j];
          }
    }
    __syncthreads();
#pragma unroll
    for (int it = 0; it < 8; ++it) {
      const int c = tid + 256 * it;
      const int m = c >> 5, seg = c & 31;
      *(float4*)&out[(size_t)(m0 + pass * 64 + m) * 256 + n0 + seg * 4] =
          *(const float4*)&Cs[m * 132 + seg * 4];
    }
  }
}

// ---------------------------------------------------------------------------
extern "C" void kernel_launch(void* const* d_in, const int* in_sizes, int n_in,
                              void* d_out, int out_size, void* d_ws, size_t ws_size,
                              hipStream_t stream) {
  const float* x      = (const float*)d_in[0];
  const float* Wfx    = (const float*)d_in[1];
  const float* bfx    = (const float*)d_in[2];
  const float* Wx     = (const float*)d_in[3];
  const float* bx     = (const float*)d_in[4];
  const float* Wslice = (const float*)d_in[5];
  const float* bslice = (const float*)d_in[6];
  const float* temp   = (const float*)d_in[7];
  const float* inw    = (const float*)d_in[8];
  const float* convw  = (const float*)d_in[9];
  const float* convb  = (const float*)d_in[10];
  const float* dtbias = (const float*)d_in[11];
  const float* Alog   = (const float*)d_in[12];
  const float* Dp     = (const float*)d_in[13];
  const float* fcdw   = (const float*)d_in[14];
  const float* normw  = (const float*)d_in[15];
  const float* how    = (const float*)d_in[16];
  const float* outw   = (const float*)d_in[17];
  const float* outb   = (const float*)d_in[18];

  unsigned short* us = (unsigned short*)d_ws;
  unsigned short* cb     = us;                   // 33,554,432 (fx|xm token-major)
  unsigned short* swb    = cb + 33554432;        // 16,777,216
  unsigned short* interb = swb + 16777216;       // 16,777,216
  unsigned short* xbfb   = interb + 16777216;    //  8,388,608
  unsigned short* wcatb  = xbfb + 8388608;       //    262,144
  unsigned short* outwbf = wcatb + 262144;       //    131,072
  unsigned short* otTb   = outwbf + 131072;      //    131,072
  float* fbase = (float*)(otTb + 131072);
  float* bcat   = fbase;                          //      1,024
  float* st_raw = bcat + 1024;                    //    131,072
  float* snorm  = st_raw + 131072;                //      2,048
  float* st2    = snorm + 2048;                   //    131,072
  float* zx     = st2 + 131072;                   //    299,008
  float* xbc    = zx + 299008;                    //    163,840
  float* dt2    = xbc + 163840;                   //      4,096
  float* ldA2   = dt2 + 4096;                     //      4,096
  float* ysb    = ldA2 + 4096;                    //    262,144
  float* ygb    = ysb + 262144;                   //    131,072

  hipMemsetAsync(st_raw, 0, (131072 + 2048) * sizeof(float), stream);

  k_cvt   <<<dim3(8577),     256, 0, stream>>>(x, Wfx, Wx, outw, bfx, bx, xbfb, wcatb, outwbf, bcat);
  k_fxxm  <<<dim3(256, 8),   256, 0, stream>>>(xbfb, wcatb, bcat, cb);
  k_sw    <<<dim3(32, 32),   256, 0, stream>>>(cb, Wslice, bslice, temp, swb);
  k_st    <<<dim3(16, 32),   256, 0, stream>>>(swb, cb, st_raw, snorm);
  k_stnorm<<<dim3(512),      256, 0, stream>>>(st_raw, snorm, st2);
  k_inproj<<<dim3(4, 19),    256, 0, stream>>>(st2, inw, zx);
  k_prep  <<<dim3(656),      256, 0, stream>>>(zx, convw, convb, dtbias, Alog, xbc, dt2, ldA2);
  k_ssm   <<<dim3(64),       256, 0, stream>>>(xbc, dt2, ldA2, ysb);
  k_gate  <<<dim3(256),      256, 0, stream>>>(ysb, xbc, zx, fcdw, Dp, normw, ygb);
  k_oproj <<<dim3(4, 8),     256, 0, stream>>>(ygb, how, otTb);
  k_mix   <<<dim3(32, 32),   256, 0, stream>>>(swb, otTb, interb);
  k_final <<<dim3(256, 2),   256, 0, stream>>>(interb, outwbf, outb, (float*)d_out);
}

// Round 6
// 278.780 us; speedup vs baseline: 4.3432x; 1.2016x over previous
//
#include <hip/hip_runtime.h>
#include <hip/hip_bf16.h>
#include <cstdint>
#include <cstddef>

#define Hh 8
#define DIN 512
#define CONVD 640
#define DPROJ 1168
#define NTOK 8192
#define DIM 256

typedef __attribute__((ext_vector_type(8))) short short8;
typedef __attribute__((ext_vector_type(4))) float f32x4;

static __device__ __forceinline__ float sigmoidf_(float x) { return 1.f / (1.f + expf(-x)); }
static __device__ __forceinline__ unsigned short f2b(float f) {
  __hip_bfloat16 h = __float2bfloat16(f);
  return *(unsigned short*)&h;
}
static __device__ __forceinline__ float b2f(unsigned short u) {
  union { unsigned int i; float f; } cv; cv.i = ((unsigned int)u) << 16; return cv.f;
}

// ---------------------------------------------------------------------------
// K0: fp32->bf16: x, Wfx|Wx->wcat, outw, inw, how; bcat = [bfx|bx] (fp32).
__global__ __launch_bounds__(256) void k_cvt(
    const float* __restrict__ x, const float* __restrict__ wfx, const float* __restrict__ wx,
    const float* __restrict__ outw, const float* __restrict__ inw, const float* __restrict__ how,
    const float* __restrict__ bfx, const float* __restrict__ bx,
    unsigned short* __restrict__ xb, unsigned short* __restrict__ wcat,
    unsigned short* __restrict__ outwb, unsigned short* __restrict__ inwb,
    unsigned short* __restrict__ howb, float* __restrict__ bcat) {
  const int e = (blockIdx.x * 256 + threadIdx.x) * 4;
  if (e >= 9641984) {
    const int i = e - 9641984;  // 0..1023
    float4 v;
    if (i < 512) v = *(const float4*)(bfx + i);
    else         v = *(const float4*)(bx + (i - 512));
    *(float4*)(bcat + i) = v;
    return;
  }
  const float* src; unsigned short* dst; int i;
  if (e < 8388608)       { i = e;           src = x;    dst = xb; }
  else if (e < 8519680)  { i = e - 8388608; src = wfx;  dst = wcat; }
  else if (e < 8650752)  { i = e - 8519680; src = wx;   dst = wcat + 131072; }
  else if (e < 8781824)  { i = e - 8650752; src = outw; dst = outwb; }
  else if (e < 9379840)  { i = e - 8781824; src = inw;  dst = inwb; }
  else                   { i = e - 9379840; src = how;  dst = howb; }
  float4 v = *(const float4*)(src + i);
  ushort4 o;
  o.x = f2b(v.x); o.y = f2b(v.y); o.z = f2b(v.z); o.w = f2b(v.w);
  *(ushort4*)(dst + i) = o;
}

// ---------------------------------------------------------------------------
// K1: cb = x @ [W_fx|W_x]^T + bcat, token-major bf16 (32768 x 1024).
__global__ __launch_bounds__(256) void k_fxxm(
    const unsigned short* __restrict__ xb, const unsigned short* __restrict__ wcat,
    const float* __restrict__ bcat, unsigned short* __restrict__ cb) {
  __shared__ unsigned short lds[17408];
  unsigned short* As = lds;              // [kb][130][8]
  unsigned short* Bs = lds + 8320;
  const int tid = threadIdx.x;
  const int m0 = blockIdx.x * 128;
  const int n0 = blockIdx.y * 128;
  const int w = tid >> 6, lane = tid & 63;
  const int l15 = lane & 15, kq = lane >> 4;
  const int wm = (w & 1) * 64, wn = (w >> 1) * 64;
  float bs[4];
#pragma unroll
  for (int j = 0; j < 4; ++j) bs[j] = bcat[n0 + wn + j * 16 + l15];
  f32x4 acc[4][4];
#pragma unroll
  for (int i = 0; i < 4; ++i)
#pragma unroll
    for (int j = 0; j < 4; ++j) acc[i][j] = (f32x4){0.f, 0.f, 0.f, 0.f};
  for (int kt = 0; kt < 256; kt += 64) {
#pragma unroll
    for (int i = 0; i < 4; ++i) {
      const int c = tid + 256 * i, m = c >> 3, kb = c & 7;
      *(short8*)&As[(kb * 130 + m) * 8] = *(const short8*)&xb[(size_t)(m0 + m) * 256 + kt + kb * 8];
      *(short8*)&Bs[(kb * 130 + m) * 8] = *(const short8*)&wcat[(size_t)(n0 + m) * 256 + kt + kb * 8];
    }
    __syncthreads();
#pragma unroll
    for (int kw = 0; kw < 2; ++kw) {
      short8 af[4], bfr[4];
#pragma unroll
      for (int i = 0; i < 4; ++i) {
        af[i]  = *(const short8*)&As[((kw * 4 + kq) * 130 + wm + i * 16 + l15) * 8];
        bfr[i] = *(const short8*)&Bs[((kw * 4 + kq) * 130 + wn + i * 16 + l15) * 8];
      }
#pragma unroll
      for (int i = 0; i < 4; ++i)
#pragma unroll
        for (int j = 0; j < 4; ++j)
          acc[i][j] = __builtin_amdgcn_mfma_f32_16x16x32_bf16(af[i], bfr[j], acc[i][j], 0, 0, 0);
    }
    __syncthreads();
  }
  unsigned short* Cs = lds;
#pragma unroll
  for (int i = 0; i < 4; ++i)
#pragma unroll
    for (int j = 0; j < 4; ++j)
#pragma unroll
      for (int r = 0; r < 4; ++r) {
        const int m = wm + i * 16 + kq * 4 + r;
        const int n = wn + j * 16 + l15;
        Cs[m * 136 + n] = f2b(acc[i][j][r] + bs[j]);
      }
  __syncthreads();
#pragma unroll
  for (int it = 0; it < 8; ++it) {
    const int c = tid + 256 * it;
    const int m = c >> 4, seg = c & 15;
    *(short8*)&cb[(size_t)(m0 + m) * 1024 + n0 + seg * 8] = *(const short8*)&Cs[m * 136 + seg * 8];
  }
}

// ---------------------------------------------------------------------------
// K2: fused score-GEMM + softmax; reads xm part of cb (cols 512..1023).
__global__ __launch_bounds__(256) void k_sw(
    const unsigned short* __restrict__ cb, const float* __restrict__ Wslice,
    const float* __restrict__ bslice, const float* __restrict__ temperature,
    unsigned short* __restrict__ swb) {
  __shared__ unsigned short s_sw[256][72];
  const int tid = threadIdx.x;
  const int bh = blockIdx.y;
  const int b = bh >> 3, h = bh & 7;
  const int n0 = blockIdx.x * 256;
  const int w = tid >> 6, lane = tid & 63;
  const int l15 = lane & 15, kq = lane >> 4;
  const float invt = 1.f / fmaxf(temperature[h], 1e-6f);
  short8 bfr[2][4];
#pragma unroll
  for (int kt = 0; kt < 2; ++kt)
#pragma unroll
    for (int j = 0; j < 4; ++j) {
      const float* wp = Wslice + (j * 16 + l15) * 64 + kt * 32 + kq * 8;
      short8 t;
#pragma unroll
      for (int u = 0; u < 8; ++u) t[u] = (short)f2b(wp[u]);
      bfr[kt][j] = t;
    }
  float bs[4];
#pragma unroll
  for (int j = 0; j < 4; ++j) bs[j] = bslice[j * 16 + l15];
  f32x4 acc[4][4];
#pragma unroll
  for (int i = 0; i < 4; ++i)
#pragma unroll
    for (int j = 0; j < 4; ++j) acc[i][j] = (f32x4){0.f, 0.f, 0.f, 0.f};
#pragma unroll
  for (int kt = 0; kt < 2; ++kt) {
    short8 af[4];
#pragma unroll
    for (int i = 0; i < 4; ++i)
      af[i] = *(const short8*)&cb[((size_t)(b * NTOK) + n0 + w * 64 + i * 16 + l15) * 1024 +
                                  512 + h * 64 + kt * 32 + kq * 8];
#pragma unroll
    for (int i = 0; i < 4; ++i)
#pragma unroll
      for (int j = 0; j < 4; ++j)
        acc[i][j] = __builtin_amdgcn_mfma_f32_16x16x32_bf16(af[i], bfr[kt][j], acc[i][j], 0, 0, 0);
  }
#pragma unroll
  for (int i = 0; i < 4; ++i)
#pragma unroll
    for (int r = 0; r < 4; ++r) {
      float v[4];
      float m = -1e30f;
#pragma unroll
      for (int j = 0; j < 4; ++j) { v[j] = (acc[i][j][r] + bs[j]) * invt; m = fmaxf(m, v[j]); }
#pragma unroll
      for (int off = 8; off; off >>= 1) m = fmaxf(m, __shfl_xor(m, off));
      float s = 0.f;
#pragma unroll
      for (int j = 0; j < 4; ++j) { v[j] = expf(v[j] - m); s += v[j]; }
#pragma unroll
      for (int off = 8; off; off >>= 1) s += __shfl_xor(s, off);
      const float inv = 1.f / s;
      const int row = w * 64 + i * 16 + kq * 4 + r;
#pragma unroll
      for (int j = 0; j < 4; ++j) s_sw[row][j * 16 + l15] = f2b(v[j] * inv);
    }
  __syncthreads();
#pragma unroll
  for (int it = 0; it < 8; ++it) {
    const int c = tid + 256 * it;
    const int row = c >> 3, seg = c & 7;
    *(short8*)&swb[((size_t)bh * NTOK + n0 + row) * 64 + seg * 8] =
        *(const short8*)&s_sw[row][seg * 8];
  }
}

// ---------------------------------------------------------------------------
// K3: st_raw[bh][g][p] = sum_n sw[n,g]*fx[n,p]; snorm[bh][g] = sum_n sw[n,g].
__global__ __launch_bounds__(256) void k_st(
    const unsigned short* __restrict__ swb, const unsigned short* __restrict__ cb,
    float* __restrict__ st_raw, float* __restrict__ snorm) {
  __shared__ unsigned short swT[64][136];
  __shared__ unsigned short fxT[64][136];
  const int tid = threadIdx.x;
  const int bh = blockIdx.y;
  const int b = bh >> 3, h = bh & 7;
  const int nbase = blockIdx.x * 512;
  const int w = tid >> 6, lane = tid & 63;
  const int l15 = lane & 15, kq = lane >> 4;
  f32x4 acc[4];
#pragma unroll
  for (int i = 0; i < 4; ++i) acc[i] = (f32x4){0.f, 0.f, 0.f, 0.f};
  float sn = 0.f;
  for (int nc = 0; nc < 4; ++nc) {
    const int n0 = nbase + nc * 128;
#pragma unroll
    for (int i = 0; i < 4; ++i) {
      const int c = tid + 256 * i, n = c >> 3, gc = c & 7;
      short8 sv = *(const short8*)&swb[((size_t)bh * NTOK + n0 + n) * 64 + gc * 8];
      short8 fv = *(const short8*)&cb[((size_t)(b * NTOK) + n0 + n) * 1024 + h * 64 + gc * 8];
#pragma unroll
      for (int u = 0; u < 8; ++u) {
        swT[gc * 8 + u][n] = (unsigned short)sv[u];
        fxT[gc * 8 + u][n] = (unsigned short)fv[u];
      }
    }
    __syncthreads();
    {
      const int g = tid & 63, q = tid >> 6;
#pragma unroll
      for (int nn = 0; nn < 32; ++nn) sn += b2f(swT[g][q * 32 + nn]);
    }
#pragma unroll
    for (int kw = 0; kw < 4; ++kw) {
      short8 bfr = *(const short8*)&fxT[w * 16 + l15][kw * 32 + kq * 8];
#pragma unroll
      for (int mi = 0; mi < 4; ++mi) {
        short8 af = *(const short8*)&swT[mi * 16 + l15][kw * 32 + kq * 8];
        acc[mi] = __builtin_amdgcn_mfma_f32_16x16x32_bf16(af, bfr, acc[mi], 0, 0, 0);
      }
    }
    __syncthreads();
  }
  float* stp = st_raw + (size_t)bh * 4096;
#pragma unroll
  for (int mi = 0; mi < 4; ++mi)
#pragma unroll
    for (int r = 0; r < 4; ++r)
      atomicAdd(&stp[(mi * 16 + kq * 4 + r) * 64 + w * 16 + l15], acc[mi][r]);
  atomicAdd(&snorm[bh * 64 + (tid & 63)], sn);
}

// ---------------------------------------------------------------------------
// K3b: st2b[b*64+g][h*64+p] = st_raw[b,h,g,p] / (snorm[b,h,g] + 1e-5)  (bf16)
__global__ __launch_bounds__(256) void k_stnorm(
    const float* __restrict__ st_raw, const float* __restrict__ snorm,
    unsigned short* __restrict__ st2b) {
  const int idx = blockIdx.x * 256 + threadIdx.x;
  const int p = idx & 63, g = (idx >> 6) & 63, h = (idx >> 12) & 7, b = idx >> 15;
  const float v = st_raw[idx] / (snorm[(b * Hh + h) * 64 + g] + 1e-5f);
  st2b[(size_t)(b * 64 + g) * DIN + h * 64 + p] = f2b(v);
}

// ---------------------------------------------------------------------------
// K4: zx = st2b (256x512) @ inwb^T (1168x512). MFMA, no LDS. grid (4, 19).
__global__ __launch_bounds__(256) void k_inproj(
    const unsigned short* __restrict__ st2b, const unsigned short* __restrict__ inwb,
    float* __restrict__ zx) {
  const int tid = threadIdx.x;
  const int m0 = blockIdx.x * 64;
  const int n0 = blockIdx.y * 64;
  const int w = tid >> 6, lane = tid & 63;
  const int l15 = lane & 15, kq = lane >> 4;
  f32x4 acc[4];
#pragma unroll
  for (int j = 0; j < 4; ++j) acc[j] = (f32x4){0.f, 0.f, 0.f, 0.f};
  const int arow = m0 + w * 16 + l15;
#pragma unroll
  for (int kc = 0; kc < 16; ++kc) {
    const short8 af = *(const short8*)&st2b[(size_t)arow * DIN + kc * 32 + kq * 8];
#pragma unroll
    for (int j = 0; j < 4; ++j) {
      int brow = n0 + j * 16 + l15;
      if (brow >= DPROJ) brow = 0;
      const short8 bfr = *(const short8*)&inwb[(size_t)brow * DIN + kc * 32 + kq * 8];
      acc[j] = __builtin_amdgcn_mfma_f32_16x16x32_bf16(af, bfr, acc[j], 0, 0, 0);
    }
  }
#pragma unroll
  for (int j = 0; j < 4; ++j)
#pragma unroll
    for (int r = 0; r < 4; ++r) {
      const int m = m0 + w * 16 + kq * 4 + r;
      const int c = n0 + j * 16 + l15;
      if (c < DPROJ) zx[(size_t)m * DPROJ + c] = acc[j][r];
    }
}

// ---------------------------------------------------------------------------
// K4b: conv(k=3)+silu; dt2 / ldA2 (LOG decay).
__global__ __launch_bounds__(256) void k_prep(
    const float* __restrict__ zx, const float* __restrict__ convw, const float* __restrict__ convb,
    const float* __restrict__ dtbias, const float* __restrict__ Alog,
    float* __restrict__ xbc, float* __restrict__ dt2, float* __restrict__ ldA2) {
  const int idx = blockIdx.x * 256 + threadIdx.x;
  const int NCONV = 4 * 64 * CONVD;
  if (idx < NCONV) {
    const int c = idx % CONVD;
    const int l = (idx / CONVD) & 63;
    const int b = idx / (CONVD * 64);
    float acc = convb[c];
#pragma unroll
    for (int k = 0; k < 3; ++k) {
      const int ls = l - 2 + k;
      if (ls >= 0) acc += zx[(size_t)(b * 64 + ls) * DPROJ + DIN + c] * convw[c * 3 + k];
    }
    xbc[idx] = acc * sigmoidf_(acc);
  } else if (idx < NCONV + 8 * 64 * 8) {
    const int j = idx - NCONV;
    const int h = j & 7, l = (j >> 3) & 63, bb = j >> 9;
    float raw;
    if (bb < 4) raw = zx[(size_t)(bb * 64 + l) * DPROJ + 1152 + h];
    else        raw = zx[(size_t)((bb - 4) * 64 + (63 - l)) * DPROJ + 1160 + h];
    const float d = raw + dtbias[h];
    const float sp = (d > 20.f) ? d : log1pf(expf(d));
    dt2[j] = sp;
    ldA2[j] = sp * -expf(Alog[h]);
  }
}

// ---------------------------------------------------------------------------
// K5: SSM via decay-matrix MFMA form. One block per (bb,h).
__global__ __launch_bounds__(256) void k_ssm(
    const float* __restrict__ xbc, const float* __restrict__ dt2, const float* __restrict__ ldA2,
    float* __restrict__ ys) {
  __shared__ unsigned short s_C[64][72];
  __shared__ unsigned short s_Bm[64][72];
  __shared__ unsigned short s_X[64][72];
  __shared__ unsigned short s_G[64][72];
  __shared__ float s_L[64];
  __shared__ float s_dt[64];
  const int blk = blockIdx.x;
  const int h = blk & 7, bb = blk >> 3;
  const int b = (bb < 4) ? bb : bb - 4;
  const bool rev = bb >= 4;
  const int tid = threadIdx.x;
  const int w = tid >> 6, lane = tid & 63;
  const int l15 = lane & 15, kq = lane >> 4;
  {
    const int l = tid >> 2, part = tid & 3;
    const int t = rev ? 63 - l : l;
    const float* src = xbc + (size_t)(b * 64 + l) * CONVD + DIN + part * 32;
#pragma unroll
    for (int u = 0; u < 32; u += 4) {
      float4 v = *(const float4*)(src + u);
      const int c = part * 32 + u;
      unsigned short* dst = (c < 64) ? &s_Bm[t][c] : &s_C[t][c - 64];
      dst[0] = f2b(v.x); dst[1] = f2b(v.y); dst[2] = f2b(v.z); dst[3] = f2b(v.w);
    }
    const float* xs = xbc + (size_t)(b * 64 + l) * CONVD + h * 64 + part * 16;
#pragma unroll
    for (int u = 0; u < 16; u += 4) {
      float4 v = *(const float4*)(xs + u);
      const int p = part * 16 + u;
      s_X[p + 0][t] = f2b(v.x); s_X[p + 1][t] = f2b(v.y);
      s_X[p + 2][t] = f2b(v.z); s_X[p + 3][t] = f2b(v.w);
    }
  }
  if (w == 0) {
    const float dtv = dt2[(bb * 64 + lane) * 8 + h];
    float ld = ldA2[(bb * 64 + lane) * 8 + h];
#pragma unroll
    for (int off = 1; off < 64; off <<= 1) {
      const float o = __shfl_up(ld, off);
      if (lane >= off) ld += o;
    }
    s_L[lane] = ld;
    s_dt[lane] = dtv;
  }
  __syncthreads();
  f32x4 accS[4];
#pragma unroll
  for (int i = 0; i < 4; ++i) accS[i] = (f32x4){0.f, 0.f, 0.f, 0.f};
#pragma unroll
  for (int kw = 0; kw < 2; ++kw) {
    const short8 bfr = *(const short8*)&s_Bm[w * 16 + l15][kw * 32 + kq * 8];
#pragma unroll
    for (int i = 0; i < 4; ++i) {
      const short8 af = *(const short8*)&s_C[i * 16 + l15][kw * 32 + kq * 8];
      accS[i] = __builtin_amdgcn_mfma_f32_16x16x32_bf16(af, bfr, accS[i], 0, 0, 0);
    }
  }
  const int s_idx = w * 16 + l15;
  const float Ls = s_L[s_idx];
  const float dts = s_dt[s_idx];
#pragma unroll
  for (int i = 0; i < 4; ++i)
#pragma unroll
    for (int r = 0; r < 4; ++r) {
      const int t = i * 16 + kq * 4 + r;
      const float g = (s_idx <= t) ? accS[i][r] * expf(s_L[t] - Ls) * dts : 0.f;
      s_G[t][s_idx] = f2b(g);
    }
  __syncthreads();
  f32x4 accY[4];
#pragma unroll
  for (int i = 0; i < 4; ++i) accY[i] = (f32x4){0.f, 0.f, 0.f, 0.f};
#pragma unroll
  for (int kw = 0; kw < 2; ++kw) {
    const short8 bfr = *(const short8*)&s_X[w * 16 + l15][kw * 32 + kq * 8];
#pragma unroll
    for (int i = 0; i < 4; ++i) {
      const short8 af = *(const short8*)&s_G[i * 16 + l15][kw * 32 + kq * 8];
      accY[i] = __builtin_amdgcn_mfma_f32_16x16x32_bf16(af, bfr, accY[i], 0, 0, 0);
    }
  }
#pragma unroll
  for (int i = 0; i < 4; ++i)
#pragma unroll
    for (int r = 0; r < 4; ++r) {
      const int t = i * 16 + kq * 4 + r;
      ys[(((size_t)(bb * 64 + t) * 8 + h) << 6) + w * 16 + l15] = accY[i][r];
    }
}

// ---------------------------------------------------------------------------
// K6a: combine + gate + RMS norm; emits bf16 ygb.
__global__ __launch_bounds__(256) void k_gate(
    const float* __restrict__ ys, const float* __restrict__ xbc, const float* __restrict__ zx,
    const float* __restrict__ fcdw, const float* __restrict__ Dp,
    const float* __restrict__ normw, unsigned short* __restrict__ ygb) {
  __shared__ float red[256][9];
  __shared__ float s_xfc[8];
  const int bl = blockIdx.x;
  const int b = bl >> 6, l = bl & 63;
  const int tid = threadIdx.x;
  const float xog0 = xbc[(size_t)bl * CONVD + tid];
  const float xog1 = xbc[(size_t)bl * CONVD + 256 + tid];
#pragma unroll
  for (int h = 0; h < 8; ++h)
    red[tid][h] = xog0 * fcdw[h * DIN + tid] + xog1 * fcdw[h * DIN + 256 + tid];
  __syncthreads();
  for (int s = 128; s > 0; s >>= 1) {
    if (tid < s) {
#pragma unroll
      for (int h = 0; h < 8; ++h) red[tid][h] += red[tid + s][h];
    }
    __syncthreads();
  }
  if (tid < 8) s_xfc[tid] = red[0][tid] + Dp[tid];
  __syncthreads();
  float ygv[2];
  float sumsq = 0.f;
#pragma unroll
  for (int ci = 0; ci < 2; ++ci) {
    const int c = tid + ci * 256;
    const int h = c >> 6, p = c & 63;
    float yv = 0.f;
    if (l >= 1)  yv += ys[(((size_t)(b * 64 + (l - 1)) * 8 + h) << 6) + p];
    if (l <= 62) yv += ys[(((size_t)((4 + b) * 64 + (62 - l)) * 8 + h) << 6) + p];
    const float xog = (ci == 0) ? xog0 : xog1;
    yv += xog * s_xfc[h];
    const float z = zx[(size_t)bl * DPROJ + c];
    const float g = yv * (z * sigmoidf_(z));
    ygv[ci] = g;
    sumsq += g * g;
  }
  red[tid][0] = sumsq;
  __syncthreads();
  for (int s = 128; s > 0; s >>= 1) {
    if (tid < s) red[tid][0] += red[tid + s][0];
    __syncthreads();
  }
  const float scale = 1.f / sqrtf(red[0][0] / 512.f + 1e-5f);
#pragma unroll
  for (int ci = 0; ci < 2; ++ci) {
    const int c = tid + ci * 256;
    ygb[(size_t)bl * DIN + c] = f2b(ygv[ci] * scale * normw[c]);
  }
}

// ---------------------------------------------------------------------------
// K6b: ot = ygb (256x512) @ howb^T (512x512). MFMA, no LDS staging for inputs.
// Writes otT bf16 [(b,h,p)][g] via LDS transpose. grid (4, 8).
__global__ __launch_bounds__(256) void k_oproj(
    const unsigned short* __restrict__ ygb, const unsigned short* __restrict__ howb,
    unsigned short* __restrict__ otT) {
  __shared__ unsigned short Cs[64][72];
  const int tid = threadIdx.x;
  const int b = blockIdx.x;   // m0 = b*64 (rows b*64+g)
  const int h = blockIdx.y;   // n0 = h*64 (cols h*64+p)
  const int m0 = b * 64, n0 = h * 64;
  const int w = tid >> 6, lane = tid & 63;
  const int l15 = lane & 15, kq = lane >> 4;
  f32x4 acc[4];
#pragma unroll
  for (int j = 0; j < 4; ++j) acc[j] = (f32x4){0.f, 0.f, 0.f, 0.f};
  const int arow = m0 + w * 16 + l15;
#pragma unroll
  for (int kc = 0; kc < 16; ++kc) {
    const short8 af = *(const short8*)&ygb[(size_t)arow * DIN + kc * 32 + kq * 8];
#pragma unroll
    for (int j = 0; j < 4; ++j) {
      const int brow = n0 + j * 16 + l15;
      const short8 bfr = *(const short8*)&howb[(size_t)brow * DIN + kc * 32 + kq * 8];
      acc[j] = __builtin_amdgcn_mfma_f32_16x16x32_bf16(af, bfr, acc[j], 0, 0, 0);
    }
  }
  // stage transpose: Cs[p][g]
#pragma unroll
  for (int j = 0; j < 4; ++j)
#pragma unroll
    for (int r = 0; r < 4; ++r) {
      const int g = w * 16 + kq * 4 + r;   // local row (g)
      const int p = j * 16 + l15;          // local col (p)
      Cs[p][g] = f2b(acc[j][r]);
    }
  __syncthreads();
#pragma unroll
  for (int it = 0; it < 2; ++it) {
    const int c = tid + 256 * it;
    const int p = c >> 3, seg = c & 7;
    *(short8*)&otT[(((size_t)(b * 8 + h) * 64 + p) << 6) + seg * 8] = *(const short8*)&Cs[p][seg * 8];
  }
}

// ---------------------------------------------------------------------------
// K7: inter[b,n,h*64+p] = sum_g sw[bh,n,g]*otT[bh,p,g].
__global__ __launch_bounds__(256) void k_mix(
    const unsigned short* __restrict__ swb, const unsigned short* __restrict__ otT,
    unsigned short* __restrict__ interb) {
  __shared__ unsigned short lds[20736];
  unsigned short* As = lds;              // [kb][258][8]
  unsigned short* Bs = lds + 16512;      // [kb][66][8]
  const int tid = threadIdx.x;
  const int bh = blockIdx.y;
  const int b = bh >> 3, h = bh & 7;
  const int n0 = blockIdx.x * 256;
  const int w = tid >> 6, lane = tid & 63;
  const int l15 = lane & 15, kq = lane >> 4;
#pragma unroll
  for (int i = 0; i < 8; ++i) {
    const int c = tid + 256 * i, m = c >> 3, kb = c & 7;
    *(short8*)&As[(kb * 258 + m) * 8] = *(const short8*)&swb[((size_t)bh * NTOK + n0 + m) * 64 + kb * 8];
  }
#pragma unroll
  for (int i = 0; i < 2; ++i) {
    const int c = tid + 256 * i, p = c >> 3, kb = c & 7;
    *(short8*)&Bs[(kb * 66 + p) * 8] = *(const short8*)&otT[((size_t)bh * 64 + p) * 64 + kb * 8];
  }
  __syncthreads();
  f32x4 acc[4][4];
#pragma unroll
  for (int i = 0; i < 4; ++i)
#pragma unroll
    for (int j = 0; j < 4; ++j) acc[i][j] = (f32x4){0.f, 0.f, 0.f, 0.f};
#pragma unroll
  for (int kw = 0; kw < 2; ++kw) {
    short8 af[4], bfr[4];
#pragma unroll
    for (int i = 0; i < 4; ++i) {
      af[i]  = *(const short8*)&As[((kw * 4 + kq) * 258 + w * 64 + i * 16 + l15) * 8];
      bfr[i] = *(const short8*)&Bs[((kw * 4 + kq) * 66 + i * 16 + l15) * 8];
    }
#pragma unroll
    for (int i = 0; i < 4; ++i)
#pragma unroll
      for (int j = 0; j < 4; ++j)
        acc[i][j] = __builtin_amdgcn_mfma_f32_16x16x32_bf16(af[i], bfr[j], acc[i][j], 0, 0, 0);
  }
  __syncthreads();
  unsigned short* Cs = lds;
#pragma unroll
  for (int i = 0; i < 4; ++i)
#pragma unroll
    for (int j = 0; j < 4; ++j)
#pragma unroll
      for (int r = 0; r < 4; ++r) {
        const int m = w * 64 + i * 16 + kq * 4 + r;
        const int n = j * 16 + l15;
        Cs[m * 72 + n] = f2b(acc[i][j][r]);
      }
  __syncthreads();
#pragma unroll
  for (int it = 0; it < 8; ++it) {
    const int c = tid + 256 * it;
    const int row = c >> 3, seg = c & 7;
    *(short8*)&interb[((size_t)(b * NTOK) + n0 + row) * 512 + h * 64 + seg * 8] =
        *(const short8*)&Cs[row * 72 + seg * 8];
  }
}

// ---------------------------------------------------------------------------
// K8: out = inter @ out_w^T + out_b.
__global__ __launch_bounds__(256) void k_final(
    const unsigned short* __restrict__ interb, const unsigned short* __restrict__ outwb,
    const float* __restrict__ outb, float* __restrict__ out) {
  __shared__ float ldsf[8448];
  unsigned short* ls = (unsigned short*)ldsf;
  unsigned short* As = ls;               // [kb][130][8]
  unsigned short* Bs = ls + 8320;
  const int tid = threadIdx.x;
  const int m0 = blockIdx.x * 128;
  const int n0 = blockIdx.y * 128;
  const int w = tid >> 6, lane = tid & 63;
  const int l15 = lane & 15, kq = lane >> 4;
  const int wm = (w & 1) * 64, wn = (w >> 1) * 64;
  float ob[4];
#pragma unroll
  for (int j = 0; j < 4; ++j) ob[j] = outb[n0 + wn + j * 16 + l15];
  f32x4 acc[4][4];
#pragma unroll
  for (int i = 0; i < 4; ++i)
#pragma unroll
    for (int j = 0; j < 4; ++j) acc[i][j] = (f32x4){0.f, 0.f, 0.f, 0.f};
  for (int kt = 0; kt < DIN; kt += 64) {
#pragma unroll
    for (int i = 0; i < 4; ++i) {
      const int c = tid + 256 * i, m = c >> 3, kb = c & 7;
      *(short8*)&As[(kb * 130 + m) * 8] = *(const short8*)&interb[(size_t)(m0 + m) * DIN + kt + kb * 8];
      *(short8*)&Bs[(kb * 130 + m) * 8] = *(const short8*)&outwb[(size_t)(n0 + m) * DIN + kt + kb * 8];
    }
    __syncthreads();
#pragma unroll
    for (int kw = 0; kw < 2; ++kw) {
      short8 af[4], bfr[4];
#pragma unroll
      for (int i = 0; i < 4; ++i) {
        af[i]  = *(const short8*)&As[((kw * 4 + kq) * 130 + wm + i * 16 + l15) * 8];
        bfr[i] = *(const short8*)&Bs[((kw * 4 + kq) * 130 + wn + i * 16 + l15) * 8];
      }
#pragma unroll
      for (int i = 0; i < 4; ++i)
#pragma unroll
        for (int j = 0; j < 4; ++j)
          acc[i][j] = __builtin_amdgcn_mfma_f32_16x16x32_bf16(af[i], bfr[j], acc[i][j], 0, 0, 0);
    }
    __syncthreads();
  }
  float* Cs = ldsf;
#pragma unroll
  for (int pass = 0; pass < 2; ++pass) {
    __syncthreads();
    if ((w & 1) == pass) {
#pragma unroll
      for (int i = 0; i < 4; ++i)
#pragma unroll
        for (int j = 0; j < 4; ++j)
#pragma unroll
          for (int r = 0; r < 4; ++r) {
            const int ml = i * 16 + kq * 4 + r;
            const int n = wn + j * 16 + l15;
            Cs[ml * 132 + n] = acc[i][j][r] + ob[j];
          }
    }
    __syncthreads();
#pragma unroll
    for (int it = 0; it < 8; ++it) {
      const int c = tid + 256 * it;
      const int m = c >> 5, seg = c & 31;
      *(float4*)&out[(size_t)(m0 + pass * 64 + m) * 256 + n0 + seg * 4] =
          *(const float4*)&Cs[m * 132 + seg * 4];
    }
  }
}

// ---------------------------------------------------------------------------
extern "C" void kernel_launch(void* const* d_in, const int* in_sizes, int n_in,
                              void* d_out, int out_size, void* d_ws, size_t ws_size,
                              hipStream_t stream) {
  const float* x      = (const float*)d_in[0];
  const float* Wfx    = (const float*)d_in[1];
  const float* bfx    = (const float*)d_in[2];
  const float* Wx     = (const float*)d_in[3];
  const float* bx     = (const float*)d_in[4];
  const float* Wslice = (const float*)d_in[5];
  const float* bslice = (const float*)d_in[6];
  const float* temp   = (const float*)d_in[7];
  const float* inw    = (const float*)d_in[8];
  const float* convw  = (const float*)d_in[9];
  const float* convb  = (const float*)d_in[10];
  const float* dtbias = (const float*)d_in[11];
  const float* Alog   = (const float*)d_in[12];
  const float* Dp     = (const float*)d_in[13];
  const float* fcdw   = (const float*)d_in[14];
  const float* normw  = (const float*)d_in[15];
  const float* how    = (const float*)d_in[16];
  const float* outw   = (const float*)d_in[17];
  const float* outb   = (const float*)d_in[18];

  unsigned short* us = (unsigned short*)d_ws;
  unsigned short* cb     = us;                   // 33,554,432
  unsigned short* swb    = cb + 33554432;        // 16,777,216
  unsigned short* interb = swb + 16777216;       // 16,777,216
  unsigned short* xbfb   = interb + 16777216;    //  8,388,608
  unsigned short* wcatb  = xbfb + 8388608;       //    262,144
  unsigned short* outwbf = wcatb + 262144;       //    131,072
  unsigned short* otTb   = outwbf + 131072;      //    131,072
  unsigned short* inwb   = otTb + 131072;        //    598,016
  unsigned short* howb   = inwb + 598016;        //    262,144
  unsigned short* st2b   = howb + 262144;        //    131,072
  unsigned short* ygbb   = st2b + 131072;        //    131,072
  float* fbase = (float*)(ygbb + 131072);
  float* bcat   = fbase;                          //      1,024
  float* st_raw = bcat + 1024;                    //    131,072
  float* snorm  = st_raw + 131072;                //      2,048
  float* zx     = snorm + 2048;                   //    299,008
  float* xbc    = zx + 299008;                    //    163,840
  float* dt2    = xbc + 163840;                   //      4,096
  float* ldA2   = dt2 + 4096;                     //      4,096
  float* ysb    = ldA2 + 4096;                    //    262,144

  hipMemsetAsync(st_raw, 0, (131072 + 2048) * sizeof(float), stream);

  k_cvt   <<<dim3(9417),     256, 0, stream>>>(x, Wfx, Wx, outw, inw, how, bfx, bx,
                                               xbfb, wcatb, outwbf, inwb, howb, bcat);
  k_fxxm  <<<dim3(256, 8),   256, 0, stream>>>(xbfb, wcatb, bcat, cb);
  k_sw    <<<dim3(32, 32),   256, 0, stream>>>(cb, Wslice, bslice, temp, swb);
  k_st    <<<dim3(16, 32),   256, 0, stream>>>(swb, cb, st_raw, snorm);
  k_stnorm<<<dim3(512),      256, 0, stream>>>(st_raw, snorm, st2b);
  k_inproj<<<dim3(4, 19),    256, 0, stream>>>(st2b, inwb, zx);
  k_prep  <<<dim3(656),      256, 0, stream>>>(zx, convw, convb, dtbias, Alog, xbc, dt2, ldA2);
  k_ssm   <<<dim3(64),       256, 0, stream>>>(xbc, dt2, ldA2, ysb);
  k_gate  <<<dim3(256),      256, 0, stream>>>(ysb, xbc, zx, fcdw, Dp, normw, ygbb);
  k_oproj <<<dim3(4, 8),     256, 0, stream>>>(ygbb, howb, otTb);
  k_mix   <<<dim3(32, 32),   256, 0, stream>>>(swb, otTb, interb);
  k_final <<<dim3(256, 2),   256, 0, stream>>>(interb, outwbf, outb, (float*)d_out);
}

// Round 8
// 267.666 us; speedup vs baseline: 4.5236x; 1.0415x over previous
//
#include <hip/hip_runtime.h>
#include <hip/hip_bf16.h>
#include <cstdint>
#include <cstddef>

#define Hh 8
#define DIN 512
#define CONVD 640
#define DPROJ 1168
#define NTOK 8192
#define DIM 256

typedef __attribute__((ext_vector_type(8))) short short8;
typedef __attribute__((ext_vector_type(4))) float f32x4;

static __device__ __forceinline__ float sigmoidf_(float x) { return 1.f / (1.f + expf(-x)); }
static __device__ __forceinline__ unsigned short f2b(float f) {
  __hip_bfloat16 h = __float2bfloat16(f);
  return *(unsigned short*)&h;
}
static __device__ __forceinline__ float b2f(unsigned short u) {
  union { unsigned int i; float f; } cv; cv.i = ((unsigned int)u) << 16; return cv.f;
}

// ---------------------------------------------------------------------------
// K0: weights fp32->bf16: [Wfx|Wx]->wcat, outw, inw, how; bcat=[bfx|bx] fp32.
__global__ __launch_bounds__(256) void k_cvt(
    const float* __restrict__ wfx, const float* __restrict__ wx, const float* __restrict__ outw,
    const float* __restrict__ inw, const float* __restrict__ how,
    const float* __restrict__ bfx, const float* __restrict__ bx,
    unsigned short* __restrict__ wcat, unsigned short* __restrict__ outwb,
    unsigned short* __restrict__ inwb, unsigned short* __restrict__ howb,
    float* __restrict__ bcat) {
  const int e = (blockIdx.x * 256 + threadIdx.x) * 4;
  if (e >= 1253376) {
    const int i = e - 1253376;  // 0..1023
    float4 v;
    if (i < 512) v = *(const float4*)(bfx + i);
    else         v = *(const float4*)(bx + (i - 512));
    *(float4*)(bcat + i) = v;
    return;
  }
  const float* src; unsigned short* dst; int i;
  if (e < 131072)        { i = e;           src = wfx;  dst = wcat; }
  else if (e < 262144)   { i = e - 131072;  src = wx;   dst = wcat + 131072; }
  else if (e < 393216)   { i = e - 262144;  src = outw; dst = outwb; }
  else if (e < 991232)   { i = e - 393216;  src = inw;  dst = inwb; }
  else                   { i = e - 991232;  src = how;  dst = howb; }
  float4 v = *(const float4*)(src + i);
  ushort4 o;
  o.x = f2b(v.x); o.y = f2b(v.y); o.z = f2b(v.z); o.w = f2b(v.w);
  *(ushort4*)(dst + i) = o;
}

// ---------------------------------------------------------------------------
// K1: fused front GEMM. C = x @ [W_fx|W_x]^T + bias (M=32768, N=1024, K=256).
// y<4: write fx cols to cb (pitch 512). y>=4: compute scores+softmax in-block
// (two heads per block) and write swb; xm never goes to global.
__global__ __launch_bounds__(256) void k_front(
    const float* __restrict__ x, const unsigned short* __restrict__ wcat,
    const float* __restrict__ bcat, const float* __restrict__ Wslice,
    const float* __restrict__ bslice, const float* __restrict__ temperature,
    unsigned short* __restrict__ cb, unsigned short* __restrict__ swb) {
  __shared__ unsigned short lds[17408];  // As/Bs staging, then Cs [128][136]
  unsigned short* As = lds;              // [kb][130][8]
  unsigned short* Bs = lds + 8320;
  const int tid = threadIdx.x;
  const int m0 = blockIdx.x * 128;
  const int n0 = blockIdx.y * 128;
  const int w = tid >> 6, lane = tid & 63;
  const int l15 = lane & 15, kq = lane >> 4;
  const int wm = (w & 1) * 64, wn = (w >> 1) * 64;
  float bs[4];
#pragma unroll
  for (int j = 0; j < 4; ++j) bs[j] = bcat[n0 + wn + j * 16 + l15];
  f32x4 acc[4][4];
#pragma unroll
  for (int i = 0; i < 4; ++i)
#pragma unroll
    for (int j = 0; j < 4; ++j) acc[i][j] = (f32x4){0.f, 0.f, 0.f, 0.f};
  for (int kt = 0; kt < 256; kt += 64) {
#pragma unroll
    for (int i = 0; i < 4; ++i) {
      const int c = tid + 256 * i, m = c >> 3, kb = c & 7;
      // A: fp32 x -> bf16 in-reg
      const float* xs = &x[(size_t)(m0 + m) * 256 + kt + kb * 8];
      float4 v0 = *(const float4*)xs;
      float4 v1 = *(const float4*)(xs + 4);
      short8 av;
      av[0] = (short)f2b(v0.x); av[1] = (short)f2b(v0.y);
      av[2] = (short)f2b(v0.z); av[3] = (short)f2b(v0.w);
      av[4] = (short)f2b(v1.x); av[5] = (short)f2b(v1.y);
      av[6] = (short)f2b(v1.z); av[7] = (short)f2b(v1.w);
      *(short8*)&As[(kb * 130 + m) * 8] = av;
      *(short8*)&Bs[(kb * 130 + m) * 8] = *(const short8*)&wcat[(size_t)(n0 + m) * 256 + kt + kb * 8];
    }
    __syncthreads();
#pragma unroll
    for (int kw = 0; kw < 2; ++kw) {
      short8 af[4], bfr[4];
#pragma unroll
      for (int i = 0; i < 4; ++i) {
        af[i]  = *(const short8*)&As[((kw * 4 + kq) * 130 + wm + i * 16 + l15) * 8];
        bfr[i] = *(const short8*)&Bs[((kw * 4 + kq) * 130 + wn + i * 16 + l15) * 8];
      }
#pragma unroll
      for (int i = 0; i < 4; ++i)
#pragma unroll
        for (int j = 0; j < 4; ++j)
          acc[i][j] = __builtin_amdgcn_mfma_f32_16x16x32_bf16(af[i], bfr[j], acc[i][j], 0, 0, 0);
    }
    __syncthreads();
  }
  // epilogue: C (+bias) -> Cs [128][136]
  unsigned short* Cs = lds;
#pragma unroll
  for (int i = 0; i < 4; ++i)
#pragma unroll
    for (int j = 0; j < 4; ++j)
#pragma unroll
      for (int r = 0; r < 4; ++r) {
        const int m = wm + i * 16 + kq * 4 + r;
        const int n = wn + j * 16 + l15;
        Cs[m * 136 + n] = f2b(acc[i][j][r] + bs[j]);
      }
  __syncthreads();
  if (blockIdx.y < 4) {
    // fx: coalesced stores, cb pitch 512. Full 128x128 tile (16 segs of 8).
#pragma unroll
    for (int it = 0; it < 8; ++it) {
      const int c = tid + 256 * it;
      const int m = c >> 4, seg = c & 15;
      *(short8*)&cb[(size_t)(m0 + m) * 512 + n0 + seg * 8] = *(const short8*)&Cs[m * 136 + seg * 8];
    }
    return;
  }
  // ---- fused scores + softmax for two heads ----
  const int h0 = (n0 - 512) >> 6;  // first head of this col-tile
  const int bidx = m0 >> 13, nb = m0 & (NTOK - 1);
  short8 sbfr[2][4];
#pragma unroll
  for (int kt = 0; kt < 2; ++kt)
#pragma unroll
    for (int j = 0; j < 4; ++j) {
      const float* wp = Wslice + (j * 16 + l15) * 64 + kt * 32 + kq * 8;
      short8 t;
#pragma unroll
      for (int u = 0; u < 8; ++u) t[u] = (short)f2b(wp[u]);
      sbfr[kt][j] = t;
    }
  float sbs[4];
#pragma unroll
  for (int j = 0; j < 4; ++j) sbs[j] = bslice[j * 16 + l15];
  f32x4 sacc[2][2][4];
#pragma unroll
  for (int hl = 0; hl < 2; ++hl)
#pragma unroll
    for (int i = 0; i < 2; ++i)
#pragma unroll
      for (int j = 0; j < 4; ++j) sacc[hl][i][j] = (f32x4){0.f, 0.f, 0.f, 0.f};
#pragma unroll
  for (int hl = 0; hl < 2; ++hl)
#pragma unroll
    for (int kt = 0; kt < 2; ++kt) {
      short8 af[2];
#pragma unroll
      for (int i = 0; i < 2; ++i)
        af[i] = *(const short8*)&Cs[(w * 32 + i * 16 + l15) * 136 + hl * 64 + kt * 32 + kq * 8];
#pragma unroll
      for (int i = 0; i < 2; ++i)
#pragma unroll
        for (int j = 0; j < 4; ++j)
          sacc[hl][i][j] = __builtin_amdgcn_mfma_f32_16x16x32_bf16(af[i], sbfr[kt][j], sacc[hl][i][j], 0, 0, 0);
    }
  __syncthreads();  // all reads of Cs done; reuse Cs for softmax output
#pragma unroll
  for (int hl = 0; hl < 2; ++hl) {
    const float invt = 1.f / fmaxf(temperature[h0 + hl], 1e-6f);
#pragma unroll
    for (int i = 0; i < 2; ++i)
#pragma unroll
      for (int r = 0; r < 4; ++r) {
        float v[4];
        float m = -1e30f;
#pragma unroll
        for (int j = 0; j < 4; ++j) { v[j] = (sacc[hl][i][j][r] + sbs[j]) * invt; m = fmaxf(m, v[j]); }
#pragma unroll
        for (int off = 8; off; off >>= 1) m = fmaxf(m, __shfl_xor(m, off));
        float s = 0.f;
#pragma unroll
        for (int j = 0; j < 4; ++j) { v[j] = expf(v[j] - m); s += v[j]; }
#pragma unroll
        for (int off = 8; off; off >>= 1) s += __shfl_xor(s, off);
        const float inv = 1.f / s;
        const int row = w * 32 + i * 16 + kq * 4 + r;
#pragma unroll
        for (int j = 0; j < 4; ++j) Cs[row * 136 + hl * 64 + j * 16 + l15] = f2b(v[j] * inv);
      }
  }
  __syncthreads();
#pragma unroll
  for (int it = 0; it < 8; ++it) {
    const int c = tid + 256 * it;          // 2048 = 2 heads x 128 rows x 8 segs
    const int head = c >> 10, row = (c >> 3) & 127, seg = c & 7;
    *(short8*)&swb[((size_t)(bidx * 8 + h0 + head) * NTOK + nb + row) * 64 + seg * 8] =
        *(const short8*)&Cs[row * 136 + head * 64 + seg * 8];
  }
}

// ---------------------------------------------------------------------------
// K3: st_raw[bh][g][p] = sum_n sw[n,g]*fx[n,p]; snorm[bh][g] = sum_n sw[n,g].
__global__ __launch_bounds__(256) void k_st(
    const unsigned short* __restrict__ swb, const unsigned short* __restrict__ cb,
    float* __restrict__ st_raw, float* __restrict__ snorm) {
  __shared__ unsigned short swT[64][136];
  __shared__ unsigned short fxT[64][136];
  const int tid = threadIdx.x;
  const int bh = blockIdx.y;
  const int b = bh >> 3, h = bh & 7;
  const int nbase = blockIdx.x * 512;
  const int w = tid >> 6, lane = tid & 63;
  const int l15 = lane & 15, kq = lane >> 4;
  f32x4 acc[4];
#pragma unroll
  for (int i = 0; i < 4; ++i) acc[i] = (f32x4){0.f, 0.f, 0.f, 0.f};
  float sn = 0.f;
  for (int nc = 0; nc < 4; ++nc) {
    const int n0 = nbase + nc * 128;
#pragma unroll
    for (int i = 0; i < 4; ++i) {
      const int c = tid + 256 * i, n = c >> 3, gc = c & 7;
      short8 sv = *(const short8*)&swb[((size_t)bh * NTOK + n0 + n) * 64 + gc * 8];
      short8 fv = *(const short8*)&cb[((size_t)(b * NTOK) + n0 + n) * 512 + h * 64 + gc * 8];
#pragma unroll
      for (int u = 0; u < 8; ++u) {
        swT[gc * 8 + u][n] = (unsigned short)sv[u];
        fxT[gc * 8 + u][n] = (unsigned short)fv[u];
      }
    }
    __syncthreads();
    {
      const int g = tid & 63, q = tid >> 6;
#pragma unroll
      for (int nn = 0; nn < 32; ++nn) sn += b2f(swT[g][q * 32 + nn]);
    }
#pragma unroll
    for (int kw = 0; kw < 4; ++kw) {
      short8 bfr = *(const short8*)&fxT[w * 16 + l15][kw * 32 + kq * 8];
#pragma unroll
      for (int mi = 0; mi < 4; ++mi) {
        short8 af = *(const short8*)&swT[mi * 16 + l15][kw * 32 + kq * 8];
        acc[mi] = __builtin_amdgcn_mfma_f32_16x16x32_bf16(af, bfr, acc[mi], 0, 0, 0);
      }
    }
    __syncthreads();
  }
  float* stp = st_raw + (size_t)bh * 4096;
#pragma unroll
  for (int mi = 0; mi < 4; ++mi)
#pragma unroll
    for (int r = 0; r < 4; ++r)
      atomicAdd(&stp[(mi * 16 + kq * 4 + r) * 64 + w * 16 + l15], acc[mi][r]);
  atomicAdd(&snorm[bh * 64 + (tid & 63)], sn);
}

// ---------------------------------------------------------------------------
// K3b: st2b[b*64+g][h*64+p] = st_raw / (snorm + 1e-5)  (bf16)
__global__ __launch_bounds__(256) void k_stnorm(
    const float* __restrict__ st_raw, const float* __restrict__ snorm,
    unsigned short* __restrict__ st2b) {
  const int idx = blockIdx.x * 256 + threadIdx.x;
  const int p = idx & 63, g = (idx >> 6) & 63, h = (idx >> 12) & 7, b = idx >> 15;
  const float v = st_raw[idx] / (snorm[(b * Hh + h) * 64 + g] + 1e-5f);
  st2b[(size_t)(b * 64 + g) * DIN + h * 64 + p] = f2b(v);
}

// ---------------------------------------------------------------------------
// K4: zx = st2b (256x512) @ inwb^T (1168x512). MFMA, no LDS.
__global__ __launch_bounds__(256) void k_inproj(
    const unsigned short* __restrict__ st2b, const unsigned short* __restrict__ inwb,
    float* __restrict__ zx) {
  const int tid = threadIdx.x;
  const int m0 = blockIdx.x * 64;
  const int n0 = blockIdx.y * 64;
  const int w = tid >> 6, lane = tid & 63;
  const int l15 = lane & 15, kq = lane >> 4;
  f32x4 acc[4];
#pragma unroll
  for (int j = 0; j < 4; ++j) acc[j] = (f32x4){0.f, 0.f, 0.f, 0.f};
  const int arow = m0 + w * 16 + l15;
#pragma unroll
  for (int kc = 0; kc < 16; ++kc) {
    const short8 af = *(const short8*)&st2b[(size_t)arow * DIN + kc * 32 + kq * 8];
#pragma unroll
    for (int j = 0; j < 4; ++j) {
      int brow = n0 + j * 16 + l15;
      if (brow >= DPROJ) brow = 0;
      const short8 bfr = *(const short8*)&inwb[(size_t)brow * DIN + kc * 32 + kq * 8];
      acc[j] = __builtin_amdgcn_mfma_f32_16x16x32_bf16(af, bfr, acc[j], 0, 0, 0);
    }
  }
#pragma unroll
  for (int j = 0; j < 4; ++j)
#pragma unroll
    for (int r = 0; r < 4; ++r) {
      const int m = m0 + w * 16 + kq * 4 + r;
      const int c = n0 + j * 16 + l15;
      if (c < DPROJ) zx[(size_t)m * DPROJ + c] = acc[j][r];
    }
}

// ---------------------------------------------------------------------------
// K4b: conv(k=3)+silu; dt2 / ldA2 (LOG decay).
__global__ __launch_bounds__(256) void k_prep(
    const float* __restrict__ zx, const float* __restrict__ convw, const float* __restrict__ convb,
    const float* __restrict__ dtbias, const float* __restrict__ Alog,
    float* __restrict__ xbc, float* __restrict__ dt2, float* __restrict__ ldA2) {
  const int idx = blockIdx.x * 256 + threadIdx.x;
  const int NCONV = 4 * 64 * CONVD;
  if (idx < NCONV) {
    const int c = idx % CONVD;
    const int l = (idx / CONVD) & 63;
    const int b = idx / (CONVD * 64);
    float acc = convb[c];
#pragma unroll
    for (int k = 0; k < 3; ++k) {
      const int ls = l - 2 + k;
      if (ls >= 0) acc += zx[(size_t)(b * 64 + ls) * DPROJ + DIN + c] * convw[c * 3 + k];
    }
    xbc[idx] = acc * sigmoidf_(acc);
  } else if (idx < NCONV + 8 * 64 * 8) {
    const int j = idx - NCONV;
    const int h = j & 7, l = (j >> 3) & 63, bb = j >> 9;
    float raw;
    if (bb < 4) raw = zx[(size_t)(bb * 64 + l) * DPROJ + 1152 + h];
    else        raw = zx[(size_t)((bb - 4) * 64 + (63 - l)) * DPROJ + 1160 + h];
    const float d = raw + dtbias[h];
    const float sp = (d > 20.f) ? d : log1pf(expf(d));
    dt2[j] = sp;
    ldA2[j] = sp * -expf(Alog[h]);
  }
}

// ---------------------------------------------------------------------------
// K5: SSM via decay-matrix MFMA form. One block per (bb,h).
__global__ __launch_bounds__(256) void k_ssm(
    const float* __restrict__ xbc, const float* __restrict__ dt2, const float* __restrict__ ldA2,
    float* __restrict__ ys) {
  __shared__ unsigned short s_C[64][72];
  __shared__ unsigned short s_Bm[64][72];
  __shared__ unsigned short s_X[64][72];
  __shared__ unsigned short s_G[64][72];
  __shared__ float s_L[64];
  __shared__ float s_dt[64];
  const int blk = blockIdx.x;
  const int h = blk & 7, bb = blk >> 3;
  const int b = (bb < 4) ? bb : bb - 4;
  const bool rev = bb >= 4;
  const int tid = threadIdx.x;
  const int w = tid >> 6, lane = tid & 63;
  const int l15 = lane & 15, kq = lane >> 4;
  {
    const int l = tid >> 2, part = tid & 3;
    const int t = rev ? 63 - l : l;
    const float* src = xbc + (size_t)(b * 64 + l) * CONVD + DIN + part * 32;
#pragma unroll
    for (int u = 0; u < 32; u += 4) {
      float4 v = *(const float4*)(src + u);
      const int c = part * 32 + u;
      unsigned short* dst = (c < 64) ? &s_Bm[t][c] : &s_C[t][c - 64];
      dst[0] = f2b(v.x); dst[1] = f2b(v.y); dst[2] = f2b(v.z); dst[3] = f2b(v.w);
    }
    const float* xs = xbc + (size_t)(b * 64 + l) * CONVD + h * 64 + part * 16;
#pragma unroll
    for (int u = 0; u < 16; u += 4) {
      float4 v = *(const float4*)(xs + u);
      const int p = part * 16 + u;
      s_X[p + 0][t] = f2b(v.x); s_X[p + 1][t] = f2b(v.y);
      s_X[p + 2][t] = f2b(v.z); s_X[p + 3][t] = f2b(v.w);
    }
  }
  if (w == 0) {
    const float dtv = dt2[(bb * 64 + lane) * 8 + h];
    float ld = ldA2[(bb * 64 + lane) * 8 + h];
#pragma unroll
    for (int off = 1; off < 64; off <<= 1) {
      const float o = __shfl_up(ld, off);
      if (lane >= off) ld += o;
    }
    s_L[lane] = ld;
    s_dt[lane] = dtv;
  }
  __syncthreads();
  f32x4 accS[4];
#pragma unroll
  for (int i = 0; i < 4; ++i) accS[i] = (f32x4){0.f, 0.f, 0.f, 0.f};
#pragma unroll
  for (int kw = 0; kw < 2; ++kw) {
    const short8 bfr = *(const short8*)&s_Bm[w * 16 + l15][kw * 32 + kq * 8];
#pragma unroll
    for (int i = 0; i < 4; ++i) {
      const short8 af = *(const short8*)&s_C[i * 16 + l15][kw * 32 + kq * 8];
      accS[i] = __builtin_amdgcn_mfma_f32_16x16x32_bf16(af, bfr, accS[i], 0, 0, 0);
    }
  }
  const int s_idx = w * 16 + l15;
  const float Ls = s_L[s_idx];
  const float dts = s_dt[s_idx];
#pragma unroll
  for (int i = 0; i < 4; ++i)
#pragma unroll
    for (int r = 0; r < 4; ++r) {
      const int t = i * 16 + kq * 4 + r;
      const float g = (s_idx <= t) ? accS[i][r] * expf(s_L[t] - Ls) * dts : 0.f;
      s_G[t][s_idx] = f2b(g);
    }
  __syncthreads();
  f32x4 accY[4];
#pragma unroll
  for (int i = 0; i < 4; ++i) accY[i] = (f32x4){0.f, 0.f, 0.f, 0.f};
#pragma unroll
  for (int kw = 0; kw < 2; ++kw) {
    const short8 bfr = *(const short8*)&s_X[w * 16 + l15][kw * 32 + kq * 8];
#pragma unroll
    for (int i = 0; i < 4; ++i) {
      const short8 af = *(const short8*)&s_G[i * 16 + l15][kw * 32 + kq * 8];
      accY[i] = __builtin_amdgcn_mfma_f32_16x16x32_bf16(af, bfr, accY[i], 0, 0, 0);
    }
  }
#pragma unroll
  for (int i = 0; i < 4; ++i)
#pragma unroll
    for (int r = 0; r < 4; ++r) {
      const int t = i * 16 + kq * 4 + r;
      ys[(((size_t)(bb * 64 + t) * 8 + h) << 6) + w * 16 + l15] = accY[i][r];
    }
}

// ---------------------------------------------------------------------------
// K6a: combine + gate + RMS norm; emits bf16 ygb.
__global__ __launch_bounds__(256) void k_gate(
    const float* __restrict__ ys, const float* __restrict__ xbc, const float* __restrict__ zx,
    const float* __restrict__ fcdw, const float* __restrict__ Dp,
    const float* __restrict__ normw, unsigned short* __restrict__ ygb) {
  __shared__ float red[256][9];
  __shared__ float s_xfc[8];
  const int bl = blockIdx.x;
  const int b = bl >> 6, l = bl & 63;
  const int tid = threadIdx.x;
  const float xog0 = xbc[(size_t)bl * CONVD + tid];
  const float xog1 = xbc[(size_t)bl * CONVD + 256 + tid];
#pragma unroll
  for (int h = 0; h < 8; ++h)
    red[tid][h] = xog0 * fcdw[h * DIN + tid] + xog1 * fcdw[h * DIN + 256 + tid];
  __syncthreads();
  for (int s = 128; s > 0; s >>= 1) {
    if (tid < s) {
#pragma unroll
      for (int h = 0; h < 8; ++h) red[tid][h] += red[tid + s][h];
    }
    __syncthreads();
  }
  if (tid < 8) s_xfc[tid] = red[0][tid] + Dp[tid];
  __syncthreads();
  float ygv[2];
  float sumsq = 0.f;
#pragma unroll
  for (int ci = 0; ci < 2; ++ci) {
    const int c = tid + ci * 256;
    const int h = c >> 6, p = c & 63;
    float yv = 0.f;
    if (l >= 1)  yv += ys[(((size_t)(b * 64 + (l - 1)) * 8 + h) << 6) + p];
    if (l <= 62) yv += ys[(((size_t)((4 + b) * 64 + (62 - l)) * 8 + h) << 6) + p];
    const float xog = (ci == 0) ? xog0 : xog1;
    yv += xog * s_xfc[h];
    const float z = zx[(size_t)bl * DPROJ + c];
    const float g = yv * (z * sigmoidf_(z));
    ygv[ci] = g;
    sumsq += g * g;
  }
  red[tid][0] = sumsq;
  __syncthreads();
  for (int s = 128; s > 0; s >>= 1) {
    if (tid < s) red[tid][0] += red[tid + s][0];
    __syncthreads();
  }
  const float scale = 1.f / sqrtf(red[0][0] / 512.f + 1e-5f);
#pragma unroll
  for (int ci = 0; ci < 2; ++ci) {
    const int c = tid + ci * 256;
    ygb[(size_t)bl * DIN + c] = f2b(ygv[ci] * scale * normw[c]);
  }
}

// ---------------------------------------------------------------------------
// K6b: ot = ygb (256x512) @ howb^T. Writes otT bf16 [(b,h,p)][g]. grid (4,8).
__global__ __launch_bounds__(256) void k_oproj(
    const unsigned short* __restrict__ ygb, const unsigned short* __restrict__ howb,
    unsigned short* __restrict__ otT) {
  __shared__ unsigned short Cs[64][72];
  const int tid = threadIdx.x;
  const int b = blockIdx.x;
  const int h = blockIdx.y;
  const int m0 = b * 64, n0 = h * 64;
  const int w = tid >> 6, lane = tid & 63;
  const int l15 = lane & 15, kq = lane >> 4;
  f32x4 acc[4];
#pragma unroll
  for (int j = 0; j < 4; ++j) acc[j] = (f32x4){0.f, 0.f, 0.f, 0.f};
  const int arow = m0 + w * 16 + l15;
#pragma unroll
  for (int kc = 0; kc < 16; ++kc) {
    const short8 af = *(const short8*)&ygb[(size_t)arow * DIN + kc * 32 + kq * 8];
#pragma unroll
    for (int j = 0; j < 4; ++j) {
      const int brow = n0 + j * 16 + l15;
      const short8 bfr = *(const short8*)&howb[(size_t)brow * DIN + kc * 32 + kq * 8];
      acc[j] = __builtin_amdgcn_mfma_f32_16x16x32_bf16(af, bfr, acc[j], 0, 0, 0);
    }
  }
#pragma unroll
  for (int j = 0; j < 4; ++j)
#pragma unroll
    for (int r = 0; r < 4; ++r) {
      const int g = w * 16 + kq * 4 + r;
      const int p = j * 16 + l15;
      Cs[p][g] = f2b(acc[j][r]);
    }
  __syncthreads();
#pragma unroll
  for (int it = 0; it < 2; ++it) {
    const int c = tid + 256 * it;
    const int p = c >> 3, seg = c & 7;
    *(short8*)&otT[(((size_t)(b * 8 + h) * 64 + p) << 6) + seg * 8] = *(const short8*)&Cs[p][seg * 8];
  }
}

// ---------------------------------------------------------------------------
// K7: fused mix + final. One block = 64 tokens of one b.
__global__ __launch_bounds__(256) void k_mixfinal(
    const unsigned short* __restrict__ swb, const unsigned short* __restrict__ otT,
    const unsigned short* __restrict__ outwb, const float* __restrict__ outb,
    float* __restrict__ out) {
  __shared__ unsigned short lm[33280];  // [64][520] bf16, reused as [64][260] fp32
  const int blk = blockIdx.x;           // 512 = 4 b x 128 chunks
  const int b = blk >> 7;
  const int t0 = (blk & 127) * 64;
  const int tid = threadIdx.x;
  const int w = tid >> 6, lane = tid & 63;
  const int l15 = lane & 15, kq = lane >> 4;
  // Phase 1: wave w handles heads 2w, 2w+1
#pragma unroll
  for (int hh = 0; hh < 2; ++hh) {
    const int h = w * 2 + hh;
    const int bh = b * 8 + h;
    f32x4 acc[4][4];
#pragma unroll
    for (int i = 0; i < 4; ++i)
#pragma unroll
      for (int j = 0; j < 4; ++j) acc[i][j] = (f32x4){0.f, 0.f, 0.f, 0.f};
#pragma unroll
    for (int kt = 0; kt < 2; ++kt) {
      short8 af[4], bfr[4];
#pragma unroll
      for (int i = 0; i < 4; ++i) {
        af[i]  = *(const short8*)&swb[((size_t)bh * NTOK + t0 + i * 16 + l15) * 64 + kt * 32 + kq * 8];
        bfr[i] = *(const short8*)&otT[(((size_t)bh * 64 + i * 16 + l15) << 6) + kt * 32 + kq * 8];
      }
#pragma unroll
      for (int i = 0; i < 4; ++i)
#pragma unroll
        for (int j = 0; j < 4; ++j)
          acc[i][j] = __builtin_amdgcn_mfma_f32_16x16x32_bf16(af[i], bfr[j], acc[i][j], 0, 0, 0);
    }
#pragma unroll
    for (int i = 0; i < 4; ++i)
#pragma unroll
      for (int j = 0; j < 4; ++j)
#pragma unroll
        for (int r = 0; r < 4; ++r)
          lm[(i * 16 + kq * 4 + r) * 520 + h * 64 + j * 16 + l15] = f2b(acc[i][j][r]);
  }
  __syncthreads();
  // Phase 2: wave w covers out-cols [w*64, w*64+64)
  float ob[4];
#pragma unroll
  for (int j = 0; j < 4; ++j) ob[j] = outb[w * 64 + j * 16 + l15];
  f32x4 facc[4][4];
#pragma unroll
  for (int i = 0; i < 4; ++i)
#pragma unroll
    for (int j = 0; j < 4; ++j) facc[i][j] = (f32x4){0.f, 0.f, 0.f, 0.f};
#pragma unroll
  for (int kt = 0; kt < 16; ++kt) {
    short8 af[4], bfr[4];
#pragma unroll
    for (int i = 0; i < 4; ++i) {
      af[i]  = *(const short8*)&lm[(i * 16 + l15) * 520 + kt * 32 + kq * 8];
      bfr[i] = *(const short8*)&outwb[(size_t)(w * 64 + i * 16 + l15) * 512 + kt * 32 + kq * 8];
    }
#pragma unroll
    for (int i = 0; i < 4; ++i)
#pragma unroll
      for (int j = 0; j < 4; ++j)
        facc[i][j] = __builtin_amdgcn_mfma_f32_16x16x32_bf16(af[i], bfr[j], facc[i][j], 0, 0, 0);
  }
  __syncthreads();
  float* lf = (float*)lm;  // [64][260]
#pragma unroll
  for (int i = 0; i < 4; ++i)
#pragma unroll
    for (int j = 0; j < 4; ++j)
#pragma unroll
      for (int r = 0; r < 4; ++r)
        lf[(i * 16 + kq * 4 + r) * 260 + w * 64 + j * 16 + l15] = facc[i][j][r] + ob[j];
  __syncthreads();
#pragma unroll
  for (int it = 0; it < 16; ++it) {
    const int c = tid + 256 * it;        // 4096 = 64 rows x 64 float4
    const int row = c >> 6, seg = c & 63;
    *(float4*)&out[((size_t)(b * NTOK + t0 + row)) * 256 + seg * 4] =
        *(const float4*)&lf[row * 260 + seg * 4];
  }
}

// ---------------------------------------------------------------------------
extern "C" void kernel_launch(void* const* d_in, const int* in_sizes, int n_in,
                              void* d_out, int out_size, void* d_ws, size_t ws_size,
                              hipStream_t stream) {
  const float* x      = (const float*)d_in[0];
  const float* Wfx    = (const float*)d_in[1];
  const float* bfx    = (const float*)d_in[2];
  const float* Wx     = (const float*)d_in[3];
  const float* bx     = (const float*)d_in[4];
  const float* Wslice = (const float*)d_in[5];
  const float* bslice = (const float*)d_in[6];
  const float* temp   = (const float*)d_in[7];
  const float* inw    = (const float*)d_in[8];
  const float* convw  = (const float*)d_in[9];
  const float* convb  = (const float*)d_in[10];
  const float* dtbias = (const float*)d_in[11];
  const float* Alog   = (const float*)d_in[12];
  const float* Dp     = (const float*)d_in[13];
  const float* fcdw   = (const float*)d_in[14];
  const float* normw  = (const float*)d_in[15];
  const float* how    = (const float*)d_in[16];
  const float* outw   = (const float*)d_in[17];
  const float* outb   = (const float*)d_in[18];

  unsigned short* us = (unsigned short*)d_ws;
  unsigned short* cb     = us;                   // 16,777,216 (fx token-major, pitch 512)
  unsigned short* swb    = cb + 16777216;        // 16,777,216
  unsigned short* wcatb  = swb + 16777216;       //    262,144
  unsigned short* outwbf = wcatb + 262144;       //    131,072
  unsigned short* otTb   = outwbf + 131072;      //    131,072
  unsigned short* inwb   = otTb + 131072;        //    598,016
  unsigned short* howb   = inwb + 598016;        //    262,144
  unsigned short* st2b   = howb + 262144;        //    131,072
  unsigned short* ygbb   = st2b + 131072;        //    131,072
  float* fbase = (float*)(ygbb + 131072);
  float* bcat   = fbase;                          //      1,024
  float* st_raw = bcat + 1024;                    //    131,072
  float* snorm  = st_raw + 131072;                //      2,048
  float* zx     = snorm + 2048;                   //    299,008
  float* xbc    = zx + 299008;                    //    163,840
  float* dt2    = xbc + 163840;                   //      4,096
  float* ldA2   = dt2 + 4096;                     //      4,096
  float* ysb    = ldA2 + 4096;                    //    262,144

  hipMemsetAsync(st_raw, 0, (131072 + 2048) * sizeof(float), stream);

  k_cvt     <<<dim3(1225),    256, 0, stream>>>(Wfx, Wx, outw, inw, how, bfx, bx,
                                                wcatb, outwbf, inwb, howb, bcat);
  k_front   <<<dim3(256, 8),  256, 0, stream>>>(x, wcatb, bcat, Wslice, bslice, temp, cb, swb);
  k_st      <<<dim3(16, 32),  256, 0, stream>>>(swb, cb, st_raw, snorm);
  k_stnorm  <<<dim3(512),     256, 0, stream>>>(st_raw, snorm, st2b);
  k_inproj  <<<dim3(4, 19),   256, 0, stream>>>(st2b, inwb, zx);
  k_prep    <<<dim3(656),     256, 0, stream>>>(zx, convw, convb, dtbias, Alog, xbc, dt2, ldA2);
  k_ssm     <<<dim3(64),      256, 0, stream>>>(xbc, dt2, ldA2, ysb);
  k_gate    <<<dim3(256),     256, 0, stream>>>(ysb, xbc, zx, fcdw, Dp, normw, ygbb);
  k_oproj   <<<dim3(4, 8),    256, 0, stream>>>(ygbb, howb, otTb);
  k_mixfinal<<<dim3(512),     256, 0, stream>>>(swb, otTb, outwbf, outb, (float*)d_out);
}